// Round 1
// baseline (996.528 us; speedup 1.0000x reference)
//
#include <hip/hip_runtime.h>
#include <hip/hip_bf16.h>

#define NT 20000
#define NU 2000
#define HID 256
#define HEADS 8
#define FPH 32
#define E_TT 320000
#define E_UT 100000

// ---------------- small K=32 GEMM: C[N,256] = A[N,32] @ W[32,256] + b ----------------
__global__ __launch_bounds__(256) void gemm_k32(const float* __restrict__ A,
                                                const float* __restrict__ W,
                                                const float* __restrict__ bias,
                                                float* __restrict__ C) {
  __shared__ float arow[32];
  int n = blockIdx.x;
  int tid = threadIdx.x;
  if (tid < 32) arow[tid] = A[n * 32 + tid];
  __syncthreads();
  float acc = bias ? bias[tid] : 0.f;
#pragma unroll
  for (int k = 0; k < 32; ++k) acc += arow[k] * W[k * 256 + tid];
  C[n * 256 + tid] = acc;
}

// ---------------- tiled f32 GEMM: C[N,256] = A[N,256] @ W[256,256] (+b)(+relu) -------
#define BM 64
#define BN 64
#define BK 16
__global__ __launch_bounds__(256) void gemm256(const float* __restrict__ A,
                                               const float* __restrict__ W,
                                               const float* __restrict__ bias,
                                               float* __restrict__ C,
                                               int N, int relu) {
  __shared__ float As[BK][BM + 1];
  __shared__ float Bs[BK][BN + 1];
  const int K = 256, M = 256;
  int tid = threadIdx.x;
  int row0 = blockIdx.y * BM, col0 = blockIdx.x * BN;
  int tr = tid / 16, tc = tid % 16;
  float acc[4][4] = {};
  for (int k0 = 0; k0 < K; k0 += BK) {
#pragma unroll
    for (int i = 0; i < 4; ++i) {
      int t = tid + i * 256;
      int ar = t >> 4, ac = t & 15;
      int gr = row0 + ar;
      As[ac][ar] = (gr < N) ? A[gr * K + k0 + ac] : 0.f;
    }
#pragma unroll
    for (int i = 0; i < 4; ++i) {
      int t = tid + i * 256;
      int brow = t >> 6, bcol = t & 63;
      Bs[brow][bcol] = W[(k0 + brow) * M + col0 + bcol];
    }
    __syncthreads();
#pragma unroll
    for (int kk = 0; kk < BK; ++kk) {
      float a[4], b[4];
#pragma unroll
      for (int i = 0; i < 4; ++i) a[i] = As[kk][tr * 4 + i];
#pragma unroll
      for (int j = 0; j < 4; ++j) b[j] = Bs[kk][tc * 4 + j];
#pragma unroll
      for (int i = 0; i < 4; ++i)
#pragma unroll
        for (int j = 0; j < 4; ++j) acc[i][j] += a[i] * b[j];
    }
    __syncthreads();
  }
#pragma unroll
  for (int i = 0; i < 4; ++i) {
    int r = row0 + tr * 4 + i;
    if (r >= N) continue;
#pragma unroll
    for (int j = 0; j < 4; ++j) {
      int c = col0 + tc * 4 + j;
      float v = acc[i][j];
      if (bias) v += bias[c];
      if (relu) v = fmaxf(v, 0.f);
      C[r * M + c] = v;
    }
  }
}

// ---------------- attention helpers ----------------
// W2[k,h] = sum_f wdst[k, h*32+f] * ar[h,f]   (er = h_dst @ W2)
__global__ __launch_bounds__(256) void compute_w2(const float* __restrict__ wdst,
                                                  const float* __restrict__ ar,
                                                  float* __restrict__ w2) {
  int idx = blockIdx.x * 256 + threadIdx.x;  // 2048
  if (idx >= 256 * 8) return;
  int k = idx >> 3, h = idx & 7;
  float s = 0.f;
#pragma unroll
  for (int f = 0; f < 32; ++f) s += wdst[k * 256 + h * 32 + f] * ar[h * 32 + f];
  w2[idx] = s;
}

__global__ __launch_bounds__(256) void compute_er(const float* __restrict__ hdst,
                                                  const float* __restrict__ w2,
                                                  float* __restrict__ er, int N) {
  int idx = blockIdx.x * 256 + threadIdx.x;
  if (idx >= N * 8) return;
  int n = idx >> 3, h = idx & 7;
  float s = 0.f;
  for (int k = 0; k < 256; ++k) s += hdst[n * 256 + k] * w2[k * 8 + h];
  er[idx] = s;
}

// el[n,h] = sum_f fs[n, h*32+f] * al[h,f]
__global__ __launch_bounds__(256) void compute_el(const float* __restrict__ fs,
                                                  const float* __restrict__ al,
                                                  float* __restrict__ el, int N) {
  int idx = blockIdx.x * 256 + threadIdx.x;
  if (idx >= N * 8) return;
  int n = idx >> 3, h = idx & 7;
  float s = 0.f;
#pragma unroll
  for (int f = 0; f < 32; ++f) s += fs[n * 256 + h * 32 + f] * al[h * 32 + f];
  el[idx] = s;
}

// ---------------- CSR build ----------------
__global__ void deg_count(const int* __restrict__ dst, int* __restrict__ deg, int E) {
  int e = blockIdx.x * 256 + threadIdx.x;
  if (e < E) atomicAdd(&deg[dst[e]], 1);
}

__global__ __launch_bounds__(256) void scan_offsets(const int* __restrict__ deg,
                                                    int* __restrict__ off,
                                                    int* __restrict__ cursor, int n) {
  __shared__ int sd[256];
  __shared__ int running;
  int tid = threadIdx.x;
  if (tid == 0) running = 0;
  __syncthreads();
  for (int base = 0; base < n; base += 256) {
    int i = base + tid;
    int v = (i < n) ? deg[i] : 0;
    sd[tid] = v;
    __syncthreads();
    for (int s = 1; s < 256; s <<= 1) {
      int t = (tid >= s) ? sd[tid - s] : 0;
      __syncthreads();
      sd[tid] += t;
      __syncthreads();
    }
    int incl = sd[tid];
    int r = running;
    if (i < n) {
      off[i] = r + incl - v;
      cursor[i] = r + incl - v;
    }
    int total = sd[255];
    __syncthreads();
    if (tid == 0) running = r + total;
    __syncthreads();
  }
  if (tid == 0) off[n] = running;
}

__global__ void csr_scatter(const int* __restrict__ src, const int* __restrict__ dst,
                            int* __restrict__ cursor, int* __restrict__ srcs, int E) {
  int e = blockIdx.x * 256 + threadIdx.x;
  if (e < E) {
    int p = atomicAdd(&cursor[dst[e]], 1);
    srcs[p] = src[e];
  }
}

// ---------------- per-(dst,h) softmax over incoming edges; writes a[pos*8+h] --------
__global__ __launch_bounds__(256) void gat_softmax(const int* __restrict__ offs,
                                                   const int* __restrict__ srcs,
                                                   const float* __restrict__ el,
                                                   const float* __restrict__ er,
                                                   float* __restrict__ a) {
  int idx = blockIdx.x * 256 + threadIdx.x;
  if (idx >= NT * 8) return;
  int n = idx >> 3, h = idx & 7;
  int e0 = offs[n], e1 = offs[n + 1];
  if (e0 == e1) return;
  float ern = er[idx];
  float m = -3.4e38f;
  for (int i = e0; i < e1; ++i) {
    float l = el[srcs[i] * 8 + h] + ern;
    l = l >= 0.f ? l : 0.2f * l;
    m = fmaxf(m, l);
  }
  float s = 0.f;
  for (int i = e0; i < e1; ++i) {
    float l = el[srcs[i] * 8 + h] + ern;
    l = l >= 0.f ? l : 0.2f * l;
    s += expf(l - m);
  }
  float sinv = 1.f / s;
  for (int i = e0; i < e1; ++i) {
    float l = el[srcs[i] * 8 + h] + ern;
    l = l >= 0.f ? l : 0.2f * l;
    a[i * 8 + h] = expf(l - m) * sinv;
  }
}

// ---------------- aggregation: out[n, h*32+f] = sum_edges a * fs[src, h*32+f] -------
__global__ __launch_bounds__(256) void gat_aggregate(const int* __restrict__ offs,
                                                     const int* __restrict__ srcs,
                                                     const float* __restrict__ a,
                                                     const float* __restrict__ fs,
                                                     const float* __restrict__ bias0,
                                                     const float* __restrict__ bias1,
                                                     float* __restrict__ out, int accum) {
  int n = blockIdx.x;
  int tid = threadIdx.x;
  int h = tid >> 5;
  int e0 = offs[n], e1 = offs[n + 1];
  float acc = 0.f;
  for (int i = e0; i < e1; ++i) acc += a[i * 8 + h] * fs[srcs[i] * 256 + tid];
  float* po = out + n * 256 + tid;
  if (accum) {
    *po += acc;
  } else {
    float b = bias0[tid] + (bias1 ? bias1[tid] : 0.f);
    *po = acc + b;
  }
}

// ---------------- head mean: hm[n,f] = mean_h o[n,h,f] ----------------
__global__ __launch_bounds__(256) void head_mean(const float* __restrict__ o,
                                                 float* __restrict__ hm) {
  int idx = blockIdx.x * 256 + threadIdx.x;
  if (idx >= NT * 32) return;
  int n = idx >> 5, f = idx & 31;
  float s = 0.f;
#pragma unroll
  for (int h = 0; h < 8; ++h) s += o[n * 256 + h * 32 + f];
  hm[idx] = s * 0.125f;
}

// ---------------- column mean partials (atomicAdd into g) ----------------
__global__ __launch_bounds__(256) void colsum(const float* __restrict__ X, int rows,
                                              float scale, float* __restrict__ g,
                                              int gbase) {
  int col = threadIdx.x;
  int r0 = blockIdx.x * 256;
  int r1 = min(r0 + 256, rows);
  float s = 0.f;
  for (int r = r0; r < r1; ++r) s += X[r * 256 + col];
  atomicAdd(&g[gbase + col], s * scale);
}

// ---------------- global projection: out[i] = sum_k g[k]*W[k,i] + b[i] --------------
__global__ __launch_bounds__(512) void global_proj(const float* __restrict__ g,
                                                   const float* __restrict__ W,
                                                   const float* __restrict__ b,
                                                   float* __restrict__ out) {
  __shared__ float gl[512];
  int tid = threadIdx.x;
  gl[tid] = g[tid];
  __syncthreads();
  float s = b[tid];
  for (int k = 0; k < 512; ++k) s += gl[k] * W[k * 512 + tid];
  out[tid] = s;
}

extern "C" void kernel_launch(void* const* d_in, const int* in_sizes, int n_in,
                              void* d_out, int out_size, void* d_ws, size_t ws_size,
                              hipStream_t stream) {
  const float* usv_feat   = (const float*)d_in[0];
  const float* task_feat  = (const float*)d_in[1];
  const float* usv_enc_w  = (const float*)d_in[2];
  const float* usv_enc_b  = (const float*)d_in[3];
  const float* task_enc_w = (const float*)d_in[4];
  const float* task_enc_b = (const float*)d_in[5];
  const float* l0_tt_wsrc = (const float*)d_in[6];
  const float* l0_tt_wdst = (const float*)d_in[7];
  const float* l0_tt_al   = (const float*)d_in[8];
  const float* l0_tt_ar   = (const float*)d_in[9];
  const float* l0_tt_bias = (const float*)d_in[10];
  const float* l0_ut_wsrc = (const float*)d_in[11];
  const float* l0_ut_wdst = (const float*)d_in[12];
  const float* l0_ut_al   = (const float*)d_in[13];
  const float* l0_ut_ar   = (const float*)d_in[14];
  const float* l0_ut_bias = (const float*)d_in[15];
  const float* l0_post_w  = (const float*)d_in[16];
  const float* l0_post_b  = (const float*)d_in[17];
  const float* l1_tt_wsrc = (const float*)d_in[18];
  const float* l1_tt_wdst = (const float*)d_in[19];
  const float* l1_tt_al   = (const float*)d_in[20];
  const float* l1_tt_ar   = (const float*)d_in[21];
  const float* l1_tt_bias = (const float*)d_in[22];
  const float* l1_post_w  = (const float*)d_in[23];
  const float* l1_post_b  = (const float*)d_in[24];
  const float* task_dec_w = (const float*)d_in[25];
  const float* task_dec_b = (const float*)d_in[26];
  const float* gp_w       = (const float*)d_in[27];
  const float* gp_b       = (const float*)d_in[28];
  const int* tt_src = (const int*)d_in[29];
  const int* tt_dst = (const int*)d_in[30];
  const int* ut_src = (const int*)d_in[31];
  const int* ut_dst = (const int*)d_in[32];

  float* out = (float*)d_out;
  float* out_usv  = out;                      // [2000,256]
  float* out_task = out + NU * HID;           // [20000,256]
  float* out_glob = out + NU * HID + NT * HID;  // [512]

  char* ws = (char*)d_ws;
  size_t off = 0;
  auto alloc_f = [&](size_t n) {
    float* p = (float*)(ws + off);
    off += ((n * 4 + 1023) / 1024) * 1024;
    return p;
  };
  auto alloc_i = [&](size_t n) {
    int* p = (int*)(ws + off);
    off += ((n * 4 + 1023) / 1024) * 1024;
    return p;
  };
  float* taskh = alloc_f((size_t)NT * HID);
  float* fs    = alloc_f((size_t)NT * HID);
  float* fsu   = alloc_f((size_t)NU * HID);
  float* obuf  = alloc_f((size_t)NT * HID);
  float* hm    = alloc_f((size_t)NT * FPH);
  float* abuf  = alloc_f((size_t)E_TT * HEADS);
  float* el    = alloc_f((size_t)NT * HEADS);
  float* er    = alloc_f((size_t)NT * HEADS);
  float* el2   = alloc_f((size_t)NU * HEADS);
  float* er2   = alloc_f((size_t)NT * HEADS);
  float* w2    = alloc_f(256 * 8);
  float* g     = alloc_f(512);
  int* tt_deg  = alloc_i(NT);
  int* tt_offs = alloc_i(NT + 1);
  int* tt_cur  = alloc_i(NT);
  int* tt_srcs = alloc_i(E_TT);
  int* ut_deg  = alloc_i(NT);
  int* ut_offs = alloc_i(NT + 1);
  int* ut_cur  = alloc_i(NT);
  int* ut_srcs = alloc_i(E_UT);

  hipMemsetAsync(tt_deg, 0, NT * 4, stream);
  hipMemsetAsync(ut_deg, 0, NT * 4, stream);
  hipMemsetAsync(g, 0, 512 * 4, stream);

  // encoders
  gemm_k32<<<NU, 256, 0, stream>>>(usv_feat, usv_enc_w, usv_enc_b, out_usv);
  gemm_k32<<<NT, 256, 0, stream>>>(task_feat, task_enc_w, task_enc_b, taskh);

  // CSR (tt reused by both layers)
  deg_count<<<(E_TT + 255) / 256, 256, 0, stream>>>(tt_dst, tt_deg, E_TT);
  scan_offsets<<<1, 256, 0, stream>>>(tt_deg, tt_offs, tt_cur, NT);
  csr_scatter<<<(E_TT + 255) / 256, 256, 0, stream>>>(tt_src, tt_dst, tt_cur, tt_srcs, E_TT);
  deg_count<<<(E_UT + 255) / 256, 256, 0, stream>>>(ut_dst, ut_deg, E_UT);
  scan_offsets<<<1, 256, 0, stream>>>(ut_deg, ut_offs, ut_cur, NT);
  csr_scatter<<<(E_UT + 255) / 256, 256, 0, stream>>>(ut_src, ut_dst, ut_cur, ut_srcs, E_UT);

  dim3 g256(256 / BN, (NT + BM - 1) / BM);
  dim3 g256u(256 / BN, (NU + BM - 1) / BM);
  int nb_nh = (NT * 8 + 255) / 256;
  int nb_nhu = (NU * 8 + 255) / 256;

  // ---- layer 0, tt ----
  gemm256<<<g256, 256, 0, stream>>>(taskh, l0_tt_wsrc, nullptr, fs, NT, 0);
  compute_w2<<<8, 256, 0, stream>>>(l0_tt_wdst, l0_tt_ar, w2);
  compute_er<<<nb_nh, 256, 0, stream>>>(taskh, w2, er, NT);
  compute_el<<<nb_nh, 256, 0, stream>>>(fs, l0_tt_al, el, NT);
  gat_softmax<<<nb_nh, 256, 0, stream>>>(tt_offs, tt_srcs, el, er, abuf);
  gat_aggregate<<<NT, 256, 0, stream>>>(tt_offs, tt_srcs, abuf, fs, l0_tt_bias, l0_ut_bias, obuf, 0);

  // ---- layer 0, ut ----
  gemm256<<<g256u, 256, 0, stream>>>(out_usv, l0_ut_wsrc, nullptr, fsu, NU, 0);
  compute_w2<<<8, 256, 0, stream>>>(l0_ut_wdst, l0_ut_ar, w2);
  compute_er<<<nb_nh, 256, 0, stream>>>(taskh, w2, er2, NT);
  compute_el<<<nb_nhu, 256, 0, stream>>>(fsu, l0_ut_al, el2, NU);
  gat_softmax<<<nb_nh, 256, 0, stream>>>(ut_offs, ut_srcs, el2, er2, abuf);
  gat_aggregate<<<NT, 256, 0, stream>>>(ut_offs, ut_srcs, abuf, fsu, nullptr, nullptr, obuf, 1);

  // ---- post 0 ----
  head_mean<<<(NT * 32 + 255) / 256, 256, 0, stream>>>(obuf, hm);
  gemm_k32<<<NT, 256, 0, stream>>>(hm, l0_post_w, l0_post_b, taskh);

  // ---- layer 1, tt ----
  gemm256<<<g256, 256, 0, stream>>>(taskh, l1_tt_wsrc, nullptr, fs, NT, 0);
  compute_w2<<<8, 256, 0, stream>>>(l1_tt_wdst, l1_tt_ar, w2);
  compute_er<<<nb_nh, 256, 0, stream>>>(taskh, w2, er, NT);
  compute_el<<<nb_nh, 256, 0, stream>>>(fs, l1_tt_al, el, NT);
  gat_softmax<<<nb_nh, 256, 0, stream>>>(tt_offs, tt_srcs, el, er, abuf);
  gat_aggregate<<<NT, 256, 0, stream>>>(tt_offs, tt_srcs, abuf, fs, l1_tt_bias, nullptr, obuf, 0);

  // ---- post 1 ----
  head_mean<<<(NT * 32 + 255) / 256, 256, 0, stream>>>(obuf, hm);
  gemm_k32<<<NT, 256, 0, stream>>>(hm, l1_post_w, l1_post_b, taskh);

  // ---- decoder (relu) ----
  gemm256<<<g256, 256, 0, stream>>>(taskh, task_dec_w, task_dec_b, out_task, NT, 1);

  // ---- global pooling + projection ----
  colsum<<<(NU + 255) / 256, 256, 0, stream>>>(out_usv, NU, 1.f / NU, g, 0);
  colsum<<<(NT + 255) / 256, 256, 0, stream>>>(out_task, NT, 1.f / NT, g, 256);
  global_proj<<<1, 512, 0, stream>>>(g, gp_w, gp_b, out_glob);
}

// Round 2
// 691.826 us; speedup vs baseline: 1.4404x; 1.4404x over previous
//
#include <hip/hip_runtime.h>
#include <hip/hip_bf16.h>

#define NT 20000
#define NU 2000
#define HID 256
#define HEADS 8
#define FPH 32
#define E_TT 320000
#define E_UT 100000

typedef __attribute__((ext_vector_type(8))) short s16x8;
typedef __attribute__((ext_vector_type(4))) float f32x4;

__device__ inline short f2bf(float f) {
  union { float f; unsigned u; } v; v.f = f;
  unsigned r = v.u + 0x7fff + ((v.u >> 16) & 1);
  return (short)(r >> 16);
}

// ---------------- small K=32 GEMM: C[N,256] = A[N,32] @ W[32,256] + b ----------------
// 16 rows per block, W staged in LDS (16x reuse)
__global__ __launch_bounds__(256) void gemm_k32(const float* __restrict__ A,
                                                const float* __restrict__ W,
                                                const float* __restrict__ bias,
                                                float* __restrict__ C, int N) {
  __shared__ float Ws[32][256];
  __shared__ float Ar[16][32];
  int tid = threadIdx.x;
  for (int i = tid; i < 32 * 256; i += 256) Ws[i >> 8][i & 255] = W[i];
  int n0 = blockIdx.x * 16;
  int nrows = min(16, N - n0);
  for (int i = tid; i < 512; i += 256) {
    int r = i >> 5, k = i & 31;
    if (r < nrows) Ar[r][k] = A[(n0 + r) * 32 + k];
  }
  __syncthreads();
  float b = bias[tid];
  for (int r = 0; r < nrows; ++r) {
    float acc = b;
#pragma unroll
    for (int k = 0; k < 32; ++k) acc += Ar[r][k] * Ws[k][tid];
    C[(size_t)(n0 + r) * 256 + tid] = acc;
  }
}

// ---------------- transpose W[256,256] f32 -> Wt[c][k] bf16 ----------------
__global__ __launch_bounds__(256) void transpose_bf16(const float* __restrict__ W,
                                                      short* __restrict__ Wt) {
  __shared__ float tile[32][33];
  int bx = blockIdx.x, by = blockIdx.y;
  int tx = threadIdx.x & 31, ty = threadIdx.x >> 5;  // 32x8
#pragma unroll
  for (int i = 0; i < 32; i += 8)
    tile[ty + i][tx] = W[(by * 32 + ty + i) * 256 + bx * 32 + tx];
  __syncthreads();
#pragma unroll
  for (int i = 0; i < 32; i += 8)
    Wt[(bx * 32 + ty + i) * 256 + by * 32 + tx] = f2bf(tile[tx][ty + i]);
}

// ------------- MFMA bf16 GEMM: C[N,256] = A[N,256](f32) @ W(Wt bf16 [col][k]) -------
// 128x128 tile, 4 waves (2x2), each wave 64x64 via 4x4 frags of 16x16x32.
__global__ __launch_bounds__(256) void gemm_bf16(const float* __restrict__ A,
                                                 const short* __restrict__ Wt,
                                                 const float* __restrict__ bias,
                                                 float* __restrict__ C,
                                                 int N, int relu) {
  __shared__ short A_lds[128][40];
  __shared__ short B_lds[128][40];
  int tid = threadIdx.x;
  int lane = tid & 63;
  int w = tid >> 6;
  int wr = w >> 1, wc = w & 1;
  int fr = lane & 15, fq = lane >> 4;
  int row0 = blockIdx.y * 128, col0 = blockIdx.x * 128;

  f32x4 acc[4][4];
#pragma unroll
  for (int m = 0; m < 4; ++m)
#pragma unroll
    for (int n = 0; n < 4; ++n) acc[m][n] = (f32x4){0.f, 0.f, 0.f, 0.f};

  int sr = tid >> 1, half = tid & 1;

  for (int k0 = 0; k0 < 256; k0 += 32) {
    // stage A (f32 -> bf16)
    {
      int grow = row0 + sr;
      short tmp[16];
      if (grow < N) {
        const float4* src = (const float4*)(A + (size_t)grow * 256 + k0 + half * 16);
#pragma unroll
        for (int q = 0; q < 4; ++q) {
          float4 v = src[q];
          tmp[q * 4 + 0] = f2bf(v.x); tmp[q * 4 + 1] = f2bf(v.y);
          tmp[q * 4 + 2] = f2bf(v.z); tmp[q * 4 + 3] = f2bf(v.w);
        }
      } else {
#pragma unroll
        for (int q = 0; q < 16; ++q) tmp[q] = 0;
      }
      s16x8* dstp = (s16x8*)&A_lds[sr][half * 16];
      dstp[0] = *(s16x8*)&tmp[0];
      dstp[1] = *(s16x8*)&tmp[8];
    }
    // stage B (bf16, already [col][k])
    {
      const s16x8* src = (const s16x8*)(Wt + (size_t)(col0 + sr) * 256 + k0 + half * 16);
      s16x8* dstp = (s16x8*)&B_lds[sr][half * 16];
      dstp[0] = src[0];
      dstp[1] = src[1];
    }
    __syncthreads();
    s16x8 af[4], bf[4];
#pragma unroll
    for (int m = 0; m < 4; ++m) af[m] = *(s16x8*)&A_lds[wr * 64 + m * 16 + fr][fq * 8];
#pragma unroll
    for (int n = 0; n < 4; ++n) bf[n] = *(s16x8*)&B_lds[wc * 64 + n * 16 + fr][fq * 8];
#pragma unroll
    for (int m = 0; m < 4; ++m)
#pragma unroll
      for (int n = 0; n < 4; ++n)
        acc[m][n] = __builtin_amdgcn_mfma_f32_16x16x32_bf16(af[m], bf[n], acc[m][n], 0, 0, 0);
    __syncthreads();
  }

#pragma unroll
  for (int m = 0; m < 4; ++m) {
    int gr = row0 + wr * 64 + m * 16 + fq * 4;
#pragma unroll
    for (int r = 0; r < 4; ++r) {
      if (gr + r >= N) continue;
#pragma unroll
      for (int n = 0; n < 4; ++n) {
        int gc = col0 + wc * 64 + n * 16 + fr;
        float v = acc[m][n][r];
        if (bias) v += bias[gc];
        if (relu) v = fmaxf(v, 0.f);
        C[(size_t)(gr + r) * 256 + gc] = v;
      }
    }
  }
}

// ---------------- attention helpers ----------------
__global__ __launch_bounds__(256) void compute_w2(const float* __restrict__ wdst,
                                                  const float* __restrict__ ar,
                                                  float* __restrict__ w2) {
  int idx = blockIdx.x * 256 + threadIdx.x;
  if (idx >= 256 * 8) return;
  int k = idx >> 3, h = idx & 7;
  float s = 0.f;
#pragma unroll
  for (int f = 0; f < 32; ++f) s += wdst[k * 256 + h * 32 + f] * ar[h * 32 + f];
  w2[idx] = s;
}

__global__ __launch_bounds__(256) void compute_er(const float* __restrict__ hdst,
                                                  const float* __restrict__ w2,
                                                  float* __restrict__ er, int N) {
  int idx = blockIdx.x * 256 + threadIdx.x;
  if (idx >= N * 8) return;
  int n = idx >> 3, h = idx & 7;
  float s = 0.f;
  for (int k = 0; k < 256; ++k) s += hdst[n * 256 + k] * w2[k * 8 + h];
  er[idx] = s;
}

__global__ __launch_bounds__(256) void compute_el(const float* __restrict__ fs,
                                                  const float* __restrict__ al,
                                                  float* __restrict__ el, int N) {
  int idx = blockIdx.x * 256 + threadIdx.x;
  if (idx >= N * 8) return;
  int n = idx >> 3, h = idx & 7;
  float s = 0.f;
#pragma unroll
  for (int f = 0; f < 32; ++f) s += fs[n * 256 + h * 32 + f] * al[h * 32 + f];
  el[idx] = s;
}

// ---------------- CSR build ----------------
__global__ void deg_count(const int* __restrict__ dst, int* __restrict__ deg, int E) {
  int e = blockIdx.x * 256 + threadIdx.x;
  if (e < E) atomicAdd(&deg[dst[e]], 1);
}

// single block, 1024 threads, handles n <= 20480 (C=20 elems/thread)
__global__ __launch_bounds__(1024) void scan_offsets(const int* __restrict__ deg,
                                                     int* __restrict__ off,
                                                     int* __restrict__ cursor, int n) {
  int tid = threadIdx.x;
  const int C = 20;
  int base = tid * C;
  int local[C];
  int s = 0;
#pragma unroll
  for (int i = 0; i < C; ++i) {
    int idx = base + i;
    int v = (idx < n) ? deg[idx] : 0;
    local[i] = s;
    s += v;
  }
  int lane = tid & 63, wave = tid >> 6;
  int x = s;
#pragma unroll
  for (int d = 1; d < 64; d <<= 1) {
    int y = __shfl_up(x, d, 64);
    if (lane >= d) x += y;
  }
  __shared__ int wsum[16];
  if (lane == 63) wsum[wave] = x;
  __syncthreads();
  if (wave == 0) {
    int wv = (lane < 16) ? wsum[lane] : 0;
#pragma unroll
    for (int d = 1; d < 16; d <<= 1) {
      int y = __shfl_up(wv, d, 64);
      if (lane >= d) wv += y;
    }
    if (lane < 16) wsum[lane] = wv;
  }
  __syncthreads();
  int waveoff = (wave == 0) ? 0 : wsum[wave - 1];
  int excl = waveoff + x - s;
#pragma unroll
  for (int i = 0; i < C; ++i) {
    int idx = base + i;
    if (idx < n) {
      int o = excl + local[i];
      off[idx] = o;
      cursor[idx] = o;
    }
  }
  if (tid == 1023) off[n] = waveoff + x;
}

__global__ void csr_scatter(const int* __restrict__ src, const int* __restrict__ dst,
                            int* __restrict__ cursor, int* __restrict__ srcs, int E) {
  int e = blockIdx.x * 256 + threadIdx.x;
  if (e < E) {
    int p = atomicAdd(&cursor[dst[e]], 1);
    srcs[p] = src[e];
  }
}

// ---------------- per-(dst,h) softmax over incoming edges ----------------
__global__ __launch_bounds__(256) void gat_softmax(const int* __restrict__ offs,
                                                   const int* __restrict__ srcs,
                                                   const float* __restrict__ el,
                                                   const float* __restrict__ er,
                                                   float* __restrict__ a) {
  int idx = blockIdx.x * 256 + threadIdx.x;
  if (idx >= NT * 8) return;
  int n = idx >> 3, h = idx & 7;
  int e0 = offs[n], e1 = offs[n + 1];
  if (e0 == e1) return;
  float ern = er[idx];
  float m = -3.4e38f;
  for (int i = e0; i < e1; ++i) {
    float l = el[srcs[i] * 8 + h] + ern;
    l = l >= 0.f ? l : 0.2f * l;
    m = fmaxf(m, l);
  }
  float s = 0.f;
  for (int i = e0; i < e1; ++i) {
    float l = el[srcs[i] * 8 + h] + ern;
    l = l >= 0.f ? l : 0.2f * l;
    s += expf(l - m);
  }
  float sinv = 1.f / s;
  for (int i = e0; i < e1; ++i) {
    float l = el[srcs[i] * 8 + h] + ern;
    l = l >= 0.f ? l : 0.2f * l;
    a[i * 8 + h] = expf(l - m) * sinv;
  }
}

// ---------------- aggregation ----------------
__global__ __launch_bounds__(256) void gat_aggregate(const int* __restrict__ offs,
                                                     const int* __restrict__ srcs,
                                                     const float* __restrict__ a,
                                                     const float* __restrict__ fs,
                                                     const float* __restrict__ bias0,
                                                     const float* __restrict__ bias1,
                                                     float* __restrict__ out, int accum) {
  int n = blockIdx.x;
  int tid = threadIdx.x;
  int h = tid >> 5;
  int e0 = offs[n], e1 = offs[n + 1];
  float acc = 0.f;
  for (int i = e0; i < e1; ++i) acc += a[i * 8 + h] * fs[(size_t)srcs[i] * 256 + tid];
  float* po = out + (size_t)n * 256 + tid;
  if (accum) {
    *po += acc;
  } else {
    float b = bias0[tid] + (bias1 ? bias1[tid] : 0.f);
    *po = acc + b;
  }
}

// ---------------- head mean ----------------
__global__ __launch_bounds__(256) void head_mean(const float* __restrict__ o,
                                                 float* __restrict__ hm) {
  int idx = blockIdx.x * 256 + threadIdx.x;
  if (idx >= NT * 32) return;
  int n = idx >> 5, f = idx & 31;
  float s = 0.f;
#pragma unroll
  for (int h = 0; h < 8; ++h) s += o[(size_t)n * 256 + h * 32 + f];
  hm[idx] = s * 0.125f;
}

// ---------------- column mean partials ----------------
__global__ __launch_bounds__(256) void colsum(const float* __restrict__ X, int rows,
                                              float scale, float* __restrict__ g,
                                              int gbase) {
  int col = threadIdx.x;
  int r0 = blockIdx.x * 256;
  int r1 = min(r0 + 256, rows);
  float s = 0.f;
  for (int r = r0; r < r1; ++r) s += X[(size_t)r * 256 + col];
  atomicAdd(&g[gbase + col], s * scale);
}

// ---------------- global projection ----------------
__global__ __launch_bounds__(512) void global_proj(const float* __restrict__ g,
                                                   const float* __restrict__ W,
                                                   const float* __restrict__ b,
                                                   float* __restrict__ out) {
  __shared__ float gl[512];
  int tid = threadIdx.x;
  gl[tid] = g[tid];
  __syncthreads();
  float s = b[tid];
  for (int k = 0; k < 512; ++k) s += gl[k] * W[k * 512 + tid];
  out[tid] = s;
}

extern "C" void kernel_launch(void* const* d_in, const int* in_sizes, int n_in,
                              void* d_out, int out_size, void* d_ws, size_t ws_size,
                              hipStream_t stream) {
  const float* usv_feat   = (const float*)d_in[0];
  const float* task_feat  = (const float*)d_in[1];
  const float* usv_enc_w  = (const float*)d_in[2];
  const float* usv_enc_b  = (const float*)d_in[3];
  const float* task_enc_w = (const float*)d_in[4];
  const float* task_enc_b = (const float*)d_in[5];
  const float* l0_tt_wsrc = (const float*)d_in[6];
  const float* l0_tt_wdst = (const float*)d_in[7];
  const float* l0_tt_al   = (const float*)d_in[8];
  const float* l0_tt_ar   = (const float*)d_in[9];
  const float* l0_tt_bias = (const float*)d_in[10];
  const float* l0_ut_wsrc = (const float*)d_in[11];
  const float* l0_ut_wdst = (const float*)d_in[12];
  const float* l0_ut_al   = (const float*)d_in[13];
  const float* l0_ut_ar   = (const float*)d_in[14];
  const float* l0_ut_bias = (const float*)d_in[15];
  const float* l0_post_w  = (const float*)d_in[16];
  const float* l0_post_b  = (const float*)d_in[17];
  const float* l1_tt_wsrc = (const float*)d_in[18];
  const float* l1_tt_wdst = (const float*)d_in[19];
  const float* l1_tt_al   = (const float*)d_in[20];
  const float* l1_tt_ar   = (const float*)d_in[21];
  const float* l1_tt_bias = (const float*)d_in[22];
  const float* l1_post_w  = (const float*)d_in[23];
  const float* l1_post_b  = (const float*)d_in[24];
  const float* task_dec_w = (const float*)d_in[25];
  const float* task_dec_b = (const float*)d_in[26];
  const float* gp_w       = (const float*)d_in[27];
  const float* gp_b       = (const float*)d_in[28];
  const int* tt_src = (const int*)d_in[29];
  const int* tt_dst = (const int*)d_in[30];
  const int* ut_src = (const int*)d_in[31];
  const int* ut_dst = (const int*)d_in[32];

  float* out = (float*)d_out;
  float* out_usv  = out;
  float* out_task = out + NU * HID;
  float* out_glob = out + NU * HID + NT * HID;

  char* ws = (char*)d_ws;
  size_t off = 0;
  auto alloc_f = [&](size_t n) {
    float* p = (float*)(ws + off);
    off += ((n * 4 + 1023) / 1024) * 1024;
    return p;
  };
  auto alloc_i = [&](size_t n) {
    int* p = (int*)(ws + off);
    off += ((n * 4 + 1023) / 1024) * 1024;
    return p;
  };
  auto alloc_s = [&](size_t n) {
    short* p = (short*)(ws + off);
    off += ((n * 2 + 1023) / 1024) * 1024;
    return p;
  };
  float* taskh = alloc_f((size_t)NT * HID);
  float* fs    = alloc_f((size_t)NT * HID);
  float* fsu   = alloc_f((size_t)NU * HID);
  float* obuf  = alloc_f((size_t)NT * HID);
  float* hm    = alloc_f((size_t)NT * FPH);
  float* abuf  = alloc_f((size_t)E_TT * HEADS);
  float* el    = alloc_f((size_t)NT * HEADS);
  float* er    = alloc_f((size_t)NT * HEADS);
  float* el2   = alloc_f((size_t)NU * HEADS);
  float* er2   = alloc_f((size_t)NT * HEADS);
  float* w2    = alloc_f(256 * 8);
  float* g     = alloc_f(512);
  short* wt_l0tt = alloc_s(256 * 256);
  short* wt_l0ut = alloc_s(256 * 256);
  short* wt_l1tt = alloc_s(256 * 256);
  short* wt_dec  = alloc_s(256 * 256);
  int* tt_deg  = alloc_i(NT);
  int* tt_offs = alloc_i(NT + 1);
  int* tt_cur  = alloc_i(NT);
  int* tt_srcs = alloc_i(E_TT);
  int* ut_deg  = alloc_i(NT);
  int* ut_offs = alloc_i(NT + 1);
  int* ut_cur  = alloc_i(NT);
  int* ut_srcs = alloc_i(E_UT);

  hipMemsetAsync(tt_deg, 0, NT * 4, stream);
  hipMemsetAsync(ut_deg, 0, NT * 4, stream);
  hipMemsetAsync(g, 0, 512 * 4, stream);

  dim3 t8(8, 8);
  // weight transposes (independent, run upfront)
  transpose_bf16<<<t8, 256, 0, stream>>>(l0_tt_wsrc, wt_l0tt);
  transpose_bf16<<<t8, 256, 0, stream>>>(l0_ut_wsrc, wt_l0ut);
  transpose_bf16<<<t8, 256, 0, stream>>>(l1_tt_wsrc, wt_l1tt);
  transpose_bf16<<<t8, 256, 0, stream>>>(task_dec_w, wt_dec);

  // encoders
  gemm_k32<<<(NU + 15) / 16, 256, 0, stream>>>(usv_feat, usv_enc_w, usv_enc_b, out_usv, NU);
  gemm_k32<<<(NT + 15) / 16, 256, 0, stream>>>(task_feat, task_enc_w, task_enc_b, taskh, NT);

  // CSR (tt reused by both layers)
  deg_count<<<(E_TT + 255) / 256, 256, 0, stream>>>(tt_dst, tt_deg, E_TT);
  scan_offsets<<<1, 1024, 0, stream>>>(tt_deg, tt_offs, tt_cur, NT);
  csr_scatter<<<(E_TT + 255) / 256, 256, 0, stream>>>(tt_src, tt_dst, tt_cur, tt_srcs, E_TT);
  deg_count<<<(E_UT + 255) / 256, 256, 0, stream>>>(ut_dst, ut_deg, E_UT);
  scan_offsets<<<1, 1024, 0, stream>>>(ut_deg, ut_offs, ut_cur, NT);
  csr_scatter<<<(E_UT + 255) / 256, 256, 0, stream>>>(ut_src, ut_dst, ut_cur, ut_srcs, E_UT);

  dim3 gT(2, (NT + 127) / 128);
  dim3 gU(2, (NU + 127) / 128);
  int nb_nh = (NT * 8 + 255) / 256;
  int nb_nhu = (NU * 8 + 255) / 256;

  // ---- layer 0, tt ----
  gemm_bf16<<<gT, 256, 0, stream>>>(taskh, wt_l0tt, nullptr, fs, NT, 0);
  compute_w2<<<8, 256, 0, stream>>>(l0_tt_wdst, l0_tt_ar, w2);
  compute_er<<<nb_nh, 256, 0, stream>>>(taskh, w2, er, NT);
  compute_el<<<nb_nh, 256, 0, stream>>>(fs, l0_tt_al, el, NT);
  gat_softmax<<<nb_nh, 256, 0, stream>>>(tt_offs, tt_srcs, el, er, abuf);
  gat_aggregate<<<NT, 256, 0, stream>>>(tt_offs, tt_srcs, abuf, fs, l0_tt_bias, l0_ut_bias, obuf, 0);

  // ---- layer 0, ut ----
  gemm_bf16<<<gU, 256, 0, stream>>>(out_usv, wt_l0ut, nullptr, fsu, NU, 0);
  compute_w2<<<8, 256, 0, stream>>>(l0_ut_wdst, l0_ut_ar, w2);
  compute_er<<<nb_nh, 256, 0, stream>>>(taskh, w2, er2, NT);
  compute_el<<<nb_nhu, 256, 0, stream>>>(fsu, l0_ut_al, el2, NU);
  gat_softmax<<<nb_nh, 256, 0, stream>>>(ut_offs, ut_srcs, el2, er2, abuf);
  gat_aggregate<<<NT, 256, 0, stream>>>(ut_offs, ut_srcs, abuf, fsu, nullptr, nullptr, obuf, 1);

  // ---- post 0 ----
  head_mean<<<(NT * 32 + 255) / 256, 256, 0, stream>>>(obuf, hm);
  gemm_k32<<<(NT + 15) / 16, 256, 0, stream>>>(hm, l0_post_w, l0_post_b, taskh, NT);

  // ---- layer 1, tt ----
  gemm_bf16<<<gT, 256, 0, stream>>>(taskh, wt_l1tt, nullptr, fs, NT, 0);
  compute_w2<<<8, 256, 0, stream>>>(l1_tt_wdst, l1_tt_ar, w2);
  compute_er<<<nb_nh, 256, 0, stream>>>(taskh, w2, er, NT);
  compute_el<<<nb_nh, 256, 0, stream>>>(fs, l1_tt_al, el, NT);
  gat_softmax<<<nb_nh, 256, 0, stream>>>(tt_offs, tt_srcs, el, er, abuf);
  gat_aggregate<<<NT, 256, 0, stream>>>(tt_offs, tt_srcs, abuf, fs, l1_tt_bias, nullptr, obuf, 0);

  // ---- post 1 ----
  head_mean<<<(NT * 32 + 255) / 256, 256, 0, stream>>>(obuf, hm);
  gemm_k32<<<(NT + 15) / 16, 256, 0, stream>>>(hm, l1_post_w, l1_post_b, taskh, NT);

  // ---- decoder (relu) ----
  gemm_bf16<<<gT, 256, 0, stream>>>(taskh, wt_dec, task_dec_b, out_task, NT, 1);

  // ---- global pooling + projection ----
  colsum<<<(NU + 255) / 256, 256, 0, stream>>>(out_usv, NU, 1.f / NU, g, 0);
  colsum<<<(NT + 255) / 256, 256, 0, stream>>>(out_task, NT, 1.f / NT, g, 256);
  global_proj<<<1, 512, 0, stream>>>(g, gp_w, gp_b, out_glob);
}

// Round 3
// 472.918 us; speedup vs baseline: 2.1072x; 1.4629x over previous
//
#include <hip/hip_runtime.h>
#include <hip/hip_bf16.h>

#define NT 20000
#define NU 2000
#define HID 256
#define HEADS 8
#define FPH 32
#define E_TT 320000
#define E_UT 100000

typedef __attribute__((ext_vector_type(8))) short s16x8;
typedef __attribute__((ext_vector_type(4))) short s16x4;
typedef __attribute__((ext_vector_type(4))) float f32x4;

__device__ inline short f2bf(float f) {
  union { float f; unsigned u; } v; v.f = f;
  unsigned r = v.u + 0x7fff + ((v.u >> 16) & 1);
  return (short)(r >> 16);
}
__device__ inline float bf2f(short s) {
  return __uint_as_float(((unsigned)(unsigned short)s) << 16);
}

// ---------------- init: zero deg arrays + g ----------------
__global__ __launch_bounds__(256) void init_zero(int* __restrict__ tt_deg,
                                                 int* __restrict__ ut_deg,
                                                 float* __restrict__ g) {
  int i = blockIdx.x * 256 + threadIdx.x;
  if (i < NT) { tt_deg[i] = 0; ut_deg[i] = 0; }
  if (i < 512) g[i] = 0.f;
}

// ---------------- batched transpose: 4x W[256,256] f32 -> Wt[c][k] bf16 -------------
__global__ __launch_bounds__(256) void transpose4(const float* __restrict__ w0,
                                                  const float* __restrict__ w1,
                                                  const float* __restrict__ w2_,
                                                  const float* __restrict__ w3,
                                                  short* __restrict__ o0,
                                                  short* __restrict__ o1,
                                                  short* __restrict__ o2,
                                                  short* __restrict__ o3) {
  __shared__ float tile[32][33];
  int z = blockIdx.z;
  const float* W = (z == 0) ? w0 : (z == 1) ? w1 : (z == 2) ? w2_ : w3;
  short* Wt = (z == 0) ? o0 : (z == 1) ? o1 : (z == 2) ? o2 : o3;
  int bx = blockIdx.x, by = blockIdx.y;
  int tx = threadIdx.x & 31, ty = threadIdx.x >> 5;
#pragma unroll
  for (int i = 0; i < 32; i += 8)
    tile[ty + i][tx] = W[(by * 32 + ty + i) * 256 + bx * 32 + tx];
  __syncthreads();
#pragma unroll
  for (int i = 0; i < 32; i += 8)
    Wt[(bx * 32 + ty + i) * 256 + by * 32 + tx] = f2bf(tile[tx][ty + i]);
}

// ---------------- batched w2: w2all[z][k][h] = sum_f wdst[k,h*32+f]*ar[h,f] ---------
__global__ __launch_bounds__(256) void w2_batch(const float* __restrict__ wd0,
                                                const float* __restrict__ ar0,
                                                const float* __restrict__ wd1,
                                                const float* __restrict__ ar1,
                                                const float* __restrict__ wd2,
                                                const float* __restrict__ ar2,
                                                float* __restrict__ w2all) {
  int z = blockIdx.y;
  const float* wd = (z == 0) ? wd0 : (z == 1) ? wd1 : wd2;
  const float* ar = (z == 0) ? ar0 : (z == 1) ? ar1 : ar2;
  int idx = blockIdx.x * 256 + threadIdx.x;
  if (idx >= 2048) return;
  int k = idx >> 3, h = idx & 7;
  float s = 0.f;
#pragma unroll
  for (int f = 0; f < 32; ++f) s += wd[k * 256 + h * 32 + f] * ar[h * 32 + f];
  w2all[z * 2048 + idx] = s;
}

// ---------------- K=32 GEMM: [N,32]f32 @ [32,256] + b -> f32 and/or bf16 ------------
__global__ __launch_bounds__(256) void gemm_k32(const float* __restrict__ A,
                                                const float* __restrict__ W,
                                                const float* __restrict__ bias,
                                                float* __restrict__ Cf,
                                                short* __restrict__ Cb, int N) {
  __shared__ float Ws[32][256];
  __shared__ float Ar[16][32];
  int tid = threadIdx.x;
  for (int i = tid; i < 32 * 256; i += 256) Ws[i >> 8][i & 255] = W[i];
  int n0 = blockIdx.x * 16;
  int nrows = min(16, N - n0);
  for (int i = tid; i < 512; i += 256) {
    int r = i >> 5, k = i & 31;
    if (r < nrows) Ar[r][k] = A[(size_t)(n0 + r) * 32 + k];
  }
  __syncthreads();
  float b = bias[tid];
  for (int r = 0; r < nrows; ++r) {
    float acc = b;
#pragma unroll
    for (int k = 0; k < 32; ++k) acc += Ar[r][k] * Ws[k][tid];
    size_t o = (size_t)(n0 + r) * 256 + tid;
    if (Cf) Cf[o] = acc;
    if (Cb) Cb[o] = f2bf(acc);
  }
}

// ---------------- fused head-mean + K=32 GEMM -> bf16 ----------------
__global__ __launch_bounds__(256) void gemm_k32hm(const float* __restrict__ obuf,
                                                  const float* __restrict__ W,
                                                  const float* __restrict__ bias,
                                                  short* __restrict__ Cb, int N) {
  __shared__ float Ws[32][256];
  __shared__ float Ar[16][32];
  int tid = threadIdx.x;
  for (int i = tid; i < 32 * 256; i += 256) Ws[i >> 8][i & 255] = W[i];
  int n0 = blockIdx.x * 16;
  for (int i = tid; i < 512; i += 256) {
    int r = i >> 5, f = i & 31;
    int n = n0 + r;
    float s = 0.f;
    if (n < N) {
#pragma unroll
      for (int h = 0; h < 8; ++h) s += obuf[(size_t)n * 256 + h * 32 + f];
    }
    Ar[r][f] = s * 0.125f;
  }
  __syncthreads();
  float b = bias[tid];
  int nrows = min(16, N - n0);
  for (int r = 0; r < nrows; ++r) {
    float acc = b;
#pragma unroll
    for (int k = 0; k < 32; ++k) acc += Ar[r][k] * Ws[k][tid];
    Cb[(size_t)(n0 + r) * 256 + tid] = f2bf(acc);
  }
}

// ------------- MFMA bf16 GEMM: C[N,256] = A[N,256](bf16) @ Wt(bf16 [col][k]) --------
__global__ __launch_bounds__(256) void gemm_bf16(const short* __restrict__ A,
                                                 const short* __restrict__ Wt,
                                                 const float* __restrict__ bias,
                                                 float* __restrict__ Cf,
                                                 short* __restrict__ Cb,
                                                 int N, int relu) {
  __shared__ short A_lds[128][40];
  __shared__ short B_lds[128][40];
  int tid = threadIdx.x;
  int lane = tid & 63;
  int w = tid >> 6;
  int wr = w >> 1, wc = w & 1;
  int fr = lane & 15, fq = lane >> 4;
  int row0 = blockIdx.y * 128, col0 = blockIdx.x * 128;

  f32x4 acc[4][4];
#pragma unroll
  for (int m = 0; m < 4; ++m)
#pragma unroll
    for (int n = 0; n < 4; ++n) acc[m][n] = (f32x4){0.f, 0.f, 0.f, 0.f};

  int sr = tid >> 1, half = tid & 1;

  for (int k0 = 0; k0 < 256; k0 += 32) {
    int grow = row0 + sr;
    s16x8 a0 = (s16x8){0,0,0,0,0,0,0,0}, a1 = a0;
    if (grow < N) {
      const s16x8* ap = (const s16x8*)(A + (size_t)grow * 256 + k0 + half * 16);
      a0 = ap[0]; a1 = ap[1];
    }
    s16x8* da = (s16x8*)&A_lds[sr][half * 16];
    da[0] = a0; da[1] = a1;
    const s16x8* bp = (const s16x8*)(Wt + (size_t)(col0 + sr) * 256 + k0 + half * 16);
    s16x8* db = (s16x8*)&B_lds[sr][half * 16];
    db[0] = bp[0]; db[1] = bp[1];
    __syncthreads();
    s16x8 af[4], bf[4];
#pragma unroll
    for (int m = 0; m < 4; ++m) af[m] = *(s16x8*)&A_lds[wr * 64 + m * 16 + fr][fq * 8];
#pragma unroll
    for (int n = 0; n < 4; ++n) bf[n] = *(s16x8*)&B_lds[wc * 64 + n * 16 + fr][fq * 8];
#pragma unroll
    for (int m = 0; m < 4; ++m)
#pragma unroll
      for (int n = 0; n < 4; ++n)
        acc[m][n] = __builtin_amdgcn_mfma_f32_16x16x32_bf16(af[m], bf[n], acc[m][n], 0, 0, 0);
    __syncthreads();
  }

#pragma unroll
  for (int m = 0; m < 4; ++m) {
    int gr = row0 + wr * 64 + m * 16 + fq * 4;
#pragma unroll
    for (int r = 0; r < 4; ++r) {
      if (gr + r >= N) continue;
#pragma unroll
      for (int n = 0; n < 4; ++n) {
        int gc = col0 + wc * 64 + n * 16 + fr;
        float v = acc[m][n][r];
        if (bias) v += bias[gc];
        if (relu) v = fmaxf(v, 0.f);
        size_t o = (size_t)(gr + r) * 256 + gc;
        if (Cf) Cf[o] = v;
        if (Cb) Cb[o] = f2bf(v);
      }
    }
  }
}

// ---------------- fused el + er (thread per (n,h), bf16 vec loads) ----------------
__global__ __launch_bounds__(256) void el_er(const short* __restrict__ fsb,
                                             const float* __restrict__ al,
                                             float* __restrict__ el, int nEl,
                                             const short* __restrict__ hb,
                                             const float* __restrict__ w2,
                                             float* __restrict__ er, int nEr) {
  int nbEl = (nEl * 8 + 255) >> 8;
  if ((int)blockIdx.x < nbEl) {
    int idx = blockIdx.x * 256 + threadIdx.x;
    if (idx >= nEl * 8) return;
    int n = idx >> 3, h = idx & 7;
    const s16x8* p = (const s16x8*)(fsb + (size_t)n * 256 + h * 32);
    const float* alh = al + h * 32;
    float s = 0.f;
#pragma unroll
    for (int q = 0; q < 4; ++q) {
      s16x8 v = p[q];
#pragma unroll
      for (int j = 0; j < 8; ++j) s += bf2f(v[j]) * alh[q * 8 + j];
    }
    el[idx] = s;
  } else {
    int idx = (blockIdx.x - nbEl) * 256 + threadIdx.x;
    if (idx >= nEr * 8) return;
    int n = idx >> 3, h = idx & 7;
    const s16x8* p = (const s16x8*)(hb + (size_t)n * 256);
    float s = 0.f;
#pragma unroll 4
    for (int q = 0; q < 32; ++q) {
      s16x8 v = p[q];
#pragma unroll
      for (int j = 0; j < 8; ++j) s += bf2f(v[j]) * w2[(q * 8 + j) * 8 + h];
    }
    er[idx] = s;
  }
}

// ---------------- batched CSR build ----------------
__global__ void deg2(const int* __restrict__ tt_dst, const int* __restrict__ ut_dst,
                     int* __restrict__ tt_deg, int* __restrict__ ut_deg) {
  int e = blockIdx.x * 256 + threadIdx.x;
  if (e < E_TT) atomicAdd(&tt_deg[tt_dst[e]], 1);
  int e2 = e - E_TT;
  if (e2 >= 0 && e2 < E_UT) atomicAdd(&ut_deg[ut_dst[e2]], 1);
}

__global__ __launch_bounds__(1024) void scan2(const int* __restrict__ d0, int* __restrict__ o0,
                                              int* __restrict__ c0,
                                              const int* __restrict__ d1, int* __restrict__ o1,
                                              int* __restrict__ c1, int n) {
  const int* deg = blockIdx.x ? d1 : d0;
  int* off = blockIdx.x ? o1 : o0;
  int* cursor = blockIdx.x ? c1 : c0;
  int tid = threadIdx.x;
  const int C = 20;
  int base = tid * C;
  int local[C];
  int s = 0;
#pragma unroll
  for (int i = 0; i < C; ++i) {
    int idx = base + i;
    int v = (idx < n) ? deg[idx] : 0;
    local[i] = s;
    s += v;
  }
  int lane = tid & 63, wave = tid >> 6;
  int x = s;
#pragma unroll
  for (int d = 1; d < 64; d <<= 1) {
    int y = __shfl_up(x, d, 64);
    if (lane >= d) x += y;
  }
  __shared__ int wsum[16];
  if (lane == 63) wsum[wave] = x;
  __syncthreads();
  if (wave == 0) {
    int wv = (lane < 16) ? wsum[lane] : 0;
#pragma unroll
    for (int d = 1; d < 16; d <<= 1) {
      int y = __shfl_up(wv, d, 64);
      if (lane >= d) wv += y;
    }
    if (lane < 16) wsum[lane] = wv;
  }
  __syncthreads();
  int waveoff = (wave == 0) ? 0 : wsum[wave - 1];
  int excl = waveoff + x - s;
#pragma unroll
  for (int i = 0; i < C; ++i) {
    int idx = base + i;
    if (idx < n) {
      int o = excl + local[i];
      off[idx] = o;
      cursor[idx] = o;
    }
  }
  if (tid == 1023) off[n] = waveoff + x;
}

__global__ void scat2(const int* __restrict__ tt_src, const int* __restrict__ tt_dst,
                      int* __restrict__ tt_cur, int* __restrict__ tt_srcs,
                      const int* __restrict__ ut_src, const int* __restrict__ ut_dst,
                      int* __restrict__ ut_cur, int* __restrict__ ut_srcs) {
  int e = blockIdx.x * 256 + threadIdx.x;
  if (e < E_TT) {
    int p = atomicAdd(&tt_cur[tt_dst[e]], 1);
    tt_srcs[p] = tt_src[e];
  }
  int e2 = e - E_TT;
  if (e2 >= 0 && e2 < E_UT) {
    int p = atomicAdd(&ut_cur[ut_dst[e2]], 1);
    ut_srcs[p] = ut_src[e2];
  }
}

// ---------------- fused softmax + aggregation, one wave per dst node ----------------
__global__ __launch_bounds__(256) void gat_fused(const int* __restrict__ offs,
                                                 const int* __restrict__ srcs,
                                                 const float* __restrict__ el,
                                                 const float* __restrict__ er,
                                                 const short* __restrict__ fsb,
                                                 const float* __restrict__ bias0,
                                                 const float* __restrict__ bias1,
                                                 float* __restrict__ out,
                                                 int accum, int ndst) {
  int wv = threadIdx.x >> 6, lane = threadIdx.x & 63;
  int n = blockIdx.x * 4 + wv;
  if (n >= ndst) return;
  int e0 = offs[n], e1 = offs[n + 1];
  float4* po = (float4*)(out + (size_t)n * 256 + lane * 4);
  if (e0 == e1) {
    if (!accum) {
      float4 b = *(const float4*)(bias0 + lane * 4);
      if (bias1) {
        float4 b1 = *(const float4*)(bias1 + lane * 4);
        b.x += b1.x; b.y += b1.y; b.z += b1.z; b.w += b1.w;
      }
      *po = b;
    }
    return;
  }
  // phase 1: per-head max & sum (lane = slot*8 + h)
  int h1 = lane & 7, slot = lane >> 3;
  float ern1 = er[n * 8 + h1];
  float m = -3.4e38f;
  for (int i = e0 + slot; i < e1; i += 8) {
    float l = el[srcs[i] * 8 + h1] + ern1;
    l = l >= 0.f ? l : 0.2f * l;
    m = fmaxf(m, l);
  }
  m = fmaxf(m, __shfl_xor(m, 8));
  m = fmaxf(m, __shfl_xor(m, 16));
  m = fmaxf(m, __shfl_xor(m, 32));
  float s = 0.f;
  for (int i = e0 + slot; i < e1; i += 8) {
    float l = el[srcs[i] * 8 + h1] + ern1;
    l = l >= 0.f ? l : 0.2f * l;
    s += __expf(l - m);
  }
  s += __shfl_xor(s, 8);
  s += __shfl_xor(s, 16);
  s += __shfl_xor(s, 32);
  // phase 2: aggregate; lane owns elements 4*lane..4*lane+3 (head = lane>>3)
  int h2 = lane >> 3;
  float mh = __shfl(m, h2);
  float sh = __shfl(s, h2);
  float ern2 = __shfl(ern1, h2);
  float ax = 0.f, ay = 0.f, az = 0.f, aw = 0.f;
  for (int i = e0; i < e1; ++i) {
    int src = srcs[i];
    float l = el[src * 8 + h2] + ern2;
    l = l >= 0.f ? l : 0.2f * l;
    float wgt = __expf(l - mh);
    s16x4 v = *(const s16x4*)(fsb + (size_t)src * 256 + lane * 4);
    ax += wgt * bf2f(v[0]);
    ay += wgt * bf2f(v[1]);
    az += wgt * bf2f(v[2]);
    aw += wgt * bf2f(v[3]);
  }
  float sinv = 1.f / sh;
  float4 o = {ax * sinv, ay * sinv, az * sinv, aw * sinv};
  if (accum) {
    float4 p = *po;
    o.x += p.x; o.y += p.y; o.z += p.z; o.w += p.w;
    *po = o;
  } else {
    float4 b = *(const float4*)(bias0 + lane * 4);
    o.x += b.x; o.y += b.y; o.z += b.z; o.w += b.w;
    if (bias1) {
      float4 b1 = *(const float4*)(bias1 + lane * 4);
      o.x += b1.x; o.y += b1.y; o.z += b1.z; o.w += b1.w;
    }
    *po = o;
  }
}

// ---------------- batched column means ----------------
__global__ __launch_bounds__(256) void colsum2(const float* __restrict__ usv,
                                               const float* __restrict__ task,
                                               float* __restrict__ g) {
  int col = threadIdx.x;
  int b = blockIdx.x;
  if (b < 8) {
    int r0 = b * 256, r1 = min(r0 + 256, NU);
    float s = 0.f;
    for (int r = r0; r < r1; ++r) s += usv[(size_t)r * 256 + col];
    atomicAdd(&g[col], s * (1.f / NU));
  } else {
    int bb = b - 8;
    int r0 = bb * 256, r1 = min(r0 + 256, NT);
    float s = 0.f;
    for (int r = r0; r < r1; ++r) s += task[(size_t)r * 256 + col];
    atomicAdd(&g[256 + col], s * (1.f / NT));
  }
}

// ---------------- global projection ----------------
__global__ __launch_bounds__(512) void global_proj(const float* __restrict__ g,
                                                   const float* __restrict__ W,
                                                   const float* __restrict__ b,
                                                   float* __restrict__ out) {
  __shared__ float gl[512];
  int tid = threadIdx.x;
  gl[tid] = g[tid];
  __syncthreads();
  float s = b[tid];
  for (int k = 0; k < 512; ++k) s += gl[k] * W[k * 512 + tid];
  out[tid] = s;
}

extern "C" void kernel_launch(void* const* d_in, const int* in_sizes, int n_in,
                              void* d_out, int out_size, void* d_ws, size_t ws_size,
                              hipStream_t stream) {
  const float* usv_feat   = (const float*)d_in[0];
  const float* task_feat  = (const float*)d_in[1];
  const float* usv_enc_w  = (const float*)d_in[2];
  const float* usv_enc_b  = (const float*)d_in[3];
  const float* task_enc_w = (const float*)d_in[4];
  const float* task_enc_b = (const float*)d_in[5];
  const float* l0_tt_wsrc = (const float*)d_in[6];
  const float* l0_tt_wdst = (const float*)d_in[7];
  const float* l0_tt_al   = (const float*)d_in[8];
  const float* l0_tt_ar   = (const float*)d_in[9];
  const float* l0_tt_bias = (const float*)d_in[10];
  const float* l0_ut_wsrc = (const float*)d_in[11];
  const float* l0_ut_wdst = (const float*)d_in[12];
  const float* l0_ut_al   = (const float*)d_in[13];
  const float* l0_ut_ar   = (const float*)d_in[14];
  const float* l0_ut_bias = (const float*)d_in[15];
  const float* l0_post_w  = (const float*)d_in[16];
  const float* l0_post_b  = (const float*)d_in[17];
  const float* l1_tt_wsrc = (const float*)d_in[18];
  const float* l1_tt_wdst = (const float*)d_in[19];
  const float* l1_tt_al   = (const float*)d_in[20];
  const float* l1_tt_ar   = (const float*)d_in[21];
  const float* l1_tt_bias = (const float*)d_in[22];
  const float* l1_post_w  = (const float*)d_in[23];
  const float* l1_post_b  = (const float*)d_in[24];
  const float* task_dec_w = (const float*)d_in[25];
  const float* task_dec_b = (const float*)d_in[26];
  const float* gp_w       = (const float*)d_in[27];
  const float* gp_b       = (const float*)d_in[28];
  const int* tt_src = (const int*)d_in[29];
  const int* tt_dst = (const int*)d_in[30];
  const int* ut_src = (const int*)d_in[31];
  const int* ut_dst = (const int*)d_in[32];

  float* out = (float*)d_out;
  float* out_usv  = out;
  float* out_task = out + NU * HID;
  float* out_glob = out + NU * HID + NT * HID;

  char* ws = (char*)d_ws;
  size_t off = 0;
  auto alloc_f = [&](size_t n) {
    float* p = (float*)(ws + off);
    off += ((n * 4 + 1023) / 1024) * 1024;
    return p;
  };
  auto alloc_i = [&](size_t n) {
    int* p = (int*)(ws + off);
    off += ((n * 4 + 1023) / 1024) * 1024;
    return p;
  };
  auto alloc_s = [&](size_t n) {
    short* p = (short*)(ws + off);
    off += ((n * 2 + 1023) / 1024) * 1024;
    return p;
  };
  short* taskh_b = alloc_s((size_t)NT * HID);
  short* usvh_b  = alloc_s((size_t)NU * HID);
  short* fs_b    = alloc_s((size_t)NT * HID);
  short* fsu_b   = alloc_s((size_t)NU * HID);
  float* obuf  = alloc_f((size_t)NT * HID);
  float* el    = alloc_f((size_t)NT * HEADS);
  float* er    = alloc_f((size_t)NT * HEADS);
  float* el2   = alloc_f((size_t)NU * HEADS);
  float* er2   = alloc_f((size_t)NT * HEADS);
  float* w2all = alloc_f(3 * 2048);
  float* g     = alloc_f(512);
  short* wt0 = alloc_s(256 * 256);
  short* wt1 = alloc_s(256 * 256);
  short* wt2 = alloc_s(256 * 256);
  short* wt3 = alloc_s(256 * 256);
  int* tt_deg  = alloc_i(NT);
  int* tt_offs = alloc_i(NT + 1);
  int* tt_cur  = alloc_i(NT);
  int* tt_srcs = alloc_i(E_TT);
  int* ut_deg  = alloc_i(NT);
  int* ut_offs = alloc_i(NT + 1);
  int* ut_cur  = alloc_i(NT);
  int* ut_srcs = alloc_i(E_UT);

  init_zero<<<(NT + 255) / 256, 256, 0, stream>>>(tt_deg, ut_deg, g);

  transpose4<<<dim3(8, 8, 4), 256, 0, stream>>>(l0_tt_wsrc, l0_ut_wsrc, l1_tt_wsrc, task_dec_w,
                                                wt0, wt1, wt2, wt3);
  w2_batch<<<dim3(8, 3), 256, 0, stream>>>(l0_tt_wdst, l0_tt_ar, l0_ut_wdst, l0_ut_ar,
                                           l1_tt_wdst, l1_tt_ar, w2all);

  // encoders
  gemm_k32<<<(NU + 15) / 16, 256, 0, stream>>>(usv_feat, usv_enc_w, usv_enc_b, out_usv, usvh_b, NU);
  gemm_k32<<<(NT + 15) / 16, 256, 0, stream>>>(task_feat, task_enc_w, task_enc_b, nullptr, taskh_b, NT);

  // CSR build (batched over both graphs)
  int nbE = (E_TT + E_UT + 255) / 256;
  deg2<<<nbE, 256, 0, stream>>>(tt_dst, ut_dst, tt_deg, ut_deg);
  scan2<<<2, 1024, 0, stream>>>(tt_deg, tt_offs, tt_cur, ut_deg, ut_offs, ut_cur, NT);
  scat2<<<nbE, 256, 0, stream>>>(tt_src, tt_dst, tt_cur, tt_srcs, ut_src, ut_dst, ut_cur, ut_srcs);

  dim3 gT(2, (NT + 127) / 128);
  dim3 gU(2, (NU + 127) / 128);
  int nbT = (NT * 8 + 255) / 256;      // el/er blocks for NT
  int nbU = (NU * 8 + 255) / 256;
  int nbAgg = (NT + 3) / 4;

  // ---- layer 0, tt ----
  gemm_bf16<<<gT, 256, 0, stream>>>(taskh_b, wt0, nullptr, nullptr, fs_b, NT, 0);
  el_er<<<nbT + nbT, 256, 0, stream>>>(fs_b, l0_tt_al, el, NT, taskh_b, w2all, er, NT);
  gat_fused<<<nbAgg, 256, 0, stream>>>(tt_offs, tt_srcs, el, er, fs_b, l0_tt_bias, l0_ut_bias, obuf, 0, NT);

  // ---- layer 0, ut ----
  gemm_bf16<<<gU, 256, 0, stream>>>(usvh_b, wt1, nullptr, nullptr, fsu_b, NU, 0);
  el_er<<<nbU + nbT, 256, 0, stream>>>(fsu_b, l0_ut_al, el2, NU, taskh_b, w2all + 2048, er2, NT);
  gat_fused<<<nbAgg, 256, 0, stream>>>(ut_offs, ut_srcs, el2, er2, fsu_b, nullptr, nullptr, obuf, 1, NT);

  // ---- post 0 (head-mean fused) ----
  gemm_k32hm<<<(NT + 15) / 16, 256, 0, stream>>>(obuf, l0_post_w, l0_post_b, taskh_b, NT);

  // ---- layer 1, tt ----
  gemm_bf16<<<gT, 256, 0, stream>>>(taskh_b, wt2, nullptr, nullptr, fs_b, NT, 0);
  el_er<<<nbT + nbT, 256, 0, stream>>>(fs_b, l1_tt_al, el, NT, taskh_b, w2all + 4096, er, NT);
  gat_fused<<<nbAgg, 256, 0, stream>>>(tt_offs, tt_srcs, el, er, fs_b, l1_tt_bias, nullptr, obuf, 0, NT);

  // ---- post 1 ----
  gemm_k32hm<<<(NT + 15) / 16, 256, 0, stream>>>(obuf, l1_post_w, l1_post_b, taskh_b, NT);

  // ---- decoder (relu, f32 out) ----
  gemm_bf16<<<gT, 256, 0, stream>>>(taskh_b, wt3, task_dec_b, out_task, nullptr, NT, 1);

  // ---- global pooling + projection ----
  colsum2<<<8 + (NT + 255) / 256, 256, 0, stream>>>(out_usv, out_task, g);
  global_proj<<<1, 512, 0, stream>>>(g, gp_w, gp_b, out_glob);
}

// Round 4
// 416.553 us; speedup vs baseline: 2.3923x; 1.1353x over previous
//
#include <hip/hip_runtime.h>
#include <hip/hip_bf16.h>

#define NT 20000
#define NU 2000
#define HID 256
#define HEADS 8
#define FPH 32
#define E_TT 320000
#define E_UT 100000

typedef __attribute__((ext_vector_type(8))) short s16x8;
typedef __attribute__((ext_vector_type(4))) short s16x4;
typedef __attribute__((ext_vector_type(4))) float f32x4;

__device__ inline short f2bf(float f) {
  union { float f; unsigned u; } v; v.f = f;
  unsigned r = v.u + 0x7fff + ((v.u >> 16) & 1);
  return (short)(r >> 16);
}
__device__ inline float bf2f(short s) {
  return __uint_as_float(((unsigned)(unsigned short)s) << 16);
}

// ---------------- init: zero deg arrays + g ----------------
__global__ __launch_bounds__(256) void init_zero(int* __restrict__ tt_deg,
                                                 int* __restrict__ ut_deg,
                                                 float* __restrict__ g) {
  int i = blockIdx.x * 256 + threadIdx.x;
  if (i < NT) { tt_deg[i] = 0; ut_deg[i] = 0; }
  if (i < 512) g[i] = 0.f;
}

// ------------- prep: 4x weight transpose (f32->bf16 [col][k]) + 3x w2 ---------------
__global__ __launch_bounds__(256) void prep(const float* __restrict__ w0,
                                            const float* __restrict__ w1,
                                            const float* __restrict__ w2_,
                                            const float* __restrict__ w3,
                                            short* __restrict__ o0,
                                            short* __restrict__ o1,
                                            short* __restrict__ o2,
                                            short* __restrict__ o3,
                                            const float* __restrict__ wd0,
                                            const float* __restrict__ ar0,
                                            const float* __restrict__ wd1,
                                            const float* __restrict__ ar1,
                                            const float* __restrict__ wd2,
                                            const float* __restrict__ ar2,
                                            float* __restrict__ w2all) {
  int z = blockIdx.z;
  if (z < 4) {
    __shared__ float tile[32][33];
    const float* W = (z == 0) ? w0 : (z == 1) ? w1 : (z == 2) ? w2_ : w3;
    short* Wt = (z == 0) ? o0 : (z == 1) ? o1 : (z == 2) ? o2 : o3;
    int bx = blockIdx.x, by = blockIdx.y;
    int tx = threadIdx.x & 31, ty = threadIdx.x >> 5;
#pragma unroll
    for (int i = 0; i < 32; i += 8)
      tile[ty + i][tx] = W[(by * 32 + ty + i) * 256 + bx * 32 + tx];
    __syncthreads();
#pragma unroll
    for (int i = 0; i < 32; i += 8)
      Wt[(bx * 32 + ty + i) * 256 + by * 32 + tx] = f2bf(tile[tx][ty + i]);
  } else {
    int flat = (blockIdx.y * 8 + blockIdx.x) * 256 + threadIdx.x;
    if (flat >= 3 * 2048) return;
    int e = flat >> 11, idx = flat & 2047;
    const float* wd = (e == 0) ? wd0 : (e == 1) ? wd1 : wd2;
    const float* ar = (e == 0) ? ar0 : (e == 1) ? ar1 : ar2;
    int k = idx >> 3, h = idx & 7;
    float s = 0.f;
#pragma unroll
    for (int f = 0; f < 32; ++f) s += wd[k * 256 + h * 32 + f] * ar[h * 32 + f];
    w2all[flat] = s;
  }
}

// ---------------- K=32 GEMM body ----------------
__device__ inline void k32_body(const float* __restrict__ A, const float* __restrict__ W,
                                const float* __restrict__ bias, float* __restrict__ Cf,
                                short* __restrict__ Cb, int N, int blk,
                                float* __restrict__ gsum) {
  __shared__ float Ws[32][256];
  __shared__ float Ar[16][32];
  int tid = threadIdx.x;
  for (int i = tid; i < 32 * 256; i += 256) Ws[i >> 8][i & 255] = W[i];
  int n0 = blk * 16;
  int nrows = min(16, N - n0);
  for (int i = tid; i < 512; i += 256) {
    int r = i >> 5, k = i & 31;
    if (r < nrows) Ar[r][k] = A[(size_t)(n0 + r) * 32 + k];
  }
  __syncthreads();
  float b = bias[tid];
  float colacc = 0.f;
  for (int r = 0; r < nrows; ++r) {
    float acc = b;
#pragma unroll
    for (int k = 0; k < 32; ++k) acc += Ar[r][k] * Ws[k][tid];
    size_t o = (size_t)(n0 + r) * 256 + tid;
    if (Cf) Cf[o] = acc;
    if (Cb) Cb[o] = f2bf(acc);
    colacc += acc;
  }
  if (gsum) atomicAdd(&gsum[tid], colacc);
}

// merged encoders: usv blocks then task blocks
__global__ __launch_bounds__(256) void enc_gemm(const float* __restrict__ uf,
                                                const float* __restrict__ uw,
                                                const float* __restrict__ ub,
                                                float* __restrict__ out_usv,
                                                short* __restrict__ usvh_b,
                                                const float* __restrict__ tf,
                                                const float* __restrict__ tw,
                                                const float* __restrict__ tb,
                                                short* __restrict__ taskh_b,
                                                float* __restrict__ g, int nbU) {
  int b = blockIdx.x;
  if (b < nbU)
    k32_body(uf, uw, ub, out_usv, usvh_b, NU, b, g);
  else
    k32_body(tf, tw, tb, nullptr, taskh_b, NT, b - nbU, nullptr);
}

// ---------------- fused head-mean + K=32 GEMM -> bf16 ----------------
__global__ __launch_bounds__(256) void gemm_k32hm(const float* __restrict__ obuf,
                                                  const float* __restrict__ W,
                                                  const float* __restrict__ bias,
                                                  short* __restrict__ Cb, int N) {
  __shared__ float Ws[32][256];
  __shared__ float Ar[16][32];
  int tid = threadIdx.x;
  for (int i = tid; i < 32 * 256; i += 256) Ws[i >> 8][i & 255] = W[i];
  int n0 = blockIdx.x * 16;
  for (int i = tid; i < 512; i += 256) {
    int r = i >> 5, f = i & 31;
    int n = n0 + r;
    float s = 0.f;
    if (n < N) {
#pragma unroll
      for (int h = 0; h < 8; ++h) s += obuf[(size_t)n * 256 + h * 32 + f];
    }
    Ar[r][f] = s * 0.125f;
  }
  __syncthreads();
  float b = bias[tid];
  int nrows = min(16, N - n0);
  for (int r = 0; r < nrows; ++r) {
    float acc = b;
#pragma unroll
    for (int k = 0; k < 32; ++k) acc += Ar[r][k] * Ws[k][tid];
    Cb[(size_t)(n0 + r) * 256 + tid] = f2bf(acc);
  }
}

// ------------- MFMA bf16 GEMM body: C[N,256] = A(bf16) @ Wt(bf16 [col][k]) ----------
__device__ inline void gemm_body(const short* __restrict__ A, const short* __restrict__ Wt,
                                 const float* __restrict__ bias, float* __restrict__ Cf,
                                 short* __restrict__ Cb, int N, int relu,
                                 float* __restrict__ gsum, int bx, int by) {
  __shared__ short A_lds[128][40];
  __shared__ short B_lds[128][40];
  int tid = threadIdx.x;
  int lane = tid & 63;
  int w = tid >> 6;
  int wr = w >> 1, wc = w & 1;
  int fr = lane & 15, fq = lane >> 4;
  int row0 = by * 128, col0 = bx * 128;

  f32x4 acc[4][4];
#pragma unroll
  for (int m = 0; m < 4; ++m)
#pragma unroll
    for (int n = 0; n < 4; ++n) acc[m][n] = (f32x4){0.f, 0.f, 0.f, 0.f};

  int sr = tid >> 1, half = tid & 1;

  for (int k0 = 0; k0 < 256; k0 += 32) {
    int grow = row0 + sr;
    s16x8 a0 = (s16x8){0,0,0,0,0,0,0,0}, a1 = a0;
    if (grow < N) {
      const s16x8* ap = (const s16x8*)(A + (size_t)grow * 256 + k0 + half * 16);
      a0 = ap[0]; a1 = ap[1];
    }
    s16x8* da = (s16x8*)&A_lds[sr][half * 16];
    da[0] = a0; da[1] = a1;
    const s16x8* bp = (const s16x8*)(Wt + (size_t)(col0 + sr) * 256 + k0 + half * 16);
    s16x8* db = (s16x8*)&B_lds[sr][half * 16];
    db[0] = bp[0]; db[1] = bp[1];
    __syncthreads();
    s16x8 af[4], bf[4];
#pragma unroll
    for (int m = 0; m < 4; ++m) af[m] = *(s16x8*)&A_lds[wr * 64 + m * 16 + fr][fq * 8];
#pragma unroll
    for (int n = 0; n < 4; ++n) bf[n] = *(s16x8*)&B_lds[wc * 64 + n * 16 + fr][fq * 8];
#pragma unroll
    for (int m = 0; m < 4; ++m)
#pragma unroll
      for (int n = 0; n < 4; ++n)
        acc[m][n] = __builtin_amdgcn_mfma_f32_16x16x32_bf16(af[m], bf[n], acc[m][n], 0, 0, 0);
    __syncthreads();
  }

  float csum[4] = {0.f, 0.f, 0.f, 0.f};
#pragma unroll
  for (int m = 0; m < 4; ++m) {
    int gr = row0 + wr * 64 + m * 16 + fq * 4;
#pragma unroll
    for (int r = 0; r < 4; ++r) {
      if (gr + r >= N) continue;
#pragma unroll
      for (int n = 0; n < 4; ++n) {
        int gc = col0 + wc * 64 + n * 16 + fr;
        float v = acc[m][n][r];
        if (bias) v += bias[gc];
        if (relu) v = fmaxf(v, 0.f);
        size_t o = (size_t)(gr + r) * 256 + gc;
        if (Cf) Cf[o] = v;
        if (Cb) Cb[o] = f2bf(v);
        csum[n] += v;
      }
    }
  }
  if (gsum) {
#pragma unroll
    for (int n = 0; n < 4; ++n) {
      float s = csum[n];
      s += __shfl_xor(s, 16);
      s += __shfl_xor(s, 32);
      if (fq == 0) atomicAdd(&gsum[col0 + wc * 64 + n * 16 + fr], s);
    }
  }
}

__global__ __launch_bounds__(256) void gemm_bf16(const short* __restrict__ A,
                                                 const short* __restrict__ Wt,
                                                 const float* __restrict__ bias,
                                                 float* __restrict__ Cf,
                                                 short* __restrict__ Cb,
                                                 int N, int relu, float* __restrict__ gsum) {
  gemm_body(A, Wt, bias, Cf, Cb, N, relu, gsum, blockIdx.x, blockIdx.y);
}

// layer-0 dual: tt rows (by < nbyTT) then ut rows
__global__ __launch_bounds__(256) void gemm_bf16_dual(const short* __restrict__ A0,
                                                      const short* __restrict__ Wt0,
                                                      short* __restrict__ C0,
                                                      const short* __restrict__ A1,
                                                      const short* __restrict__ Wt1,
                                                      short* __restrict__ C1,
                                                      int nbyTT) {
  if ((int)blockIdx.y < nbyTT)
    gemm_body(A0, Wt0, nullptr, nullptr, C0, NT, 0, nullptr, blockIdx.x, blockIdx.y);
  else
    gemm_body(A1, Wt1, nullptr, nullptr, C1, NU, 0, nullptr, blockIdx.x, blockIdx.y - nbyTT);
}

// ---------------- el/er multi-job kernel ----------------
struct EJob { const short* x; const float* w; float* o; int n; int type; };

__device__ inline void ej_run(const EJob& jb, int rel) {
  int idx = rel * 256 + (int)threadIdx.x;
  if (idx >= jb.n * 8) return;
  int n = idx >> 3, h = idx & 7;
  if (jb.type == 0) {
    const s16x8* p = (const s16x8*)(jb.x + (size_t)n * 256 + h * 32);
    const float* alh = jb.w + h * 32;
    float s = 0.f;
#pragma unroll
    for (int q = 0; q < 4; ++q) {
      s16x8 v = p[q];
#pragma unroll
      for (int j = 0; j < 8; ++j) s += bf2f(v[j]) * alh[q * 8 + j];
    }
    jb.o[idx] = s;
  } else {
    const s16x8* p = (const s16x8*)(jb.x + (size_t)n * 256);
    float s = 0.f;
#pragma unroll 4
    for (int q = 0; q < 32; ++q) {
      s16x8 v = p[q];
#pragma unroll
      for (int j = 0; j < 8; ++j) s += bf2f(v[j]) * jb.w[(q * 8 + j) * 8 + h];
    }
    jb.o[idx] = s;
  }
}

__global__ __launch_bounds__(256) void el_er_multi(EJob j0, EJob j1, EJob j2, EJob j3,
                                                   int b0, int b1, int b2, int b3) {
  int b = blockIdx.x;
  if (b < b0) { ej_run(j0, b); return; }
  b -= b0;
  if (b < b1) { ej_run(j1, b); return; }
  b -= b1;
  if (b < b2) { ej_run(j2, b); return; }
  b -= b2;
  ej_run(j3, b);
}

// ---------------- batched CSR build ----------------
__global__ void deg2(const int* __restrict__ tt_dst, const int* __restrict__ ut_dst,
                     int* __restrict__ tt_deg, int* __restrict__ ut_deg) {
  int e = blockIdx.x * 256 + threadIdx.x;
  if (e < E_TT) atomicAdd(&tt_deg[tt_dst[e]], 1);
  int e2 = e - E_TT;
  if (e2 >= 0 && e2 < E_UT) atomicAdd(&ut_deg[ut_dst[e2]], 1);
}

__global__ __launch_bounds__(1024) void scan2(const int* __restrict__ d0, int* __restrict__ o0,
                                              int* __restrict__ c0,
                                              const int* __restrict__ d1, int* __restrict__ o1,
                                              int* __restrict__ c1, int n) {
  const int* deg = blockIdx.x ? d1 : d0;
  int* off = blockIdx.x ? o1 : o0;
  int* cursor = blockIdx.x ? c1 : c0;
  int tid = threadIdx.x;
  const int C = 20;
  int base = tid * C;
  int local[C];
  int s = 0;
#pragma unroll
  for (int i = 0; i < C; ++i) {
    int idx = base + i;
    int v = (idx < n) ? deg[idx] : 0;
    local[i] = s;
    s += v;
  }
  int lane = tid & 63, wave = tid >> 6;
  int x = s;
#pragma unroll
  for (int d = 1; d < 64; d <<= 1) {
    int y = __shfl_up(x, d, 64);
    if (lane >= d) x += y;
  }
  __shared__ int wsum[16];
  if (lane == 63) wsum[wave] = x;
  __syncthreads();
  if (wave == 0) {
    int wv = (lane < 16) ? wsum[lane] : 0;
#pragma unroll
    for (int d = 1; d < 16; d <<= 1) {
      int y = __shfl_up(wv, d, 64);
      if (lane >= d) wv += y;
    }
    if (lane < 16) wsum[lane] = wv;
  }
  __syncthreads();
  int waveoff = (wave == 0) ? 0 : wsum[wave - 1];
  int excl = waveoff + x - s;
#pragma unroll
  for (int i = 0; i < C; ++i) {
    int idx = base + i;
    if (idx < n) {
      int o = excl + local[i];
      off[idx] = o;
      cursor[idx] = o;
    }
  }
  if (tid == 1023) off[n] = waveoff + x;
}

__global__ void scat2(const int* __restrict__ tt_src, const int* __restrict__ tt_dst,
                      int* __restrict__ tt_cur, int* __restrict__ tt_srcs,
                      const int* __restrict__ ut_src, const int* __restrict__ ut_dst,
                      int* __restrict__ ut_cur, int* __restrict__ ut_srcs) {
  int e = blockIdx.x * 256 + threadIdx.x;
  if (e < E_TT) {
    int p = atomicAdd(&tt_cur[tt_dst[e]], 1);
    tt_srcs[p] = tt_src[e];
  }
  int e2 = e - E_TT;
  if (e2 >= 0 && e2 < E_UT) {
    int p = atomicAdd(&ut_cur[ut_dst[e2]], 1);
    ut_srcs[p] = ut_src[e2];
  }
}

// ---------------- fused softmax + aggregation, one wave per dst node ----------------
__global__ __launch_bounds__(256) void gat_fused(const int* __restrict__ offs,
                                                 const int* __restrict__ srcs,
                                                 const float* __restrict__ el,
                                                 const float* __restrict__ er,
                                                 const short* __restrict__ fsb,
                                                 const float* __restrict__ bias0,
                                                 const float* __restrict__ bias1,
                                                 float* __restrict__ out,
                                                 int accum, int ndst) {
  int wv = threadIdx.x >> 6, lane = threadIdx.x & 63;
  int n = blockIdx.x * 4 + wv;
  if (n >= ndst) return;
  int e0 = offs[n], e1 = offs[n + 1];
  float4* po = (float4*)(out + (size_t)n * 256 + lane * 4);
  if (e0 == e1) {
    if (!accum) {
      float4 b = *(const float4*)(bias0 + lane * 4);
      if (bias1) {
        float4 b1 = *(const float4*)(bias1 + lane * 4);
        b.x += b1.x; b.y += b1.y; b.z += b1.z; b.w += b1.w;
      }
      *po = b;
    }
    return;
  }
  // phase 1: per-head max & sum (lane = slot*8 + h)
  int h1 = lane & 7, slot = lane >> 3;
  float ern1 = er[n * 8 + h1];
  float m = -3.4e38f;
  for (int i = e0 + slot; i < e1; i += 8) {
    float l = el[srcs[i] * 8 + h1] + ern1;
    l = l >= 0.f ? l : 0.2f * l;
    m = fmaxf(m, l);
  }
  m = fmaxf(m, __shfl_xor(m, 8));
  m = fmaxf(m, __shfl_xor(m, 16));
  m = fmaxf(m, __shfl_xor(m, 32));
  float s = 0.f;
  for (int i = e0 + slot; i < e1; i += 8) {
    float l = el[srcs[i] * 8 + h1] + ern1;
    l = l >= 0.f ? l : 0.2f * l;
    s += __expf(l - m);
  }
  s += __shfl_xor(s, 8);
  s += __shfl_xor(s, 16);
  s += __shfl_xor(s, 32);
  // phase 2: aggregate; lane owns elements 4*lane..4*lane+3 (head = lane>>3)
  int h2 = lane >> 3;
  float mh = __shfl(m, h2);
  float sh = __shfl(s, h2);
  float ern2 = __shfl(ern1, h2);
  float ax = 0.f, ay = 0.f, az = 0.f, aw = 0.f;
  for (int i = e0; i < e1; ++i) {
    int src = srcs[i];
    float l = el[src * 8 + h2] + ern2;
    l = l >= 0.f ? l : 0.2f * l;
    float wgt = __expf(l - mh);
    s16x4 v = *(const s16x4*)(fsb + (size_t)src * 256 + lane * 4);
    ax += wgt * bf2f(v[0]);
    ay += wgt * bf2f(v[1]);
    az += wgt * bf2f(v[2]);
    aw += wgt * bf2f(v[3]);
  }
  float sinv = 1.f / sh;
  float4 o = {ax * sinv, ay * sinv, az * sinv, aw * sinv};
  if (accum) {
    float4 p = *po;
    o.x += p.x; o.y += p.y; o.z += p.z; o.w += p.w;
    *po = o;
  } else {
    float4 b = *(const float4*)(bias0 + lane * 4);
    o.x += b.x; o.y += b.y; o.z += b.z; o.w += b.w;
    if (bias1) {
      float4 b1 = *(const float4*)(bias1 + lane * 4);
      o.x += b1.x; o.y += b1.y; o.z += b1.z; o.w += b1.w;
    }
    *po = o;
  }
}

// ---------------- global projection (with mean scaling) ----------------
__global__ __launch_bounds__(512) void global_proj(const float* __restrict__ g,
                                                   const float* __restrict__ W,
                                                   const float* __restrict__ b,
                                                   float* __restrict__ out) {
  __shared__ float gl[512];
  int tid = threadIdx.x;
  gl[tid] = g[tid] * (tid < 256 ? (1.f / NU) : (1.f / NT));
  __syncthreads();
  float s = b[tid];
  for (int k = 0; k < 512; ++k) s += gl[k] * W[k * 512 + tid];
  out[tid] = s;
}

extern "C" void kernel_launch(void* const* d_in, const int* in_sizes, int n_in,
                              void* d_out, int out_size, void* d_ws, size_t ws_size,
                              hipStream_t stream) {
  const float* usv_feat   = (const float*)d_in[0];
  const float* task_feat  = (const float*)d_in[1];
  const float* usv_enc_w  = (const float*)d_in[2];
  const float* usv_enc_b  = (const float*)d_in[3];
  const float* task_enc_w = (const float*)d_in[4];
  const float* task_enc_b = (const float*)d_in[5];
  const float* l0_tt_wsrc = (const float*)d_in[6];
  const float* l0_tt_wdst = (const float*)d_in[7];
  const float* l0_tt_al   = (const float*)d_in[8];
  const float* l0_tt_ar   = (const float*)d_in[9];
  const float* l0_tt_bias = (const float*)d_in[10];
  const float* l0_ut_wsrc = (const float*)d_in[11];
  const float* l0_ut_wdst = (const float*)d_in[12];
  const float* l0_ut_al   = (const float*)d_in[13];
  const float* l0_ut_ar   = (const float*)d_in[14];
  const float* l0_ut_bias = (const float*)d_in[15];
  const float* l0_post_w  = (const float*)d_in[16];
  const float* l0_post_b  = (const float*)d_in[17];
  const float* l1_tt_wsrc = (const float*)d_in[18];
  const float* l1_tt_wdst = (const float*)d_in[19];
  const float* l1_tt_al   = (const float*)d_in[20];
  const float* l1_tt_ar   = (const float*)d_in[21];
  const float* l1_tt_bias = (const float*)d_in[22];
  const float* l1_post_w  = (const float*)d_in[23];
  const float* l1_post_b  = (const float*)d_in[24];
  const float* task_dec_w = (const float*)d_in[25];
  const float* task_dec_b = (const float*)d_in[26];
  const float* gp_w       = (const float*)d_in[27];
  const float* gp_b       = (const float*)d_in[28];
  const int* tt_src = (const int*)d_in[29];
  const int* tt_dst = (const int*)d_in[30];
  const int* ut_src = (const int*)d_in[31];
  const int* ut_dst = (const int*)d_in[32];

  float* out = (float*)d_out;
  float* out_usv  = out;
  float* out_task = out + NU * HID;
  float* out_glob = out + NU * HID + NT * HID;

  char* ws = (char*)d_ws;
  size_t off = 0;
  auto alloc_f = [&](size_t n) {
    float* p = (float*)(ws + off);
    off += ((n * 4 + 1023) / 1024) * 1024;
    return p;
  };
  auto alloc_i = [&](size_t n) {
    int* p = (int*)(ws + off);
    off += ((n * 4 + 1023) / 1024) * 1024;
    return p;
  };
  auto alloc_s = [&](size_t n) {
    short* p = (short*)(ws + off);
    off += ((n * 2 + 1023) / 1024) * 1024;
    return p;
  };
  short* taskh_b = alloc_s((size_t)NT * HID);
  short* usvh_b  = alloc_s((size_t)NU * HID);
  short* fs_b    = alloc_s((size_t)NT * HID);
  short* fsu_b   = alloc_s((size_t)NU * HID);
  float* obuf  = alloc_f((size_t)NT * HID);
  float* el    = alloc_f((size_t)NT * HEADS);
  float* er    = alloc_f((size_t)NT * HEADS);
  float* el2   = alloc_f((size_t)NU * HEADS);
  float* er2   = alloc_f((size_t)NT * HEADS);
  float* w2all = alloc_f(3 * 2048);
  float* g     = alloc_f(512);
  short* wt0 = alloc_s(256 * 256);
  short* wt1 = alloc_s(256 * 256);
  short* wt2 = alloc_s(256 * 256);
  short* wt3 = alloc_s(256 * 256);
  int* tt_deg  = alloc_i(NT);
  int* tt_offs = alloc_i(NT + 1);
  int* tt_cur  = alloc_i(NT);
  int* tt_srcs = alloc_i(E_TT);
  int* ut_deg  = alloc_i(NT);
  int* ut_offs = alloc_i(NT + 1);
  int* ut_cur  = alloc_i(NT);
  int* ut_srcs = alloc_i(E_UT);

  init_zero<<<(NT + 255) / 256, 256, 0, stream>>>(tt_deg, ut_deg, g);

  prep<<<dim3(8, 8, 5), 256, 0, stream>>>(l0_tt_wsrc, l0_ut_wsrc, l1_tt_wsrc, task_dec_w,
                                          wt0, wt1, wt2, wt3,
                                          l0_tt_wdst, l0_tt_ar, l0_ut_wdst, l0_ut_ar,
                                          l1_tt_wdst, l1_tt_ar, w2all);

  // encoders (merged; usv part also accumulates raw column sums into g[0:256])
  int nbU16 = (NU + 15) / 16, nbT16 = (NT + 15) / 16;
  enc_gemm<<<nbU16 + nbT16, 256, 0, stream>>>(usv_feat, usv_enc_w, usv_enc_b, out_usv, usvh_b,
                                              task_feat, task_enc_w, task_enc_b, taskh_b,
                                              g, nbU16);

  // CSR build (batched over both graphs)
  int nbE = (E_TT + E_UT + 255) / 256;
  deg2<<<nbE, 256, 0, stream>>>(tt_dst, ut_dst, tt_deg, ut_deg);
  scan2<<<2, 1024, 0, stream>>>(tt_deg, tt_offs, tt_cur, ut_deg, ut_offs, ut_cur, NT);
  scat2<<<nbE, 256, 0, stream>>>(tt_src, tt_dst, tt_cur, tt_srcs, ut_src, ut_dst, ut_cur, ut_srcs);

  int nbyT = (NT + 127) / 128, nbyU = (NU + 127) / 128;
  int nbT = (NT * 8 + 255) / 256;
  int nbU = (NU * 8 + 255) / 256;
  int nbAgg = (NT + 3) / 4;

  // ---- layer 0: both GEMMs in one launch ----
  gemm_bf16_dual<<<dim3(2, nbyT + nbyU), 256, 0, stream>>>(taskh_b, wt0, fs_b,
                                                           usvh_b, wt1, fsu_b, nbyT);
  {
    EJob jel  = {fs_b, l0_tt_al, el, NT, 0};
    EJob jer  = {taskh_b, w2all, er, NT, 1};
    EJob jel2 = {fsu_b, l0_ut_al, el2, NU, 0};
    EJob jer2 = {taskh_b, w2all + 2048, er2, NT, 1};
    el_er_multi<<<nbT + nbT + nbU + nbT, 256, 0, stream>>>(jel, jer, jel2, jer2,
                                                           nbT, nbT, nbU, nbT);
  }
  gat_fused<<<nbAgg, 256, 0, stream>>>(tt_offs, tt_srcs, el, er, fs_b, l0_tt_bias, l0_ut_bias, obuf, 0, NT);
  gat_fused<<<nbAgg, 256, 0, stream>>>(ut_offs, ut_srcs, el2, er2, fsu_b, nullptr, nullptr, obuf, 1, NT);

  // ---- post 0 (head-mean fused) ----
  gemm_k32hm<<<nbT16, 256, 0, stream>>>(obuf, l0_post_w, l0_post_b, taskh_b, NT);

  // ---- layer 1, tt ----
  gemm_bf16<<<dim3(2, nbyT), 256, 0, stream>>>(taskh_b, wt2, nullptr, nullptr, fs_b, NT, 0, nullptr);
  {
    EJob jel = {fs_b, l1_tt_al, el, NT, 0};
    EJob jer = {taskh_b, w2all + 4096, er, NT, 1};
    el_er_multi<<<nbT + nbT, 256, 0, stream>>>(jel, jer, jel, jel, nbT, nbT, 0, 0);
  }
  gat_fused<<<nbAgg, 256, 0, stream>>>(tt_offs, tt_srcs, el, er, fs_b, l1_tt_bias, nullptr, obuf, 0, NT);

  // ---- post 1 ----
  gemm_k32hm<<<nbT16, 256, 0, stream>>>(obuf, l1_post_w, l1_post_b, taskh_b, NT);

  // ---- decoder (relu, f32 out, fused task column sums into g[256:512]) ----
  gemm_bf16<<<dim3(2, nbyT), 256, 0, stream>>>(taskh_b, wt3, task_dec_b, out_task, nullptr, NT, 1, g + 256);

  // ---- global projection (applies 1/NU, 1/NT) ----
  global_proj<<<1, 512, 0, stream>>>(g, gp_w, gp_b, out_glob);
}

// Round 5
// 369.960 us; speedup vs baseline: 2.6936x; 1.1259x over previous
//
#include <hip/hip_runtime.h>
#include <hip/hip_bf16.h>

#define NT 20000
#define NU 2000
#define HID 256
#define HEADS 8
#define FPH 32
#define E_TT 320000
#define E_UT 100000
#define CAP 80

typedef __attribute__((ext_vector_type(8))) short s16x8;
typedef __attribute__((ext_vector_type(4))) short s16x4;
typedef __attribute__((ext_vector_type(4))) float f32x4;

__device__ inline short f2bf(float f) {
  union { float f; unsigned u; } v; v.f = f;
  unsigned r = v.u + 0x7fff + ((v.u >> 16) & 1);
  return (short)(r >> 16);
}
__device__ inline float bf2f(short s) {
  return __uint_as_float(((unsigned)(unsigned short)s) << 16);
}

// ---------------- init: zero deg arrays + g ----------------
__global__ __launch_bounds__(256) void init_zero(int* __restrict__ tt_deg,
                                                 int* __restrict__ ut_deg,
                                                 float* __restrict__ g) {
  int i = blockIdx.x * 256 + threadIdx.x;
  if (i < NT) { tt_deg[i] = 0; ut_deg[i] = 0; }
  if (i < 512) g[i] = 0.f;
}

// ------------- prep: 4x weight transpose (f32->bf16 [col][k]) + 3x w2 ---------------
__global__ __launch_bounds__(256) void prep(const float* __restrict__ w0,
                                            const float* __restrict__ w1,
                                            const float* __restrict__ w2_,
                                            const float* __restrict__ w3,
                                            short* __restrict__ o0,
                                            short* __restrict__ o1,
                                            short* __restrict__ o2,
                                            short* __restrict__ o3,
                                            const float* __restrict__ wd0,
                                            const float* __restrict__ ar0,
                                            const float* __restrict__ wd1,
                                            const float* __restrict__ ar1,
                                            const float* __restrict__ wd2,
                                            const float* __restrict__ ar2,
                                            float* __restrict__ w2all) {
  int z = blockIdx.z;
  if (z < 4) {
    __shared__ float tile[32][33];
    const float* W = (z == 0) ? w0 : (z == 1) ? w1 : (z == 2) ? w2_ : w3;
    short* Wt = (z == 0) ? o0 : (z == 1) ? o1 : (z == 2) ? o2 : o3;
    int bx = blockIdx.x, by = blockIdx.y;
    int tx = threadIdx.x & 31, ty = threadIdx.x >> 5;
#pragma unroll
    for (int i = 0; i < 32; i += 8)
      tile[ty + i][tx] = W[(by * 32 + ty + i) * 256 + bx * 32 + tx];
    __syncthreads();
#pragma unroll
    for (int i = 0; i < 32; i += 8)
      Wt[(bx * 32 + ty + i) * 256 + by * 32 + tx] = f2bf(tile[tx][ty + i]);
  } else {
    int flat = (blockIdx.y * 8 + blockIdx.x) * 256 + threadIdx.x;
    if (flat >= 3 * 2048) return;
    int e = flat >> 11, idx = flat & 2047;
    const float* wd = (e == 0) ? wd0 : (e == 1) ? wd1 : wd2;
    const float* ar = (e == 0) ? ar0 : (e == 1) ? ar1 : ar2;
    int k = idx >> 3, h = idx & 7;
    float s = 0.f;
#pragma unroll
    for (int f = 0; f < 32; ++f) s += wd[k * 256 + h * 32 + f] * ar[h * 32 + f];
    w2all[flat] = s;
  }
}

// ---------------- K=32 GEMM body ----------------
__device__ inline void k32_body(const float* __restrict__ A, const float* __restrict__ W,
                                const float* __restrict__ bias, float* __restrict__ Cf,
                                short* __restrict__ Cb, int N, int blk,
                                float* __restrict__ gsum) {
  __shared__ float Ws[32][256];
  __shared__ float Ar[16][32];
  int tid = threadIdx.x;
  for (int i = tid; i < 32 * 256; i += 256) Ws[i >> 8][i & 255] = W[i];
  int n0 = blk * 16;
  int nrows = min(16, N - n0);
  for (int i = tid; i < 512; i += 256) {
    int r = i >> 5, k = i & 31;
    if (r < nrows) Ar[r][k] = A[(size_t)(n0 + r) * 32 + k];
  }
  __syncthreads();
  float b = bias[tid];
  float colacc = 0.f;
  for (int r = 0; r < nrows; ++r) {
    float acc = b;
#pragma unroll
    for (int k = 0; k < 32; ++k) acc += Ar[r][k] * Ws[k][tid];
    size_t o = (size_t)(n0 + r) * 256 + tid;
    if (Cf) Cf[o] = acc;
    if (Cb) Cb[o] = f2bf(acc);
    colacc += acc;
  }
  if (gsum) atomicAdd(&gsum[tid], colacc);
}

// merged encoders: usv blocks then task blocks
__global__ __launch_bounds__(256) void enc_gemm(const float* __restrict__ uf,
                                                const float* __restrict__ uw,
                                                const float* __restrict__ ub,
                                                float* __restrict__ out_usv,
                                                short* __restrict__ usvh_b,
                                                const float* __restrict__ tf,
                                                const float* __restrict__ tw,
                                                const float* __restrict__ tb,
                                                short* __restrict__ taskh_b,
                                                float* __restrict__ g, int nbU) {
  int b = blockIdx.x;
  if (b < nbU)
    k32_body(uf, uw, ub, out_usv, usvh_b, NU, b, g);
  else
    k32_body(tf, tw, tb, nullptr, taskh_b, NT, b - nbU, nullptr);
}

// ---------------- fused head-mean + K=32 GEMM -> bf16 (optional second obuf) --------
__global__ __launch_bounds__(256) void gemm_k32hm(const float* __restrict__ obuf,
                                                  const float* __restrict__ obuf2,
                                                  const float* __restrict__ W,
                                                  const float* __restrict__ bias,
                                                  short* __restrict__ Cb, int N) {
  __shared__ float Ws[32][256];
  __shared__ float Ar[16][32];
  int tid = threadIdx.x;
  for (int i = tid; i < 32 * 256; i += 256) Ws[i >> 8][i & 255] = W[i];
  int n0 = blockIdx.x * 16;
  for (int i = tid; i < 512; i += 256) {
    int r = i >> 5, f = i & 31;
    int n = n0 + r;
    float s = 0.f;
    if (n < N) {
#pragma unroll
      for (int h = 0; h < 8; ++h) s += obuf[(size_t)n * 256 + h * 32 + f];
      if (obuf2) {
#pragma unroll
        for (int h = 0; h < 8; ++h) s += obuf2[(size_t)n * 256 + h * 32 + f];
      }
    }
    Ar[r][f] = s * 0.125f;
  }
  __syncthreads();
  float b = bias[tid];
  int nrows = min(16, N - n0);
  for (int r = 0; r < nrows; ++r) {
    float acc = b;
#pragma unroll
    for (int k = 0; k < 32; ++k) acc += Ar[r][k] * Ws[k][tid];
    Cb[(size_t)(n0 + r) * 256 + tid] = f2bf(acc);
  }
}

// ------------- MFMA bf16 GEMM body: C[N,256] = A(bf16) @ Wt(bf16 [col][k]) ----------
__device__ inline void gemm_body(const short* __restrict__ A, const short* __restrict__ Wt,
                                 const float* __restrict__ bias, float* __restrict__ Cf,
                                 short* __restrict__ Cb, int N, int relu,
                                 float* __restrict__ gsum, int bx, int by) {
  __shared__ short A_lds[128][40];
  __shared__ short B_lds[128][40];
  int tid = threadIdx.x;
  int lane = tid & 63;
  int w = tid >> 6;
  int wr = w >> 1, wc = w & 1;
  int fr = lane & 15, fq = lane >> 4;
  int row0 = by * 128, col0 = bx * 128;

  f32x4 acc[4][4];
#pragma unroll
  for (int m = 0; m < 4; ++m)
#pragma unroll
    for (int n = 0; n < 4; ++n) acc[m][n] = (f32x4){0.f, 0.f, 0.f, 0.f};

  int sr = tid >> 1, half = tid & 1;

  for (int k0 = 0; k0 < 256; k0 += 32) {
    int grow = row0 + sr;
    s16x8 a0 = (s16x8){0,0,0,0,0,0,0,0}, a1 = a0;
    if (grow < N) {
      const s16x8* ap = (const s16x8*)(A + (size_t)grow * 256 + k0 + half * 16);
      a0 = ap[0]; a1 = ap[1];
    }
    s16x8* da = (s16x8*)&A_lds[sr][half * 16];
    da[0] = a0; da[1] = a1;
    const s16x8* bp = (const s16x8*)(Wt + (size_t)(col0 + sr) * 256 + k0 + half * 16);
    s16x8* db = (s16x8*)&B_lds[sr][half * 16];
    db[0] = bp[0]; db[1] = bp[1];
    __syncthreads();
    s16x8 af[4], bf[4];
#pragma unroll
    for (int m = 0; m < 4; ++m) af[m] = *(s16x8*)&A_lds[wr * 64 + m * 16 + fr][fq * 8];
#pragma unroll
    for (int n = 0; n < 4; ++n) bf[n] = *(s16x8*)&B_lds[wc * 64 + n * 16 + fr][fq * 8];
#pragma unroll
    for (int m = 0; m < 4; ++m)
#pragma unroll
      for (int n = 0; n < 4; ++n)
        acc[m][n] = __builtin_amdgcn_mfma_f32_16x16x32_bf16(af[m], bf[n], acc[m][n], 0, 0, 0);
    __syncthreads();
  }

  float csum[4] = {0.f, 0.f, 0.f, 0.f};
#pragma unroll
  for (int m = 0; m < 4; ++m) {
    int gr = row0 + wr * 64 + m * 16 + fq * 4;
#pragma unroll
    for (int r = 0; r < 4; ++r) {
      if (gr + r >= N) continue;
#pragma unroll
      for (int n = 0; n < 4; ++n) {
        int gc = col0 + wc * 64 + n * 16 + fr;
        float v = acc[m][n][r];
        if (bias) v += bias[gc];
        if (relu) v = fmaxf(v, 0.f);
        size_t o = (size_t)(gr + r) * 256 + gc;
        if (Cf) Cf[o] = v;
        if (Cb) Cb[o] = f2bf(v);
        csum[n] += v;
      }
    }
  }
  if (gsum) {
#pragma unroll
    for (int n = 0; n < 4; ++n) {
      float s = csum[n];
      s += __shfl_xor(s, 16);
      s += __shfl_xor(s, 32);
      if (fq == 0) atomicAdd(&gsum[col0 + wc * 64 + n * 16 + fr], s);
    }
  }
}

__global__ __launch_bounds__(256) void gemm_bf16(const short* __restrict__ A,
                                                 const short* __restrict__ Wt,
                                                 const float* __restrict__ bias,
                                                 float* __restrict__ Cf,
                                                 short* __restrict__ Cb,
                                                 int N, int relu, float* __restrict__ gsum) {
  gemm_body(A, Wt, bias, Cf, Cb, N, relu, gsum, blockIdx.x, blockIdx.y);
}

// layer-0 dual: tt rows (by < nbyTT) then ut rows
__global__ __launch_bounds__(256) void gemm_bf16_dual(const short* __restrict__ A0,
                                                      const short* __restrict__ Wt0,
                                                      short* __restrict__ C0,
                                                      const short* __restrict__ A1,
                                                      const short* __restrict__ Wt1,
                                                      short* __restrict__ C1,
                                                      int nbyTT) {
  if ((int)blockIdx.y < nbyTT)
    gemm_body(A0, Wt0, nullptr, nullptr, C0, NT, 0, nullptr, blockIdx.x, blockIdx.y);
  else
    gemm_body(A1, Wt1, nullptr, nullptr, C1, NU, 0, nullptr, blockIdx.x, blockIdx.y - nbyTT);
}

// ---------------- el/er multi-job kernel ----------------
struct EJob { const short* x; const float* w; float* o; int n; int type; };

__device__ inline void ej_run(const EJob& jb, int rel) {
  int idx = rel * 256 + (int)threadIdx.x;
  if (idx >= jb.n * 8) return;
  int n = idx >> 3, h = idx & 7;
  if (jb.type == 0) {
    const s16x8* p = (const s16x8*)(jb.x + (size_t)n * 256 + h * 32);
    const float* alh = jb.w + h * 32;
    float s = 0.f;
#pragma unroll
    for (int q = 0; q < 4; ++q) {
      s16x8 v = p[q];
#pragma unroll
      for (int j = 0; j < 8; ++j) s += bf2f(v[j]) * alh[q * 8 + j];
    }
    jb.o[idx] = s;
  } else {
    const s16x8* p = (const s16x8*)(jb.x + (size_t)n * 256);
    float s = 0.f;
#pragma unroll 4
    for (int q = 0; q < 32; ++q) {
      s16x8 v = p[q];
#pragma unroll
      for (int j = 0; j < 8; ++j) s += bf2f(v[j]) * jb.w[(q * 8 + j) * 8 + h];
    }
    jb.o[idx] = s;
  }
}

__global__ __launch_bounds__(256) void el_er_multi(EJob j0, EJob j1, EJob j2, EJob j3,
                                                   int b0, int b1, int b2, int b3) {
  int b = blockIdx.x;
  if (b < b0) { ej_run(j0, b); return; }
  b -= b0;
  if (b < b1) { ej_run(j1, b); return; }
  b -= b1;
  if (b < b2) { ej_run(j2, b); return; }
  b -= b2;
  ej_run(j3, b);
}

// ---------------- batched CSR build ----------------
__global__ void deg2(const int* __restrict__ tt_dst, const int* __restrict__ ut_dst,
                     int* __restrict__ tt_deg, int* __restrict__ ut_deg) {
  int e = blockIdx.x * 256 + threadIdx.x;
  if (e < E_TT) atomicAdd(&tt_deg[tt_dst[e]], 1);
  int e2 = e - E_TT;
  if (e2 >= 0 && e2 < E_UT) atomicAdd(&ut_deg[ut_dst[e2]], 1);
}

__global__ __launch_bounds__(1024) void scan2(const int* __restrict__ d0, int* __restrict__ o0,
                                              int* __restrict__ c0,
                                              const int* __restrict__ d1, int* __restrict__ o1,
                                              int* __restrict__ c1, int n) {
  const int* deg = blockIdx.x ? d1 : d0;
  int* off = blockIdx.x ? o1 : o0;
  int* cursor = blockIdx.x ? c1 : c0;
  int tid = threadIdx.x;
  const int C = 20;
  int base = tid * C;
  int local[C];
  int s = 0;
#pragma unroll
  for (int i = 0; i < C; ++i) {
    int idx = base + i;
    int v = (idx < n) ? deg[idx] : 0;
    local[i] = s;
    s += v;
  }
  int lane = tid & 63, wave = tid >> 6;
  int x = s;
#pragma unroll
  for (int d = 1; d < 64; d <<= 1) {
    int y = __shfl_up(x, d, 64);
    if (lane >= d) x += y;
  }
  __shared__ int wsum[16];
  if (lane == 63) wsum[wave] = x;
  __syncthreads();
  if (wave == 0) {
    int wv = (lane < 16) ? wsum[lane] : 0;
#pragma unroll
    for (int d = 1; d < 16; d <<= 1) {
      int y = __shfl_up(wv, d, 64);
      if (lane >= d) wv += y;
    }
    if (lane < 16) wsum[lane] = wv;
  }
  __syncthreads();
  int waveoff = (wave == 0) ? 0 : wsum[wave - 1];
  int excl = waveoff + x - s;
#pragma unroll
  for (int i = 0; i < C; ++i) {
    int idx = base + i;
    if (idx < n) {
      int o = excl + local[i];
      off[idx] = o;
      cursor[idx] = o;
    }
  }
  if (tid == 1023) off[n] = waveoff + x;
}

__global__ void scat2(const int* __restrict__ tt_src, const int* __restrict__ tt_dst,
                      int* __restrict__ tt_cur, int* __restrict__ tt_srcs,
                      const int* __restrict__ ut_src, const int* __restrict__ ut_dst,
                      int* __restrict__ ut_cur, int* __restrict__ ut_srcs) {
  int e = blockIdx.x * 256 + threadIdx.x;
  if (e < E_TT) {
    int p = atomicAdd(&tt_cur[tt_dst[e]], 1);
    tt_srcs[p] = tt_src[e];
  }
  int e2 = e - E_TT;
  if (e2 >= 0 && e2 < E_UT) {
    int p = atomicAdd(&ut_cur[ut_dst[e2]], 1);
    ut_srcs[p] = ut_src[e2];
  }
}

// -------- fused softmax + aggregation, wave/node, LDS-cached weights, 4x unroll -----
__device__ inline float gat_w(const float* __restrict__ el, int src, int h,
                              float ern, float mh) {
  float l = el[src * 8 + h] + ern;
  l = l >= 0.f ? l : 0.2f * l;
  return __expf(l - mh);
}

__device__ inline void gat_body(const int* __restrict__ offs, const int* __restrict__ srcs,
                                const float* __restrict__ el, const float* __restrict__ er,
                                const short* __restrict__ fsb,
                                const float* __restrict__ bias0,
                                const float* __restrict__ bias1,
                                float* __restrict__ out, int n, float (*wl)[8]) {
  int lane = threadIdx.x & 63;
  int e0 = offs[n], e1 = offs[n + 1];
  float4* po = (float4*)(out + (size_t)n * 256 + lane * 4);
  if (e0 == e1) {
    float4 o = {0.f, 0.f, 0.f, 0.f};
    if (bias0) {
      o = *(const float4*)(bias0 + lane * 4);
      if (bias1) {
        float4 b1 = *(const float4*)(bias1 + lane * 4);
        o.x += b1.x; o.y += b1.y; o.z += b1.z; o.w += b1.w;
      }
    }
    *po = o;
    return;
  }
  // phase 1: per-head max (stash leaky logits in LDS), then exp-sum (stash weights)
  int h1 = lane & 7, slot = lane >> 3;
  float ern1 = er[n * 8 + h1];
  float m = -3.4e38f;
  for (int i = e0 + slot; i < e1; i += 8) {
    float l = el[srcs[i] * 8 + h1] + ern1;
    l = l >= 0.f ? l : 0.2f * l;
    int idx = i - e0;
    if (idx < CAP) wl[idx][h1] = l;
    m = fmaxf(m, l);
  }
  m = fmaxf(m, __shfl_xor(m, 8));
  m = fmaxf(m, __shfl_xor(m, 16));
  m = fmaxf(m, __shfl_xor(m, 32));
  float s = 0.f;
  for (int i = e0 + slot; i < e1; i += 8) {
    int idx = i - e0;
    float l;
    if (idx < CAP) l = wl[idx][h1];
    else {
      l = el[srcs[i] * 8 + h1] + ern1;
      l = l >= 0.f ? l : 0.2f * l;
    }
    float w = __expf(l - m);
    if (idx < CAP) wl[idx][h1] = w;
    s += w;
  }
  s += __shfl_xor(s, 8);
  s += __shfl_xor(s, 16);
  s += __shfl_xor(s, 32);
  // phase 2: aggregate; lane owns elements 4*lane..4*lane+3 (head = lane>>3)
  int h2 = lane >> 3;
  float mh = __shfl(m, h2);
  float sh = __shfl(s, h2);
  float ern2 = __shfl(ern1, h2);
  float ax = 0.f, ay = 0.f, az = 0.f, aw = 0.f;
  int i = e0;
  for (; i + 4 <= e1; i += 4) {
    int s0 = srcs[i], s1 = srcs[i + 1], s2 = srcs[i + 2], s3 = srcs[i + 3];
    s16x4 v0 = *(const s16x4*)(fsb + (size_t)s0 * 256 + lane * 4);
    s16x4 v1 = *(const s16x4*)(fsb + (size_t)s1 * 256 + lane * 4);
    s16x4 v2 = *(const s16x4*)(fsb + (size_t)s2 * 256 + lane * 4);
    s16x4 v3 = *(const s16x4*)(fsb + (size_t)s3 * 256 + lane * 4);
    int idx = i - e0;
    float w0, w1, w2, w3;
    if (idx + 3 < CAP) {
      w0 = wl[idx][h2]; w1 = wl[idx + 1][h2];
      w2 = wl[idx + 2][h2]; w3 = wl[idx + 3][h2];
    } else {
      w0 = (idx < CAP) ? wl[idx][h2] : gat_w(el, s0, h2, ern2, mh);
      w1 = (idx + 1 < CAP) ? wl[idx + 1][h2] : gat_w(el, s1, h2, ern2, mh);
      w2 = (idx + 2 < CAP) ? wl[idx + 2][h2] : gat_w(el, s2, h2, ern2, mh);
      w3 = gat_w(el, s3, h2, ern2, mh);
    }
    ax += w0 * bf2f(v0[0]) + w1 * bf2f(v1[0]) + w2 * bf2f(v2[0]) + w3 * bf2f(v3[0]);
    ay += w0 * bf2f(v0[1]) + w1 * bf2f(v1[1]) + w2 * bf2f(v2[1]) + w3 * bf2f(v3[1]);
    az += w0 * bf2f(v0[2]) + w1 * bf2f(v1[2]) + w2 * bf2f(v2[2]) + w3 * bf2f(v3[2]);
    aw += w0 * bf2f(v0[3]) + w1 * bf2f(v1[3]) + w2 * bf2f(v2[3]) + w3 * bf2f(v3[3]);
  }
  for (; i < e1; ++i) {
    int src = srcs[i];
    int idx = i - e0;
    float w = (idx < CAP) ? wl[idx][h2] : gat_w(el, src, h2, ern2, mh);
    s16x4 v = *(const s16x4*)(fsb + (size_t)src * 256 + lane * 4);
    ax += w * bf2f(v[0]);
    ay += w * bf2f(v[1]);
    az += w * bf2f(v[2]);
    aw += w * bf2f(v[3]);
  }
  float sinv = 1.f / sh;
  float4 o = {ax * sinv, ay * sinv, az * sinv, aw * sinv};
  if (bias0) {
    float4 b = *(const float4*)(bias0 + lane * 4);
    o.x += b.x; o.y += b.y; o.z += b.z; o.w += b.w;
    if (bias1) {
      float4 b1 = *(const float4*)(bias1 + lane * 4);
      o.x += b1.x; o.y += b1.y; o.z += b1.z; o.w += b1.w;
    }
  }
  *po = o;
}

// dual-job gat: blocks [0,nA) -> job A (with biases), blocks [nA,..) -> job B (raw)
__global__ __launch_bounds__(256) void gat_fused2(
    const int* __restrict__ oA, const int* __restrict__ sA,
    const float* __restrict__ elA, const float* __restrict__ erA,
    const short* __restrict__ fA,
    const float* __restrict__ b0A, const float* __restrict__ b1A,
    float* __restrict__ outA, int ndstA, int nA,
    const int* __restrict__ oB, const int* __restrict__ sB,
    const float* __restrict__ elB, const float* __restrict__ erB,
    const short* __restrict__ fB, float* __restrict__ outB, int ndstB) {
  __shared__ float wlds[4][CAP][8];
  int wv = threadIdx.x >> 6;
  int b = blockIdx.x;
  if (b < nA) {
    int n = b * 4 + wv;
    if (n >= ndstA) return;
    gat_body(oA, sA, elA, erA, fA, b0A, b1A, outA, n, wlds[wv]);
  } else {
    int n = (b - nA) * 4 + wv;
    if (n >= ndstB) return;
    gat_body(oB, sB, elB, erB, fB, nullptr, nullptr, outB, n, wlds[wv]);
  }
}

// ---------------- global projection (with mean scaling) ----------------
__global__ __launch_bounds__(512) void global_proj(const float* __restrict__ g,
                                                   const float* __restrict__ W,
                                                   const float* __restrict__ b,
                                                   float* __restrict__ out) {
  __shared__ float gl[512];
  int tid = threadIdx.x;
  gl[tid] = g[tid] * (tid < 256 ? (1.f / NU) : (1.f / NT));
  __syncthreads();
  float s = b[tid];
  for (int k = 0; k < 512; ++k) s += gl[k] * W[k * 512 + tid];
  out[tid] = s;
}

extern "C" void kernel_launch(void* const* d_in, const int* in_sizes, int n_in,
                              void* d_out, int out_size, void* d_ws, size_t ws_size,
                              hipStream_t stream) {
  const float* usv_feat   = (const float*)d_in[0];
  const float* task_feat  = (const float*)d_in[1];
  const float* usv_enc_w  = (const float*)d_in[2];
  const float* usv_enc_b  = (const float*)d_in[3];
  const float* task_enc_w = (const float*)d_in[4];
  const float* task_enc_b = (const float*)d_in[5];
  const float* l0_tt_wsrc = (const float*)d_in[6];
  const float* l0_tt_wdst = (const float*)d_in[7];
  const float* l0_tt_al   = (const float*)d_in[8];
  const float* l0_tt_ar   = (const float*)d_in[9];
  const float* l0_tt_bias = (const float*)d_in[10];
  const float* l0_ut_wsrc = (const float*)d_in[11];
  const float* l0_ut_wdst = (const float*)d_in[12];
  const float* l0_ut_al   = (const float*)d_in[13];
  const float* l0_ut_ar   = (const float*)d_in[14];
  const float* l0_ut_bias = (const float*)d_in[15];
  const float* l0_post_w  = (const float*)d_in[16];
  const float* l0_post_b  = (const float*)d_in[17];
  const float* l1_tt_wsrc = (const float*)d_in[18];
  const float* l1_tt_wdst = (const float*)d_in[19];
  const float* l1_tt_al   = (const float*)d_in[20];
  const float* l1_tt_ar   = (const float*)d_in[21];
  const float* l1_tt_bias = (const float*)d_in[22];
  const float* l1_post_w  = (const float*)d_in[23];
  const float* l1_post_b  = (const float*)d_in[24];
  const float* task_dec_w = (const float*)d_in[25];
  const float* task_dec_b = (const float*)d_in[26];
  const float* gp_w       = (const float*)d_in[27];
  const float* gp_b       = (const float*)d_in[28];
  const int* tt_src = (const int*)d_in[29];
  const int* tt_dst = (const int*)d_in[30];
  const int* ut_src = (const int*)d_in[31];
  const int* ut_dst = (const int*)d_in[32];

  float* out = (float*)d_out;
  float* out_usv  = out;
  float* out_task = out + NU * HID;
  float* out_glob = out + NU * HID + NT * HID;

  char* ws = (char*)d_ws;
  size_t off = 0;
  auto alloc_f = [&](size_t n) {
    float* p = (float*)(ws + off);
    off += ((n * 4 + 1023) / 1024) * 1024;
    return p;
  };
  auto alloc_i = [&](size_t n) {
    int* p = (int*)(ws + off);
    off += ((n * 4 + 1023) / 1024) * 1024;
    return p;
  };
  auto alloc_s = [&](size_t n) {
    short* p = (short*)(ws + off);
    off += ((n * 2 + 1023) / 1024) * 1024;
    return p;
  };
  short* taskh_b = alloc_s((size_t)NT * HID);
  short* usvh_b  = alloc_s((size_t)NU * HID);
  short* fs_b    = alloc_s((size_t)NT * HID);
  short* fsu_b   = alloc_s((size_t)NU * HID);
  float* obuf  = alloc_f((size_t)NT * HID);
  float* obuf2 = alloc_f((size_t)NT * HID);
  float* el    = alloc_f((size_t)NT * HEADS);
  float* er    = alloc_f((size_t)NT * HEADS);
  float* el2   = alloc_f((size_t)NU * HEADS);
  float* er2   = alloc_f((size_t)NT * HEADS);
  float* w2all = alloc_f(3 * 2048);
  float* g     = alloc_f(512);
  short* wt0 = alloc_s(256 * 256);
  short* wt1 = alloc_s(256 * 256);
  short* wt2 = alloc_s(256 * 256);
  short* wt3 = alloc_s(256 * 256);
  int* tt_deg  = alloc_i(NT);
  int* tt_offs = alloc_i(NT + 1);
  int* tt_cur  = alloc_i(NT);
  int* tt_srcs = alloc_i(E_TT);
  int* ut_deg  = alloc_i(NT);
  int* ut_offs = alloc_i(NT + 1);
  int* ut_cur  = alloc_i(NT);
  int* ut_srcs = alloc_i(E_UT);

  init_zero<<<(NT + 255) / 256, 256, 0, stream>>>(tt_deg, ut_deg, g);

  prep<<<dim3(8, 8, 5), 256, 0, stream>>>(l0_tt_wsrc, l0_ut_wsrc, l1_tt_wsrc, task_dec_w,
                                          wt0, wt1, wt2, wt3,
                                          l0_tt_wdst, l0_tt_ar, l0_ut_wdst, l0_ut_ar,
                                          l1_tt_wdst, l1_tt_ar, w2all);

  // encoders (merged; usv part also accumulates raw column sums into g[0:256])
  int nbU16 = (NU + 15) / 16, nbT16 = (NT + 15) / 16;
  enc_gemm<<<nbU16 + nbT16, 256, 0, stream>>>(usv_feat, usv_enc_w, usv_enc_b, out_usv, usvh_b,
                                              task_feat, task_enc_w, task_enc_b, taskh_b,
                                              g, nbU16);

  // CSR build (batched over both graphs)
  int nbE = (E_TT + E_UT + 255) / 256;
  deg2<<<nbE, 256, 0, stream>>>(tt_dst, ut_dst, tt_deg, ut_deg);
  scan2<<<2, 1024, 0, stream>>>(tt_deg, tt_offs, tt_cur, ut_deg, ut_offs, ut_cur, NT);
  scat2<<<nbE, 256, 0, stream>>>(tt_src, tt_dst, tt_cur, tt_srcs, ut_src, ut_dst, ut_cur, ut_srcs);

  int nbyT = (NT + 127) / 128, nbyU = (NU + 127) / 128;
  int nbT = (NT * 8 + 255) / 256;
  int nbU = (NU * 8 + 255) / 256;
  int nbAgg = (NT + 3) / 4;

  // ---- layer 0: both GEMMs in one launch ----
  gemm_bf16_dual<<<dim3(2, nbyT + nbyU), 256, 0, stream>>>(taskh_b, wt0, fs_b,
                                                           usvh_b, wt1, fsu_b, nbyT);
  {
    EJob jel  = {fs_b, l0_tt_al, el, NT, 0};
    EJob jer  = {taskh_b, w2all, er, NT, 1};
    EJob jel2 = {fsu_b, l0_ut_al, el2, NU, 0};
    EJob jer2 = {taskh_b, w2all + 2048, er2, NT, 1};
    el_er_multi<<<nbT + nbT + nbU + nbT, 256, 0, stream>>>(jel, jer, jel2, jer2,
                                                           nbT, nbT, nbU, nbT);
  }
  // ---- layer 0: both aggregations in one launch (tt -> obuf, ut -> obuf2) ----
  gat_fused2<<<nbAgg + nbAgg, 256, 0, stream>>>(
      tt_offs, tt_srcs, el, er, fs_b, l0_tt_bias, l0_ut_bias, obuf, NT, nbAgg,
      ut_offs, ut_srcs, el2, er2, fsu_b, obuf2, NT);

  // ---- post 0 (head-mean over obuf+obuf2, fused) ----
  gemm_k32hm<<<nbT16, 256, 0, stream>>>(obuf, obuf2, l0_post_w, l0_post_b, taskh_b, NT);

  // ---- layer 1, tt ----
  gemm_bf16<<<dim3(2, nbyT), 256, 0, stream>>>(taskh_b, wt2, nullptr, nullptr, fs_b, NT, 0, nullptr);
  {
    EJob jel = {fs_b, l1_tt_al, el, NT, 0};
    EJob jer = {taskh_b, w2all + 4096, er, NT, 1};
    el_er_multi<<<nbT + nbT, 256, 0, stream>>>(jel, jer, jel, jel, nbT, nbT, 0, 0);
  }
  gat_fused2<<<nbAgg, 256, 0, stream>>>(
      tt_offs, tt_srcs, el, er, fs_b, l1_tt_bias, nullptr, obuf, NT, nbAgg,
      tt_offs, tt_srcs, el, er, fs_b, obuf2, 0);

  // ---- post 1 ----
  gemm_k32hm<<<nbT16, 256, 0, stream>>>(obuf, nullptr, l1_post_w, l1_post_b, taskh_b, NT);

  // ---- decoder (relu, f32 out, fused task column sums into g[256:512]) ----
  gemm_bf16<<<dim3(2, nbyT), 256, 0, stream>>>(taskh_b, wt3, task_dec_b, out_task, nullptr, NT, 1, g + 256);

  // ---- global projection (applies 1/NU, 1/NT) ----
  global_proj<<<1, 512, 0, stream>>>(g, gp_w, gp_b, out_glob);
}

// Round 6
// 338.143 us; speedup vs baseline: 2.9471x; 1.0941x over previous
//
#include <hip/hip_runtime.h>
#include <hip/hip_bf16.h>

#define NT 20000
#define NU 2000
#define HID 256
#define HEADS 8
#define FPH 32
#define E_TT 320000
#define E_UT 100000
#define CAP 80

typedef __attribute__((ext_vector_type(8))) short s16x8;
typedef __attribute__((ext_vector_type(4))) short s16x4;
typedef __attribute__((ext_vector_type(4))) float f32x4;

__device__ inline short f2bf(float f) {
  union { float f; unsigned u; } v; v.f = f;
  unsigned r = v.u + 0x7fff + ((v.u >> 16) & 1);
  return (short)(r >> 16);
}
__device__ inline float bf2f(short s) {
  return __uint_as_float(((unsigned)(unsigned short)s) << 16);
}

// ---------------- init: zero deg arrays + g ----------------
__global__ __launch_bounds__(256) void init_zero(int* __restrict__ tt_deg,
                                                 int* __restrict__ ut_deg,
                                                 float* __restrict__ g) {
  int i = blockIdx.x * 256 + threadIdx.x;
  if (i < NT) { tt_deg[i] = 0; ut_deg[i] = 0; }
  if (i < 512) g[i] = 0.f;
}

// ------------- prep: 4x weight transpose (f32->bf16 [col][k]) + 3x w2 ---------------
__global__ __launch_bounds__(256) void prep(const float* __restrict__ w0,
                                            const float* __restrict__ w1,
                                            const float* __restrict__ w2_,
                                            const float* __restrict__ w3,
                                            short* __restrict__ o0,
                                            short* __restrict__ o1,
                                            short* __restrict__ o2,
                                            short* __restrict__ o3,
                                            const float* __restrict__ wd0,
                                            const float* __restrict__ ar0,
                                            const float* __restrict__ wd1,
                                            const float* __restrict__ ar1,
                                            const float* __restrict__ wd2,
                                            const float* __restrict__ ar2,
                                            float* __restrict__ w2all) {
  int z = blockIdx.z;
  if (z < 4) {
    __shared__ float tile[32][33];
    const float* W = (z == 0) ? w0 : (z == 1) ? w1 : (z == 2) ? w2_ : w3;
    short* Wt = (z == 0) ? o0 : (z == 1) ? o1 : (z == 2) ? o2 : o3;
    int bx = blockIdx.x, by = blockIdx.y;
    int tx = threadIdx.x & 31, ty = threadIdx.x >> 5;
#pragma unroll
    for (int i = 0; i < 32; i += 8)
      tile[ty + i][tx] = W[(by * 32 + ty + i) * 256 + bx * 32 + tx];
    __syncthreads();
#pragma unroll
    for (int i = 0; i < 32; i += 8)
      Wt[(bx * 32 + ty + i) * 256 + by * 32 + tx] = f2bf(tile[tx][ty + i]);
  } else {
    int flat = (blockIdx.y * 8 + blockIdx.x) * 256 + threadIdx.x;
    if (flat >= 3 * 2048) return;
    int e = flat >> 11, idx = flat & 2047;
    const float* wd = (e == 0) ? wd0 : (e == 1) ? wd1 : wd2;
    const float* ar = (e == 0) ? ar0 : (e == 1) ? ar1 : ar2;
    int k = idx >> 3, h = idx & 7;
    float s = 0.f;
#pragma unroll
    for (int f = 0; f < 32; ++f) s += wd[k * 256 + h * 32 + f] * ar[h * 32 + f];
    w2all[flat] = s;
  }
}

// ---------------- K=32 GEMM body ----------------
__device__ inline void k32_body(const float* __restrict__ A, const float* __restrict__ W,
                                const float* __restrict__ bias, float* __restrict__ Cf,
                                short* __restrict__ Cb, int N, int blk,
                                float* __restrict__ gsum) {
  __shared__ float Ws[32][256];
  __shared__ float Ar[16][32];
  int tid = threadIdx.x;
  for (int i = tid; i < 32 * 256; i += 256) Ws[i >> 8][i & 255] = W[i];
  int n0 = blk * 16;
  int nrows = min(16, N - n0);
  for (int i = tid; i < 512; i += 256) {
    int r = i >> 5, k = i & 31;
    if (r < nrows) Ar[r][k] = A[(size_t)(n0 + r) * 32 + k];
  }
  __syncthreads();
  float b = bias[tid];
  float colacc = 0.f;
  for (int r = 0; r < nrows; ++r) {
    float acc = b;
#pragma unroll
    for (int k = 0; k < 32; ++k) acc += Ar[r][k] * Ws[k][tid];
    size_t o = (size_t)(n0 + r) * 256 + tid;
    if (Cf) Cf[o] = acc;
    if (Cb) Cb[o] = f2bf(acc);
    colacc += acc;
  }
  if (gsum) atomicAdd(&gsum[tid], colacc);
}

// merged encoders: usv blocks then task blocks
__global__ __launch_bounds__(256) void enc_gemm(const float* __restrict__ uf,
                                                const float* __restrict__ uw,
                                                const float* __restrict__ ub,
                                                float* __restrict__ out_usv,
                                                short* __restrict__ usvh_b,
                                                const float* __restrict__ tf,
                                                const float* __restrict__ tw,
                                                const float* __restrict__ tb,
                                                short* __restrict__ taskh_b,
                                                float* __restrict__ g, int nbU) {
  int b = blockIdx.x;
  if (b < nbU)
    k32_body(uf, uw, ub, out_usv, usvh_b, NU, b, g);
  else
    k32_body(tf, tw, tb, nullptr, taskh_b, NT, b - nbU, nullptr);
}

// ---------- fused head-mean + K=32 GEMM -> bf16 (bf16 obuf inputs) ----------
__global__ __launch_bounds__(256) void gemm_k32hm(const short* __restrict__ obuf,
                                                  const short* __restrict__ obuf2,
                                                  const float* __restrict__ W,
                                                  const float* __restrict__ bias,
                                                  short* __restrict__ Cb, int N) {
  __shared__ float Ws[32][256];
  __shared__ float Ar[16][32];
  int tid = threadIdx.x;
  for (int i = tid; i < 32 * 256; i += 256) Ws[i >> 8][i & 255] = W[i];
  int n0 = blockIdx.x * 16;
  for (int i = tid; i < 512; i += 256) {
    int r = i >> 5, f = i & 31;
    int n = n0 + r;
    float s = 0.f;
    if (n < N) {
#pragma unroll
      for (int h = 0; h < 8; ++h) s += bf2f(obuf[(size_t)n * 256 + h * 32 + f]);
      if (obuf2) {
#pragma unroll
        for (int h = 0; h < 8; ++h) s += bf2f(obuf2[(size_t)n * 256 + h * 32 + f]);
      }
    }
    Ar[r][f] = s * 0.125f;
  }
  __syncthreads();
  float b = bias[tid];
  int nrows = min(16, N - n0);
  for (int r = 0; r < nrows; ++r) {
    float acc = b;
#pragma unroll
    for (int k = 0; k < 32; ++k) acc += Ar[r][k] * Ws[k][tid];
    Cb[(size_t)(n0 + r) * 256 + tid] = f2bf(acc);
  }
}

// ---- direct-load MFMA GEMM: no LDS, wave = 32 rows x 64 cols, block = 4 col-strips --
__device__ inline void gemm_dl_body(const short* __restrict__ A,
                                    const short* __restrict__ Wt,
                                    const float* __restrict__ bias,
                                    float* __restrict__ Cf, short* __restrict__ Cb,
                                    int N, int relu, float* __restrict__ gsum,
                                    int strip) {
  int lane = threadIdx.x & 63;
  int wv = threadIdx.x >> 6;
  int fr = lane & 15, fq = lane >> 4;
  int row0 = strip * 32;
  int col0 = wv * 64;

  f32x4 acc[2][4];
#pragma unroll
  for (int m = 0; m < 2; ++m)
#pragma unroll
    for (int n = 0; n < 4; ++n) acc[m][n] = (f32x4){0.f, 0.f, 0.f, 0.f};

  const int gr0 = row0 + fr, gr1 = row0 + 16 + fr;
  const bool v0 = gr0 < N, v1 = gr1 < N;
  const short* pa0 = A + (size_t)gr0 * 256 + fq * 8;
  const short* pa1 = A + (size_t)gr1 * 256 + fq * 8;
  const short* pb = Wt + (size_t)(col0 + fr) * 256 + fq * 8;

#pragma unroll
  for (int k0 = 0; k0 < 256; k0 += 32) {
    s16x8 a0 = v0 ? *(const s16x8*)(pa0 + k0) : (s16x8){0,0,0,0,0,0,0,0};
    s16x8 a1 = v1 ? *(const s16x8*)(pa1 + k0) : (s16x8){0,0,0,0,0,0,0,0};
    s16x8 b0 = *(const s16x8*)(pb + k0);
    s16x8 b1 = *(const s16x8*)(pb + 16 * 256 + k0);
    s16x8 b2 = *(const s16x8*)(pb + 32 * 256 + k0);
    s16x8 b3 = *(const s16x8*)(pb + 48 * 256 + k0);
    acc[0][0] = __builtin_amdgcn_mfma_f32_16x16x32_bf16(a0, b0, acc[0][0], 0, 0, 0);
    acc[0][1] = __builtin_amdgcn_mfma_f32_16x16x32_bf16(a0, b1, acc[0][1], 0, 0, 0);
    acc[0][2] = __builtin_amdgcn_mfma_f32_16x16x32_bf16(a0, b2, acc[0][2], 0, 0, 0);
    acc[0][3] = __builtin_amdgcn_mfma_f32_16x16x32_bf16(a0, b3, acc[0][3], 0, 0, 0);
    acc[1][0] = __builtin_amdgcn_mfma_f32_16x16x32_bf16(a1, b0, acc[1][0], 0, 0, 0);
    acc[1][1] = __builtin_amdgcn_mfma_f32_16x16x32_bf16(a1, b1, acc[1][1], 0, 0, 0);
    acc[1][2] = __builtin_amdgcn_mfma_f32_16x16x32_bf16(a1, b2, acc[1][2], 0, 0, 0);
    acc[1][3] = __builtin_amdgcn_mfma_f32_16x16x32_bf16(a1, b3, acc[1][3], 0, 0, 0);
  }

  float bv[4];
#pragma unroll
  for (int n = 0; n < 4; ++n) bv[n] = bias ? bias[col0 + n * 16 + fr] : 0.f;

  float csum[4] = {0.f, 0.f, 0.f, 0.f};
#pragma unroll
  for (int m = 0; m < 2; ++m) {
    int grb = row0 + m * 16 + fq * 4;
#pragma unroll
    for (int r = 0; r < 4; ++r) {
      if (grb + r >= N) continue;
#pragma unroll
      for (int n = 0; n < 4; ++n) {
        float v = acc[m][n][r] + bv[n];
        if (relu) v = fmaxf(v, 0.f);
        size_t o = (size_t)(grb + r) * 256 + col0 + n * 16 + fr;
        if (Cf) Cf[o] = v;
        if (Cb) Cb[o] = f2bf(v);
        csum[n] += v;
      }
    }
  }
  if (gsum) {
#pragma unroll
    for (int n = 0; n < 4; ++n) {
      float s = csum[n];
      s += __shfl_xor(s, 16);
      s += __shfl_xor(s, 32);
      if (fq == 0) atomicAdd(&gsum[col0 + n * 16 + fr], s);
    }
  }
}

__global__ __launch_bounds__(256) void gemm_dl(const short* __restrict__ A,
                                               const short* __restrict__ Wt,
                                               const float* __restrict__ bias,
                                               float* __restrict__ Cf,
                                               short* __restrict__ Cb,
                                               int N, int relu, float* __restrict__ gsum) {
  gemm_dl_body(A, Wt, bias, Cf, Cb, N, relu, gsum, blockIdx.x);
}

// layer-0 dual: tt strips then ut strips
__global__ __launch_bounds__(256) void gemm_dl_dual(const short* __restrict__ A0,
                                                    const short* __restrict__ Wt0,
                                                    short* __restrict__ C0,
                                                    const short* __restrict__ A1,
                                                    const short* __restrict__ Wt1,
                                                    short* __restrict__ C1,
                                                    int nstr0) {
  if ((int)blockIdx.x < nstr0)
    gemm_dl_body(A0, Wt0, nullptr, nullptr, C0, NT, 0, nullptr, blockIdx.x);
  else
    gemm_dl_body(A1, Wt1, nullptr, nullptr, C1, NU, 0, nullptr, blockIdx.x - nstr0);
}

// ---------------- el/er multi-job kernel ----------------
struct EJob { const short* x; const float* w; float* o; int n; int type; };

__device__ inline void ej_run(const EJob& jb, int rel) {
  int idx = rel * 256 + (int)threadIdx.x;
  if (idx >= jb.n * 8) return;
  int n = idx >> 3, h = idx & 7;
  if (jb.type == 0) {
    const s16x8* p = (const s16x8*)(jb.x + (size_t)n * 256 + h * 32);
    const float* alh = jb.w + h * 32;
    float s = 0.f;
#pragma unroll
    for (int q = 0; q < 4; ++q) {
      s16x8 v = p[q];
#pragma unroll
      for (int j = 0; j < 8; ++j) s += bf2f(v[j]) * alh[q * 8 + j];
    }
    jb.o[idx] = s;
  } else {
    const s16x8* p = (const s16x8*)(jb.x + (size_t)n * 256);
    float s = 0.f;
#pragma unroll 4
    for (int q = 0; q < 32; ++q) {
      s16x8 v = p[q];
#pragma unroll
      for (int j = 0; j < 8; ++j) s += bf2f(v[j]) * jb.w[(q * 8 + j) * 8 + h];
    }
    jb.o[idx] = s;
  }
}

__global__ __launch_bounds__(256) void el_er_multi(EJob j0, EJob j1, EJob j2, EJob j3,
                                                   int b0, int b1, int b2, int b3) {
  int b = blockIdx.x;
  if (b < b0) { ej_run(j0, b); return; }
  b -= b0;
  if (b < b1) { ej_run(j1, b); return; }
  b -= b1;
  if (b < b2) { ej_run(j2, b); return; }
  b -= b2;
  ej_run(j3, b);
}

// ---------------- batched CSR build ----------------
__global__ void deg2(const int* __restrict__ tt_dst, const int* __restrict__ ut_dst,
                     int* __restrict__ tt_deg, int* __restrict__ ut_deg) {
  int e = blockIdx.x * 256 + threadIdx.x;
  if (e < E_TT) atomicAdd(&tt_deg[tt_dst[e]], 1);
  int e2 = e - E_TT;
  if (e2 >= 0 && e2 < E_UT) atomicAdd(&ut_deg[ut_dst[e2]], 1);
}

__global__ __launch_bounds__(1024) void scan2(const int* __restrict__ d0, int* __restrict__ o0,
                                              int* __restrict__ c0,
                                              const int* __restrict__ d1, int* __restrict__ o1,
                                              int* __restrict__ c1, int n) {
  const int* deg = blockIdx.x ? d1 : d0;
  int* off = blockIdx.x ? o1 : o0;
  int* cursor = blockIdx.x ? c1 : c0;
  int tid = threadIdx.x;
  const int C = 20;
  int base = tid * C;
  int local[C];
  int s = 0;
#pragma unroll
  for (int i = 0; i < C; ++i) {
    int idx = base + i;
    int v = (idx < n) ? deg[idx] : 0;
    local[i] = s;
    s += v;
  }
  int lane = tid & 63, wave = tid >> 6;
  int x = s;
#pragma unroll
  for (int d = 1; d < 64; d <<= 1) {
    int y = __shfl_up(x, d, 64);
    if (lane >= d) x += y;
  }
  __shared__ int wsum[16];
  if (lane == 63) wsum[wave] = x;
  __syncthreads();
  if (wave == 0) {
    int wv = (lane < 16) ? wsum[lane] : 0;
#pragma unroll
    for (int d = 1; d < 16; d <<= 1) {
      int y = __shfl_up(wv, d, 64);
      if (lane >= d) wv += y;
    }
    if (lane < 16) wsum[lane] = wv;
  }
  __syncthreads();
  int waveoff = (wave == 0) ? 0 : wsum[wave - 1];
  int excl = waveoff + x - s;
#pragma unroll
  for (int i = 0; i < C; ++i) {
    int idx = base + i;
    if (idx < n) {
      int o = excl + local[i];
      off[idx] = o;
      cursor[idx] = o;
    }
  }
  if (tid == 1023) off[n] = waveoff + x;
}

__global__ void scat2(const int* __restrict__ tt_src, const int* __restrict__ tt_dst,
                      int* __restrict__ tt_cur, int* __restrict__ tt_srcs,
                      const int* __restrict__ ut_src, const int* __restrict__ ut_dst,
                      int* __restrict__ ut_cur, int* __restrict__ ut_srcs) {
  int e = blockIdx.x * 256 + threadIdx.x;
  if (e < E_TT) {
    int p = atomicAdd(&tt_cur[tt_dst[e]], 1);
    tt_srcs[p] = tt_src[e];
  }
  int e2 = e - E_TT;
  if (e2 >= 0 && e2 < E_UT) {
    int p = atomicAdd(&ut_cur[ut_dst[e2]], 1);
    ut_srcs[p] = ut_src[e2];
  }
}

// -------- fused softmax + aggregation, wave/node, LDS-cached weights, 4x unroll -----
__device__ inline float gat_w(const float* __restrict__ el, int src, int h,
                              float ern, float mh) {
  float l = el[src * 8 + h] + ern;
  l = l >= 0.f ? l : 0.2f * l;
  return __expf(l - mh);
}

__device__ inline void gat_body(const int* __restrict__ offs, const int* __restrict__ srcs,
                                const float* __restrict__ el, const float* __restrict__ er,
                                const short* __restrict__ fsb,
                                const float* __restrict__ bias0,
                                const float* __restrict__ bias1,
                                short* __restrict__ out, int n, float (*wl)[8]) {
  int lane = threadIdx.x & 63;
  int e0 = offs[n], e1 = offs[n + 1];
  s16x4* po = (s16x4*)(out + (size_t)n * 256 + lane * 4);
  if (e0 == e1) {
    float4 o = {0.f, 0.f, 0.f, 0.f};
    if (bias0) {
      o = *(const float4*)(bias0 + lane * 4);
      if (bias1) {
        float4 b1 = *(const float4*)(bias1 + lane * 4);
        o.x += b1.x; o.y += b1.y; o.z += b1.z; o.w += b1.w;
      }
    }
    *po = (s16x4){f2bf(o.x), f2bf(o.y), f2bf(o.z), f2bf(o.w)};
    return;
  }
  // phase 1: per-head max (stash leaky logits in LDS), then exp-sum (stash weights)
  int h1 = lane & 7, slot = lane >> 3;
  float ern1 = er[n * 8 + h1];
  float m = -3.4e38f;
  for (int i = e0 + slot; i < e1; i += 8) {
    float l = el[srcs[i] * 8 + h1] + ern1;
    l = l >= 0.f ? l : 0.2f * l;
    int idx = i - e0;
    if (idx < CAP) wl[idx][h1] = l;
    m = fmaxf(m, l);
  }
  m = fmaxf(m, __shfl_xor(m, 8));
  m = fmaxf(m, __shfl_xor(m, 16));
  m = fmaxf(m, __shfl_xor(m, 32));
  float s = 0.f;
  for (int i = e0 + slot; i < e1; i += 8) {
    int idx = i - e0;
    float l;
    if (idx < CAP) l = wl[idx][h1];
    else {
      l = el[srcs[i] * 8 + h1] + ern1;
      l = l >= 0.f ? l : 0.2f * l;
    }
    float w = __expf(l - m);
    if (idx < CAP) wl[idx][h1] = w;
    s += w;
  }
  s += __shfl_xor(s, 8);
  s += __shfl_xor(s, 16);
  s += __shfl_xor(s, 32);
  // phase 2: aggregate; lane owns elements 4*lane..4*lane+3 (head = lane>>3)
  int h2 = lane >> 3;
  float mh = __shfl(m, h2);
  float sh = __shfl(s, h2);
  float ern2 = __shfl(ern1, h2);
  float ax = 0.f, ay = 0.f, az = 0.f, aw = 0.f;
  int i = e0;
  for (; i + 4 <= e1; i += 4) {
    int s0 = srcs[i], s1 = srcs[i + 1], s2 = srcs[i + 2], s3 = srcs[i + 3];
    s16x4 v0 = *(const s16x4*)(fsb + (size_t)s0 * 256 + lane * 4);
    s16x4 v1 = *(const s16x4*)(fsb + (size_t)s1 * 256 + lane * 4);
    s16x4 v2 = *(const s16x4*)(fsb + (size_t)s2 * 256 + lane * 4);
    s16x4 v3 = *(const s16x4*)(fsb + (size_t)s3 * 256 + lane * 4);
    int idx = i - e0;
    float w0, w1, w2, w3;
    if (idx + 3 < CAP) {
      w0 = wl[idx][h2]; w1 = wl[idx + 1][h2];
      w2 = wl[idx + 2][h2]; w3 = wl[idx + 3][h2];
    } else {
      w0 = (idx < CAP) ? wl[idx][h2] : gat_w(el, s0, h2, ern2, mh);
      w1 = (idx + 1 < CAP) ? wl[idx + 1][h2] : gat_w(el, s1, h2, ern2, mh);
      w2 = (idx + 2 < CAP) ? wl[idx + 2][h2] : gat_w(el, s2, h2, ern2, mh);
      w3 = gat_w(el, s3, h2, ern2, mh);
    }
    ax += w0 * bf2f(v0[0]) + w1 * bf2f(v1[0]) + w2 * bf2f(v2[0]) + w3 * bf2f(v3[0]);
    ay += w0 * bf2f(v0[1]) + w1 * bf2f(v1[1]) + w2 * bf2f(v2[1]) + w3 * bf2f(v3[1]);
    az += w0 * bf2f(v0[2]) + w1 * bf2f(v1[2]) + w2 * bf2f(v2[2]) + w3 * bf2f(v3[2]);
    aw += w0 * bf2f(v0[3]) + w1 * bf2f(v1[3]) + w2 * bf2f(v2[3]) + w3 * bf2f(v3[3]);
  }
  for (; i < e1; ++i) {
    int src = srcs[i];
    int idx = i - e0;
    float w = (idx < CAP) ? wl[idx][h2] : gat_w(el, src, h2, ern2, mh);
    s16x4 v = *(const s16x4*)(fsb + (size_t)src * 256 + lane * 4);
    ax += w * bf2f(v[0]);
    ay += w * bf2f(v[1]);
    az += w * bf2f(v[2]);
    aw += w * bf2f(v[3]);
  }
  float sinv = 1.f / sh;
  float4 o = {ax * sinv, ay * sinv, az * sinv, aw * sinv};
  if (bias0) {
    float4 b = *(const float4*)(bias0 + lane * 4);
    o.x += b.x; o.y += b.y; o.z += b.z; o.w += b.w;
    if (bias1) {
      float4 b1 = *(const float4*)(bias1 + lane * 4);
      o.x += b1.x; o.y += b1.y; o.z += b1.z; o.w += b1.w;
    }
  }
  *po = (s16x4){f2bf(o.x), f2bf(o.y), f2bf(o.z), f2bf(o.w)};
}

// dual-job gat: blocks [0,nA) -> job A (with biases), blocks [nA,..) -> job B (raw)
__global__ __launch_bounds__(256) void gat_fused2(
    const int* __restrict__ oA, const int* __restrict__ sA,
    const float* __restrict__ elA, const float* __restrict__ erA,
    const short* __restrict__ fA,
    const float* __restrict__ b0A, const float* __restrict__ b1A,
    short* __restrict__ outA, int ndstA, int nA,
    const int* __restrict__ oB, const int* __restrict__ sB,
    const float* __restrict__ elB, const float* __restrict__ erB,
    const short* __restrict__ fB, short* __restrict__ outB, int ndstB) {
  __shared__ float wlds[4][CAP][8];
  int wv = threadIdx.x >> 6;
  int b = blockIdx.x;
  if (b < nA) {
    int n = b * 4 + wv;
    if (n >= ndstA) return;
    gat_body(oA, sA, elA, erA, fA, b0A, b1A, outA, n, wlds[wv]);
  } else {
    int n = (b - nA) * 4 + wv;
    if (n >= ndstB) return;
    gat_body(oB, sB, elB, erB, fB, nullptr, nullptr, outB, n, wlds[wv]);
  }
}

// ---------------- global projection (with mean scaling) ----------------
__global__ __launch_bounds__(512) void global_proj(const float* __restrict__ g,
                                                   const float* __restrict__ W,
                                                   const float* __restrict__ b,
                                                   float* __restrict__ out) {
  __shared__ float gl[512];
  int tid = threadIdx.x;
  gl[tid] = g[tid] * (tid < 256 ? (1.f / NU) : (1.f / NT));
  __syncthreads();
  float s = b[tid];
  for (int k = 0; k < 512; ++k) s += gl[k] * W[k * 512 + tid];
  out[tid] = s;
}

extern "C" void kernel_launch(void* const* d_in, const int* in_sizes, int n_in,
                              void* d_out, int out_size, void* d_ws, size_t ws_size,
                              hipStream_t stream) {
  const float* usv_feat   = (const float*)d_in[0];
  const float* task_feat  = (const float*)d_in[1];
  const float* usv_enc_w  = (const float*)d_in[2];
  const float* usv_enc_b  = (const float*)d_in[3];
  const float* task_enc_w = (const float*)d_in[4];
  const float* task_enc_b = (const float*)d_in[5];
  const float* l0_tt_wsrc = (const float*)d_in[6];
  const float* l0_tt_wdst = (const float*)d_in[7];
  const float* l0_tt_al   = (const float*)d_in[8];
  const float* l0_tt_ar   = (const float*)d_in[9];
  const float* l0_tt_bias = (const float*)d_in[10];
  const float* l0_ut_wsrc = (const float*)d_in[11];
  const float* l0_ut_wdst = (const float*)d_in[12];
  const float* l0_ut_al   = (const float*)d_in[13];
  const float* l0_ut_ar   = (const float*)d_in[14];
  const float* l0_ut_bias = (const float*)d_in[15];
  const float* l0_post_w  = (const float*)d_in[16];
  const float* l0_post_b  = (const float*)d_in[17];
  const float* l1_tt_wsrc = (const float*)d_in[18];
  const float* l1_tt_wdst = (const float*)d_in[19];
  const float* l1_tt_al   = (const float*)d_in[20];
  const float* l1_tt_ar   = (const float*)d_in[21];
  const float* l1_tt_bias = (const float*)d_in[22];
  const float* l1_post_w  = (const float*)d_in[23];
  const float* l1_post_b  = (const float*)d_in[24];
  const float* task_dec_w = (const float*)d_in[25];
  const float* task_dec_b = (const float*)d_in[26];
  const float* gp_w       = (const float*)d_in[27];
  const float* gp_b       = (const float*)d_in[28];
  const int* tt_src = (const int*)d_in[29];
  const int* tt_dst = (const int*)d_in[30];
  const int* ut_src = (const int*)d_in[31];
  const int* ut_dst = (const int*)d_in[32];

  float* out = (float*)d_out;
  float* out_usv  = out;
  float* out_task = out + NU * HID;
  float* out_glob = out + NU * HID + NT * HID;

  char* ws = (char*)d_ws;
  size_t off = 0;
  auto alloc_f = [&](size_t n) {
    float* p = (float*)(ws + off);
    off += ((n * 4 + 1023) / 1024) * 1024;
    return p;
  };
  auto alloc_i = [&](size_t n) {
    int* p = (int*)(ws + off);
    off += ((n * 4 + 1023) / 1024) * 1024;
    return p;
  };
  auto alloc_s = [&](size_t n) {
    short* p = (short*)(ws + off);
    off += ((n * 2 + 1023) / 1024) * 1024;
    return p;
  };
  short* taskh_b = alloc_s((size_t)NT * HID);
  short* usvh_b  = alloc_s((size_t)NU * HID);
  short* fs_b    = alloc_s((size_t)NT * HID);
  short* fsu_b   = alloc_s((size_t)NU * HID);
  short* obuf_b  = alloc_s((size_t)NT * HID);
  short* obuf2_b = alloc_s((size_t)NT * HID);
  float* el    = alloc_f((size_t)NT * HEADS);
  float* er    = alloc_f((size_t)NT * HEADS);
  float* el2   = alloc_f((size_t)NU * HEADS);
  float* er2   = alloc_f((size_t)NT * HEADS);
  float* w2all = alloc_f(3 * 2048);
  float* g     = alloc_f(512);
  short* wt0 = alloc_s(256 * 256);
  short* wt1 = alloc_s(256 * 256);
  short* wt2 = alloc_s(256 * 256);
  short* wt3 = alloc_s(256 * 256);
  int* tt_deg  = alloc_i(NT);
  int* tt_offs = alloc_i(NT + 1);
  int* tt_cur  = alloc_i(NT);
  int* tt_srcs = alloc_i(E_TT);
  int* ut_deg  = alloc_i(NT);
  int* ut_offs = alloc_i(NT + 1);
  int* ut_cur  = alloc_i(NT);
  int* ut_srcs = alloc_i(E_UT);

  init_zero<<<(NT + 255) / 256, 256, 0, stream>>>(tt_deg, ut_deg, g);

  prep<<<dim3(8, 8, 5), 256, 0, stream>>>(l0_tt_wsrc, l0_ut_wsrc, l1_tt_wsrc, task_dec_w,
                                          wt0, wt1, wt2, wt3,
                                          l0_tt_wdst, l0_tt_ar, l0_ut_wdst, l0_ut_ar,
                                          l1_tt_wdst, l1_tt_ar, w2all);

  // encoders (merged; usv part also accumulates raw column sums into g[0:256])
  int nbU16 = (NU + 15) / 16, nbT16 = (NT + 15) / 16;
  enc_gemm<<<nbU16 + nbT16, 256, 0, stream>>>(usv_feat, usv_enc_w, usv_enc_b, out_usv, usvh_b,
                                              task_feat, task_enc_w, task_enc_b, taskh_b,
                                              g, nbU16);

  // CSR build (batched over both graphs)
  int nbE = (E_TT + E_UT + 255) / 256;
  deg2<<<nbE, 256, 0, stream>>>(tt_dst, ut_dst, tt_deg, ut_deg);
  scan2<<<2, 1024, 0, stream>>>(tt_deg, tt_offs, tt_cur, ut_deg, ut_offs, ut_cur, NT);
  scat2<<<nbE, 256, 0, stream>>>(tt_src, tt_dst, tt_cur, tt_srcs, ut_src, ut_dst, ut_cur, ut_srcs);

  int nstrT = (NT + 31) / 32, nstrU = (NU + 31) / 32;
  int nbT = (NT * 8 + 255) / 256;
  int nbU = (NU * 8 + 255) / 256;
  int nbAgg = (NT + 3) / 4;

  // ---- layer 0: both GEMMs in one launch (direct-load MFMA) ----
  gemm_dl_dual<<<nstrT + nstrU, 256, 0, stream>>>(taskh_b, wt0, fs_b,
                                                  usvh_b, wt1, fsu_b, nstrT);
  {
    EJob jel  = {fs_b, l0_tt_al, el, NT, 0};
    EJob jer  = {taskh_b, w2all, er, NT, 1};
    EJob jel2 = {fsu_b, l0_ut_al, el2, NU, 0};
    EJob jer2 = {taskh_b, w2all + 2048, er2, NT, 1};
    el_er_multi<<<nbT + nbT + nbU + nbT, 256, 0, stream>>>(jel, jer, jel2, jer2,
                                                           nbT, nbT, nbU, nbT);
  }
  // ---- layer 0: both aggregations in one launch (tt -> obuf_b, ut -> obuf2_b) ----
  gat_fused2<<<nbAgg + nbAgg, 256, 0, stream>>>(
      tt_offs, tt_srcs, el, er, fs_b, l0_tt_bias, l0_ut_bias, obuf_b, NT, nbAgg,
      ut_offs, ut_srcs, el2, er2, fsu_b, obuf2_b, NT);

  // ---- post 0 (head-mean over obuf+obuf2, fused) ----
  gemm_k32hm<<<nbT16, 256, 0, stream>>>(obuf_b, obuf2_b, l0_post_w, l0_post_b, taskh_b, NT);

  // ---- layer 1, tt ----
  gemm_dl<<<nstrT, 256, 0, stream>>>(taskh_b, wt2, nullptr, nullptr, fs_b, NT, 0, nullptr);
  {
    EJob jel = {fs_b, l1_tt_al, el, NT, 0};
    EJob jer = {taskh_b, w2all + 4096, er, NT, 1};
    el_er_multi<<<nbT + nbT, 256, 0, stream>>>(jel, jer, jel, jel, nbT, nbT, 0, 0);
  }
  gat_fused2<<<nbAgg, 256, 0, stream>>>(
      tt_offs, tt_srcs, el, er, fs_b, l1_tt_bias, nullptr, obuf_b, NT, nbAgg,
      tt_offs, tt_srcs, el, er, fs_b, obuf2_b, 0);

  // ---- post 1 ----
  gemm_k32hm<<<nbT16, 256, 0, stream>>>(obuf_b, nullptr, l1_post_w, l1_post_b, taskh_b, NT);

  // ---- decoder (relu, f32 out, fused task column sums into g[256:512]) ----
  gemm_dl<<<nstrT, 256, 0, stream>>>(taskh_b, wt3, task_dec_b, out_task, nullptr, NT, 1, g + 256);

  // ---- global projection (applies 1/NU, 1/NT) ----
  global_proj<<<1, 512, 0, stream>>>(g, gp_w, gp_b, out_glob);
}

// Round 7
// 297.464 us; speedup vs baseline: 3.3501x; 1.1368x over previous
//
#include <hip/hip_runtime.h>
#include <hip/hip_bf16.h>

#define NT 20000
#define NU 2000
#define HID 256
#define HEADS 8
#define FPH 32
#define E_TT 320000
#define E_UT 100000
#define CAP 80

typedef __attribute__((ext_vector_type(8))) short s16x8;
typedef __attribute__((ext_vector_type(4))) short s16x4;
typedef __attribute__((ext_vector_type(4))) float f32x4;

__device__ inline short f2bf(float f) {
  union { float f; unsigned u; } v; v.f = f;
  unsigned r = v.u + 0x7fff + ((v.u >> 16) & 1);
  return (short)(r >> 16);
}
__device__ inline float bf2f(short s) {
  return __uint_as_float(((unsigned)(unsigned short)s) << 16);
}

// ------ prep: 4x weight transpose (f32->bf16 [col][k]) + 3x w2 + zero init ----------
__global__ __launch_bounds__(256) void prep(const float* __restrict__ w0,
                                            const float* __restrict__ w1,
                                            const float* __restrict__ w2_,
                                            const float* __restrict__ w3,
                                            short* __restrict__ o0,
                                            short* __restrict__ o1,
                                            short* __restrict__ o2,
                                            short* __restrict__ o3,
                                            const float* __restrict__ wd0,
                                            const float* __restrict__ ar0,
                                            const float* __restrict__ wd1,
                                            const float* __restrict__ ar1,
                                            const float* __restrict__ wd2,
                                            const float* __restrict__ ar2,
                                            float* __restrict__ w2all,
                                            int* __restrict__ tt_deg,
                                            int* __restrict__ ut_deg,
                                            float* __restrict__ g) {
  int z = blockIdx.z;
  if (z < 4) {
    __shared__ float tile[32][33];
    const float* W = (z == 0) ? w0 : (z == 1) ? w1 : (z == 2) ? w2_ : w3;
    short* Wt = (z == 0) ? o0 : (z == 1) ? o1 : (z == 2) ? o2 : o3;
    int bx = blockIdx.x, by = blockIdx.y;
    int tx = threadIdx.x & 31, ty = threadIdx.x >> 5;
#pragma unroll
    for (int i = 0; i < 32; i += 8)
      tile[ty + i][tx] = W[(by * 32 + ty + i) * 256 + bx * 32 + tx];
    __syncthreads();
#pragma unroll
    for (int i = 0; i < 32; i += 8)
      Wt[(bx * 32 + ty + i) * 256 + by * 32 + tx] = f2bf(tile[tx][ty + i]);
  } else if (z == 4) {
    int flat = (blockIdx.y * 8 + blockIdx.x) * 256 + threadIdx.x;
    if (flat >= 3 * 2048) return;
    int e = flat >> 11, idx = flat & 2047;
    const float* wd = (e == 0) ? wd0 : (e == 1) ? wd1 : wd2;
    const float* ar = (e == 0) ? ar0 : (e == 1) ? ar1 : ar2;
    int k = idx >> 3, h = idx & 7;
    float s = 0.f;
#pragma unroll
    for (int f = 0; f < 32; ++f) s += wd[k * 256 + h * 32 + f] * ar[h * 32 + f];
    w2all[flat] = s;
  } else {
    int flat = (blockIdx.y * 8 + blockIdx.x) * 256 + threadIdx.x;  // 0..16383
    for (int i = flat; i < NT; i += 16384) { tt_deg[i] = 0; ut_deg[i] = 0; }
    if (flat < 512) g[flat] = 0.f;
  }
}

// ---- deg count (both graphs) + er-projection matrices M[3][32][8], c[3][8] ---------
__global__ void deg2M(const int* __restrict__ tt_dst, const int* __restrict__ ut_dst,
                      int* __restrict__ tt_deg, int* __restrict__ ut_deg,
                      const float* __restrict__ task_enc_w,
                      const float* __restrict__ task_enc_b,
                      const float* __restrict__ l0_post_w,
                      const float* __restrict__ l0_post_b,
                      const float* __restrict__ w2all,
                      float* __restrict__ M, float* __restrict__ c) {
  int e = blockIdx.x * 256 + threadIdx.x;
  if (e < E_TT) atomicAdd(&tt_deg[tt_dst[e]], 1);
  int e2 = e - E_TT;
  if (e2 >= 0 && e2 < E_UT) atomicAdd(&ut_deg[ut_dst[e2]], 1);
  if (e < 768) {
    int et = e >> 8, j = (e >> 3) & 31, h = e & 7;
    const float* W = (et == 2) ? l0_post_w : task_enc_w;
    const float* w2p = w2all + et * 2048;
    float s = 0.f;
    for (int k = 0; k < 256; ++k) s += W[j * 256 + k] * w2p[k * 8 + h];
    M[e] = s;
  } else if (e < 792) {
    int idx = e - 768, et = idx >> 3, h = idx & 7;
    const float* b = (et == 2) ? l0_post_b : task_enc_b;
    const float* w2p = w2all + et * 2048;
    float s = 0.f;
    for (int k = 0; k < 256; ++k) s += b[k] * w2p[k * 8 + h];
    c[idx] = s;
  }
}

// ---------------- K=32 GEMM body (+ optional colsum, + optional er epilogue) --------
__device__ inline void k32_body(const float* __restrict__ A, const float* __restrict__ W,
                                const float* __restrict__ bias, float* __restrict__ Cf,
                                short* __restrict__ Cb, int N, int blk,
                                float* __restrict__ gsum,
                                const float* __restrict__ M, const float* __restrict__ c,
                                float* __restrict__ er0, float* __restrict__ er1) {
  __shared__ float Ws[32][256];
  __shared__ float Ar[16][32];
  int tid = threadIdx.x;
  for (int i = tid; i < 32 * 256; i += 256) Ws[i >> 8][i & 255] = W[i];
  int n0 = blk * 16;
  int nrows = min(16, N - n0);
  for (int i = tid; i < 512; i += 256) {
    int r = i >> 5, k = i & 31;
    if (r < nrows) Ar[r][k] = A[(size_t)(n0 + r) * 32 + k];
  }
  __syncthreads();
  float b = bias[tid];
  float colacc = 0.f;
  for (int r = 0; r < nrows; ++r) {
    float acc = b;
#pragma unroll
    for (int k = 0; k < 32; ++k) acc += Ar[r][k] * Ws[k][tid];
    size_t o = (size_t)(n0 + r) * 256 + tid;
    if (Cf) Cf[o] = acc;
    if (Cb) Cb[o] = f2bf(acc);
    colacc += acc;
  }
  if (gsum) atomicAdd(&gsum[tid], colacc);
  if (er0) {
    int r = tid >> 4, e = (tid >> 3) & 1, h = tid & 7;
    int n = n0 + r;
    if (r < nrows) {
      const float* Mp = M + e * 256;
      float s = c[e * 8 + h];
#pragma unroll
      for (int j = 0; j < 32; ++j) s += Ar[r][j] * Mp[j * 8 + h];
      (e ? er1 : er0)[n * 8 + h] = s;
    }
  }
}

// merged encoders: usv blocks then task blocks (task part also emits er, er2)
__global__ __launch_bounds__(256) void enc_gemm(const float* __restrict__ uf,
                                                const float* __restrict__ uw,
                                                const float* __restrict__ ub,
                                                float* __restrict__ out_usv,
                                                short* __restrict__ usvh_b,
                                                const float* __restrict__ tf,
                                                const float* __restrict__ tw,
                                                const float* __restrict__ tb,
                                                short* __restrict__ taskh_b,
                                                float* __restrict__ g,
                                                const float* __restrict__ M,
                                                const float* __restrict__ c,
                                                float* __restrict__ er,
                                                float* __restrict__ er2, int nbU) {
  int b = blockIdx.x;
  if (b < nbU)
    k32_body(uf, uw, ub, out_usv, usvh_b, NU, b, g, nullptr, nullptr, nullptr, nullptr);
  else
    k32_body(tf, tw, tb, nullptr, taskh_b, NT, b - nbU, nullptr, M, c, er, er2);
}

// ---- fused head-mean + K=32 GEMM -> bf16 (bf16 obuf inputs, optional er for L1) ----
__global__ __launch_bounds__(256) void gemm_k32hm(const short* __restrict__ obuf,
                                                  const short* __restrict__ obuf2,
                                                  const float* __restrict__ W,
                                                  const float* __restrict__ bias,
                                                  short* __restrict__ Cb, int N,
                                                  const float* __restrict__ M1,
                                                  const float* __restrict__ c1,
                                                  float* __restrict__ erOut) {
  __shared__ float Ws[32][256];
  __shared__ float Ar[16][32];
  int tid = threadIdx.x;
  for (int i = tid; i < 32 * 256; i += 256) Ws[i >> 8][i & 255] = W[i];
  int n0 = blockIdx.x * 16;
  for (int i = tid; i < 512; i += 256) {
    int r = i >> 5, f = i & 31;
    int n = n0 + r;
    float s = 0.f;
    if (n < N) {
#pragma unroll
      for (int h = 0; h < 8; ++h) s += bf2f(obuf[(size_t)n * 256 + h * 32 + f]);
      if (obuf2) {
#pragma unroll
        for (int h = 0; h < 8; ++h) s += bf2f(obuf2[(size_t)n * 256 + h * 32 + f]);
      }
    }
    Ar[r][f] = s * 0.125f;
  }
  __syncthreads();
  float b = bias[tid];
  int nrows = min(16, N - n0);
  for (int r = 0; r < nrows; ++r) {
    float acc = b;
#pragma unroll
    for (int k = 0; k < 32; ++k) acc += Ar[r][k] * Ws[k][tid];
    Cb[(size_t)(n0 + r) * 256 + tid] = f2bf(acc);
  }
  if (erOut && tid < 128) {
    int r = tid >> 3, h = tid & 7;
    int n = n0 + r;
    if (r < nrows) {
      float s = c1[h];
#pragma unroll
      for (int j = 0; j < 32; ++j) s += Ar[r][j] * M1[j * 8 + h];
      erOut[n * 8 + h] = s;
    }
  }
}

// ---- direct-load MFMA GEMM: no LDS, wave = 32 rows x 64 cols; optional el epilogue --
__device__ inline void gemm_dl_body(const short* __restrict__ A,
                                    const short* __restrict__ Wt,
                                    const float* __restrict__ bias,
                                    float* __restrict__ Cf, short* __restrict__ Cb,
                                    int N, int relu, float* __restrict__ gsum,
                                    const float* __restrict__ elW,
                                    float* __restrict__ elOut,
                                    int strip) {
  int lane = threadIdx.x & 63;
  int wv = threadIdx.x >> 6;
  int fr = lane & 15, fq = lane >> 4;
  int row0 = strip * 32;
  int col0 = wv * 64;

  f32x4 acc[2][4];
#pragma unroll
  for (int m = 0; m < 2; ++m)
#pragma unroll
    for (int n = 0; n < 4; ++n) acc[m][n] = (f32x4){0.f, 0.f, 0.f, 0.f};

  const int gr0 = row0 + fr, gr1 = row0 + 16 + fr;
  const bool v0 = gr0 < N, v1 = gr1 < N;
  const short* pa0 = A + (size_t)gr0 * 256 + fq * 8;
  const short* pa1 = A + (size_t)gr1 * 256 + fq * 8;
  const short* pb = Wt + (size_t)(col0 + fr) * 256 + fq * 8;

#pragma unroll
  for (int k0 = 0; k0 < 256; k0 += 32) {
    s16x8 a0 = v0 ? *(const s16x8*)(pa0 + k0) : (s16x8){0,0,0,0,0,0,0,0};
    s16x8 a1 = v1 ? *(const s16x8*)(pa1 + k0) : (s16x8){0,0,0,0,0,0,0,0};
    s16x8 b0 = *(const s16x8*)(pb + k0);
    s16x8 b1 = *(const s16x8*)(pb + 16 * 256 + k0);
    s16x8 b2 = *(const s16x8*)(pb + 32 * 256 + k0);
    s16x8 b3 = *(const s16x8*)(pb + 48 * 256 + k0);
    acc[0][0] = __builtin_amdgcn_mfma_f32_16x16x32_bf16(a0, b0, acc[0][0], 0, 0, 0);
    acc[0][1] = __builtin_amdgcn_mfma_f32_16x16x32_bf16(a0, b1, acc[0][1], 0, 0, 0);
    acc[0][2] = __builtin_amdgcn_mfma_f32_16x16x32_bf16(a0, b2, acc[0][2], 0, 0, 0);
    acc[0][3] = __builtin_amdgcn_mfma_f32_16x16x32_bf16(a0, b3, acc[0][3], 0, 0, 0);
    acc[1][0] = __builtin_amdgcn_mfma_f32_16x16x32_bf16(a1, b0, acc[1][0], 0, 0, 0);
    acc[1][1] = __builtin_amdgcn_mfma_f32_16x16x32_bf16(a1, b1, acc[1][1], 0, 0, 0);
    acc[1][2] = __builtin_amdgcn_mfma_f32_16x16x32_bf16(a1, b2, acc[1][2], 0, 0, 0);
    acc[1][3] = __builtin_amdgcn_mfma_f32_16x16x32_bf16(a1, b3, acc[1][3], 0, 0, 0);
  }

  // el epilogue: wave covers heads 2wv, 2wv+1; reduce acc*al over the 16 fr lanes
  if (elOut) {
    float al0 = elW[(2 * wv + 0) * 32 + fr];
    float al1 = elW[(2 * wv + 0) * 32 + 16 + fr];
    float al2 = elW[(2 * wv + 1) * 32 + fr];
    float al3 = elW[(2 * wv + 1) * 32 + 16 + fr];
#pragma unroll
    for (int m = 0; m < 2; ++m) {
#pragma unroll
      for (int r = 0; r < 4; ++r) {
        int row = row0 + m * 16 + fq * 4 + r;
        float p0 = acc[m][0][r] * al0 + acc[m][1][r] * al1;
        float p1 = acc[m][2][r] * al2 + acc[m][3][r] * al3;
        p0 += __shfl_xor(p0, 1); p0 += __shfl_xor(p0, 2);
        p0 += __shfl_xor(p0, 4); p0 += __shfl_xor(p0, 8);
        p1 += __shfl_xor(p1, 1); p1 += __shfl_xor(p1, 2);
        p1 += __shfl_xor(p1, 4); p1 += __shfl_xor(p1, 8);
        if (fr == 0 && row < N) {
          elOut[row * 8 + 2 * wv] = p0;
          elOut[row * 8 + 2 * wv + 1] = p1;
        }
      }
    }
  }

  float bv[4];
#pragma unroll
  for (int n = 0; n < 4; ++n) bv[n] = bias ? bias[col0 + n * 16 + fr] : 0.f;

  float csum[4] = {0.f, 0.f, 0.f, 0.f};
#pragma unroll
  for (int m = 0; m < 2; ++m) {
    int grb = row0 + m * 16 + fq * 4;
#pragma unroll
    for (int r = 0; r < 4; ++r) {
      if (grb + r >= N) continue;
#pragma unroll
      for (int n = 0; n < 4; ++n) {
        float v = acc[m][n][r] + bv[n];
        if (relu) v = fmaxf(v, 0.f);
        size_t o = (size_t)(grb + r) * 256 + col0 + n * 16 + fr;
        if (Cf) Cf[o] = v;
        if (Cb) Cb[o] = f2bf(v);
        csum[n] += v;
      }
    }
  }
  if (gsum) {
#pragma unroll
    for (int n = 0; n < 4; ++n) {
      float s = csum[n];
      s += __shfl_xor(s, 16);
      s += __shfl_xor(s, 32);
      if (fq == 0) atomicAdd(&gsum[col0 + n * 16 + fr], s);
    }
  }
}

__global__ __launch_bounds__(256) void gemm_dl(const short* __restrict__ A,
                                               const short* __restrict__ Wt,
                                               const float* __restrict__ bias,
                                               float* __restrict__ Cf,
                                               short* __restrict__ Cb,
                                               int N, int relu, float* __restrict__ gsum,
                                               const float* __restrict__ elW,
                                               float* __restrict__ elOut) {
  gemm_dl_body(A, Wt, bias, Cf, Cb, N, relu, gsum, elW, elOut, blockIdx.x);
}

// layer-0 dual: tt strips then ut strips (both with el epilogues)
__global__ __launch_bounds__(256) void gemm_dl_dual(const short* __restrict__ A0,
                                                    const short* __restrict__ Wt0,
                                                    short* __restrict__ C0,
                                                    const float* __restrict__ elW0,
                                                    float* __restrict__ el0,
                                                    const short* __restrict__ A1,
                                                    const short* __restrict__ Wt1,
                                                    short* __restrict__ C1,
                                                    const float* __restrict__ elW1,
                                                    float* __restrict__ el1,
                                                    int nstr0) {
  if ((int)blockIdx.x < nstr0)
    gemm_dl_body(A0, Wt0, nullptr, nullptr, C0, NT, 0, nullptr, elW0, el0, blockIdx.x);
  else
    gemm_dl_body(A1, Wt1, nullptr, nullptr, C1, NU, 0, nullptr, elW1, el1, blockIdx.x - nstr0);
}

// ---------------- CSR scan + scatter ----------------
__global__ __launch_bounds__(1024) void scan2(const int* __restrict__ d0, int* __restrict__ o0,
                                              int* __restrict__ c0,
                                              const int* __restrict__ d1, int* __restrict__ o1,
                                              int* __restrict__ c1, int n) {
  const int* deg = blockIdx.x ? d1 : d0;
  int* off = blockIdx.x ? o1 : o0;
  int* cursor = blockIdx.x ? c1 : c0;
  int tid = threadIdx.x;
  const int C = 20;
  int base = tid * C;
  int local[C];
  int s = 0;
#pragma unroll
  for (int i = 0; i < C; ++i) {
    int idx = base + i;
    int v = (idx < n) ? deg[idx] : 0;
    local[i] = s;
    s += v;
  }
  int lane = tid & 63, wave = tid >> 6;
  int x = s;
#pragma unroll
  for (int d = 1; d < 64; d <<= 1) {
    int y = __shfl_up(x, d, 64);
    if (lane >= d) x += y;
  }
  __shared__ int wsum[16];
  if (lane == 63) wsum[wave] = x;
  __syncthreads();
  if (wave == 0) {
    int wv = (lane < 16) ? wsum[lane] : 0;
#pragma unroll
    for (int d = 1; d < 16; d <<= 1) {
      int y = __shfl_up(wv, d, 64);
      if (lane >= d) wv += y;
    }
    if (lane < 16) wsum[lane] = wv;
  }
  __syncthreads();
  int waveoff = (wave == 0) ? 0 : wsum[wave - 1];
  int excl = waveoff + x - s;
#pragma unroll
  for (int i = 0; i < C; ++i) {
    int idx = base + i;
    if (idx < n) {
      int o = excl + local[i];
      off[idx] = o;
      cursor[idx] = o;
    }
  }
  if (tid == 1023) off[n] = waveoff + x;
}

__global__ void scat2(const int* __restrict__ tt_src, const int* __restrict__ tt_dst,
                      int* __restrict__ tt_cur, int* __restrict__ tt_srcs,
                      const int* __restrict__ ut_src, const int* __restrict__ ut_dst,
                      int* __restrict__ ut_cur, int* __restrict__ ut_srcs) {
  int e = blockIdx.x * 256 + threadIdx.x;
  if (e < E_TT) {
    int p = atomicAdd(&tt_cur[tt_dst[e]], 1);
    tt_srcs[p] = tt_src[e];
  }
  int e2 = e - E_TT;
  if (e2 >= 0 && e2 < E_UT) {
    int p = atomicAdd(&ut_cur[ut_dst[e2]], 1);
    ut_srcs[p] = ut_src[e2];
  }
}

// -------- fused softmax + aggregation, wave/node, LDS-cached weights, 4x unroll -----
__device__ inline float gat_w(const float* __restrict__ el, int src, int h,
                              float ern, float mh) {
  float l = el[src * 8 + h] + ern;
  l = l >= 0.f ? l : 0.2f * l;
  return __expf(l - mh);
}

__device__ inline void gat_body(const int* __restrict__ offs, const int* __restrict__ srcs,
                                const float* __restrict__ el, const float* __restrict__ er,
                                const short* __restrict__ fsb,
                                const float* __restrict__ bias0,
                                const float* __restrict__ bias1,
                                short* __restrict__ out, int n, float (*wl)[8]) {
  int lane = threadIdx.x & 63;
  int e0 = offs[n], e1 = offs[n + 1];
  s16x4* po = (s16x4*)(out + (size_t)n * 256 + lane * 4);
  if (e0 == e1) {
    float4 o = {0.f, 0.f, 0.f, 0.f};
    if (bias0) {
      o = *(const float4*)(bias0 + lane * 4);
      if (bias1) {
        float4 b1 = *(const float4*)(bias1 + lane * 4);
        o.x += b1.x; o.y += b1.y; o.z += b1.z; o.w += b1.w;
      }
    }
    *po = (s16x4){f2bf(o.x), f2bf(o.y), f2bf(o.z), f2bf(o.w)};
    return;
  }
  int h1 = lane & 7, slot = lane >> 3;
  float ern1 = er[n * 8 + h1];
  float m = -3.4e38f;
  for (int i = e0 + slot; i < e1; i += 8) {
    float l = el[srcs[i] * 8 + h1] + ern1;
    l = l >= 0.f ? l : 0.2f * l;
    int idx = i - e0;
    if (idx < CAP) wl[idx][h1] = l;
    m = fmaxf(m, l);
  }
  m = fmaxf(m, __shfl_xor(m, 8));
  m = fmaxf(m, __shfl_xor(m, 16));
  m = fmaxf(m, __shfl_xor(m, 32));
  float s = 0.f;
  for (int i = e0 + slot; i < e1; i += 8) {
    int idx = i - e0;
    float l;
    if (idx < CAP) l = wl[idx][h1];
    else {
      l = el[srcs[i] * 8 + h1] + ern1;
      l = l >= 0.f ? l : 0.2f * l;
    }
    float w = __expf(l - m);
    if (idx < CAP) wl[idx][h1] = w;
    s += w;
  }
  s += __shfl_xor(s, 8);
  s += __shfl_xor(s, 16);
  s += __shfl_xor(s, 32);
  int h2 = lane >> 3;
  float mh = __shfl(m, h2);
  float sh = __shfl(s, h2);
  float ern2 = __shfl(ern1, h2);
  float ax = 0.f, ay = 0.f, az = 0.f, aw = 0.f;
  int i = e0;
  for (; i + 4 <= e1; i += 4) {
    int s0 = srcs[i], s1 = srcs[i + 1], s2 = srcs[i + 2], s3 = srcs[i + 3];
    s16x4 v0 = *(const s16x4*)(fsb + (size_t)s0 * 256 + lane * 4);
    s16x4 v1 = *(const s16x4*)(fsb + (size_t)s1 * 256 + lane * 4);
    s16x4 v2 = *(const s16x4*)(fsb + (size_t)s2 * 256 + lane * 4);
    s16x4 v3 = *(const s16x4*)(fsb + (size_t)s3 * 256 + lane * 4);
    int idx = i - e0;
    float w0, w1, w2, w3;
    if (idx + 3 < CAP) {
      w0 = wl[idx][h2]; w1 = wl[idx + 1][h2];
      w2 = wl[idx + 2][h2]; w3 = wl[idx + 3][h2];
    } else {
      w0 = (idx < CAP) ? wl[idx][h2] : gat_w(el, s0, h2, ern2, mh);
      w1 = (idx + 1 < CAP) ? wl[idx + 1][h2] : gat_w(el, s1, h2, ern2, mh);
      w2 = (idx + 2 < CAP) ? wl[idx + 2][h2] : gat_w(el, s2, h2, ern2, mh);
      w3 = gat_w(el, s3, h2, ern2, mh);
    }
    ax += w0 * bf2f(v0[0]) + w1 * bf2f(v1[0]) + w2 * bf2f(v2[0]) + w3 * bf2f(v3[0]);
    ay += w0 * bf2f(v0[1]) + w1 * bf2f(v1[1]) + w2 * bf2f(v2[1]) + w3 * bf2f(v3[1]);
    az += w0 * bf2f(v0[2]) + w1 * bf2f(v1[2]) + w2 * bf2f(v2[2]) + w3 * bf2f(v3[2]);
    aw += w0 * bf2f(v0[3]) + w1 * bf2f(v1[3]) + w2 * bf2f(v2[3]) + w3 * bf2f(v3[3]);
  }
  for (; i < e1; ++i) {
    int src = srcs[i];
    int idx = i - e0;
    float w = (idx < CAP) ? wl[idx][h2] : gat_w(el, src, h2, ern2, mh);
    s16x4 v = *(const s16x4*)(fsb + (size_t)src * 256 + lane * 4);
    ax += w * bf2f(v[0]);
    ay += w * bf2f(v[1]);
    az += w * bf2f(v[2]);
    aw += w * bf2f(v[3]);
  }
  float sinv = 1.f / sh;
  float4 o = {ax * sinv, ay * sinv, az * sinv, aw * sinv};
  if (bias0) {
    float4 b = *(const float4*)(bias0 + lane * 4);
    o.x += b.x; o.y += b.y; o.z += b.z; o.w += b.w;
    if (bias1) {
      float4 b1 = *(const float4*)(bias1 + lane * 4);
      o.x += b1.x; o.y += b1.y; o.z += b1.z; o.w += b1.w;
    }
  }
  *po = (s16x4){f2bf(o.x), f2bf(o.y), f2bf(o.z), f2bf(o.w)};
}

__global__ __launch_bounds__(256) void gat_fused2(
    const int* __restrict__ oA, const int* __restrict__ sA,
    const float* __restrict__ elA, const float* __restrict__ erA,
    const short* __restrict__ fA,
    const float* __restrict__ b0A, const float* __restrict__ b1A,
    short* __restrict__ outA, int ndstA, int nA,
    const int* __restrict__ oB, const int* __restrict__ sB,
    const float* __restrict__ elB, const float* __restrict__ erB,
    const short* __restrict__ fB, short* __restrict__ outB, int ndstB) {
  __shared__ float wlds[4][CAP][8];
  int wv = threadIdx.x >> 6;
  int b = blockIdx.x;
  if (b < nA) {
    int n = b * 4 + wv;
    if (n >= ndstA) return;
    gat_body(oA, sA, elA, erA, fA, b0A, b1A, outA, n, wlds[wv]);
  } else {
    int n = (b - nA) * 4 + wv;
    if (n >= ndstB) return;
    gat_body(oB, sB, elB, erB, fB, nullptr, nullptr, outB, n, wlds[wv]);
  }
}

// ---------------- global projection (with mean scaling) ----------------
__global__ __launch_bounds__(512) void global_proj(const float* __restrict__ g,
                                                   const float* __restrict__ W,
                                                   const float* __restrict__ b,
                                                   float* __restrict__ out) {
  __shared__ float gl[512];
  int tid = threadIdx.x;
  gl[tid] = g[tid] * (tid < 256 ? (1.f / NU) : (1.f / NT));
  __syncthreads();
  float s = b[tid];
  for (int k = 0; k < 512; ++k) s += gl[k] * W[k * 512 + tid];
  out[tid] = s;
}

extern "C" void kernel_launch(void* const* d_in, const int* in_sizes, int n_in,
                              void* d_out, int out_size, void* d_ws, size_t ws_size,
                              hipStream_t stream) {
  const float* usv_feat   = (const float*)d_in[0];
  const float* task_feat  = (const float*)d_in[1];
  const float* usv_enc_w  = (const float*)d_in[2];
  const float* usv_enc_b  = (const float*)d_in[3];
  const float* task_enc_w = (const float*)d_in[4];
  const float* task_enc_b = (const float*)d_in[5];
  const float* l0_tt_wsrc = (const float*)d_in[6];
  const float* l0_tt_wdst = (const float*)d_in[7];
  const float* l0_tt_al   = (const float*)d_in[8];
  const float* l0_tt_ar   = (const float*)d_in[9];
  const float* l0_tt_bias = (const float*)d_in[10];
  const float* l0_ut_wsrc = (const float*)d_in[11];
  const float* l0_ut_wdst = (const float*)d_in[12];
  const float* l0_ut_al   = (const float*)d_in[13];
  const float* l0_ut_ar   = (const float*)d_in[14];
  const float* l0_ut_bias = (const float*)d_in[15];
  const float* l0_post_w  = (const float*)d_in[16];
  const float* l0_post_b  = (const float*)d_in[17];
  const float* l1_tt_wsrc = (const float*)d_in[18];
  const float* l1_tt_wdst = (const float*)d_in[19];
  const float* l1_tt_al   = (const float*)d_in[20];
  const float* l1_tt_ar   = (const float*)d_in[21];
  const float* l1_tt_bias = (const float*)d_in[22];
  const float* l1_post_w  = (const float*)d_in[23];
  const float* l1_post_b  = (const float*)d_in[24];
  const float* task_dec_w = (const float*)d_in[25];
  const float* task_dec_b = (const float*)d_in[26];
  const float* gp_w       = (const float*)d_in[27];
  const float* gp_b       = (const float*)d_in[28];
  const int* tt_src = (const int*)d_in[29];
  const int* tt_dst = (const int*)d_in[30];
  const int* ut_src = (const int*)d_in[31];
  const int* ut_dst = (const int*)d_in[32];

  float* out = (float*)d_out;
  float* out_usv  = out;
  float* out_task = out + NU * HID;
  float* out_glob = out + NU * HID + NT * HID;

  char* ws = (char*)d_ws;
  size_t off = 0;
  auto alloc_f = [&](size_t n) {
    float* p = (float*)(ws + off);
    off += ((n * 4 + 1023) / 1024) * 1024;
    return p;
  };
  auto alloc_i = [&](size_t n) {
    int* p = (int*)(ws + off);
    off += ((n * 4 + 1023) / 1024) * 1024;
    return p;
  };
  auto alloc_s = [&](size_t n) {
    short* p = (short*)(ws + off);
    off += ((n * 2 + 1023) / 1024) * 1024;
    return p;
  };
  short* taskh_b = alloc_s((size_t)NT * HID);
  short* usvh_b  = alloc_s((size_t)NU * HID);
  short* fs_b    = alloc_s((size_t)NT * HID);
  short* fsu_b   = alloc_s((size_t)NU * HID);
  short* obuf_b  = alloc_s((size_t)NT * HID);
  short* obuf2_b = alloc_s((size_t)NT * HID);
  float* el    = alloc_f((size_t)NT * HEADS);
  float* er    = alloc_f((size_t)NT * HEADS);
  float* el2   = alloc_f((size_t)NU * HEADS);
  float* er2   = alloc_f((size_t)NT * HEADS);
  float* w2all = alloc_f(3 * 2048);
  float* g     = alloc_f(512);
  float* Mbuf  = alloc_f(768);
  float* cbuf  = alloc_f(24);
  short* wt0 = alloc_s(256 * 256);
  short* wt1 = alloc_s(256 * 256);
  short* wt2 = alloc_s(256 * 256);
  short* wt3 = alloc_s(256 * 256);
  int* tt_deg  = alloc_i(NT);
  int* tt_offs = alloc_i(NT + 1);
  int* tt_cur  = alloc_i(NT);
  int* tt_srcs = alloc_i(E_TT);
  int* ut_deg  = alloc_i(NT);
  int* ut_offs = alloc_i(NT + 1);
  int* ut_cur  = alloc_i(NT);
  int* ut_srcs = alloc_i(E_UT);

  // 1) transposes + w2 + zero init
  prep<<<dim3(8, 8, 6), 256, 0, stream>>>(l0_tt_wsrc, l0_ut_wsrc, l1_tt_wsrc, task_dec_w,
                                          wt0, wt1, wt2, wt3,
                                          l0_tt_wdst, l0_tt_ar, l0_ut_wdst, l0_ut_ar,
                                          l1_tt_wdst, l1_tt_ar, w2all,
                                          tt_deg, ut_deg, g);

  // 2) degree count + er-projection matrices
  int nbE = (E_TT + E_UT + 255) / 256;
  deg2M<<<nbE, 256, 0, stream>>>(tt_dst, ut_dst, tt_deg, ut_deg,
                                 task_enc_w, task_enc_b, l0_post_w, l0_post_b,
                                 w2all, Mbuf, cbuf);

  // 3-4) CSR scan + scatter
  scan2<<<2, 1024, 0, stream>>>(tt_deg, tt_offs, tt_cur, ut_deg, ut_offs, ut_cur, NT);
  scat2<<<nbE, 256, 0, stream>>>(tt_src, tt_dst, tt_cur, tt_srcs, ut_src, ut_dst, ut_cur, ut_srcs);

  // 5) encoders (usv: colsum into g; task: er, er2 epilogue)
  int nbU16 = (NU + 15) / 16, nbT16 = (NT + 15) / 16;
  enc_gemm<<<nbU16 + nbT16, 256, 0, stream>>>(usv_feat, usv_enc_w, usv_enc_b, out_usv, usvh_b,
                                              task_feat, task_enc_w, task_enc_b, taskh_b,
                                              g, Mbuf, cbuf, er, er2, nbU16);

  int nstrT = (NT + 31) / 32, nstrU = (NU + 31) / 32;
  int nbAgg = (NT + 3) / 4;

  // 6) layer 0: both GEMMs + el/el2 epilogues
  gemm_dl_dual<<<nstrT + nstrU, 256, 0, stream>>>(taskh_b, wt0, fs_b, l0_tt_al, el,
                                                  usvh_b, wt1, fsu_b, l0_ut_al, el2, nstrT);

  // 7) layer 0: both aggregations (tt -> obuf_b, ut -> obuf2_b)
  gat_fused2<<<nbAgg + nbAgg, 256, 0, stream>>>(
      tt_offs, tt_srcs, el, er, fs_b, l0_tt_bias, l0_ut_bias, obuf_b, NT, nbAgg,
      ut_offs, ut_srcs, el2, er2, fsu_b, obuf2_b, NT);

  // 8) post 0 (head-mean fused) + er for layer 1
  gemm_k32hm<<<nbT16, 256, 0, stream>>>(obuf_b, obuf2_b, l0_post_w, l0_post_b, taskh_b, NT,
                                        Mbuf + 512, cbuf + 16, er);

  // 9) layer 1 GEMM + el epilogue
  gemm_dl<<<nstrT, 256, 0, stream>>>(taskh_b, wt2, nullptr, nullptr, fs_b, NT, 0, nullptr,
                                     l1_tt_al, el);

  // 10) layer 1 aggregation
  gat_fused2<<<nbAgg, 256, 0, stream>>>(
      tt_offs, tt_srcs, el, er, fs_b, l1_tt_bias, nullptr, obuf_b, NT, nbAgg,
      tt_offs, tt_srcs, el, er, fs_b, obuf2_b, 0);

  // 11) post 1
  gemm_k32hm<<<nbT16, 256, 0, stream>>>(obuf_b, nullptr, l1_post_w, l1_post_b, taskh_b, NT,
                                        nullptr, nullptr, nullptr);

  // 12) decoder (relu, f32 out, fused task column sums)
  gemm_dl<<<nstrT, 256, 0, stream>>>(taskh_b, wt3, task_dec_b, out_task, nullptr, NT, 1, g + 256,
                                     nullptr, nullptr);

  // 13) global projection
  global_proj<<<1, 512, 0, stream>>>(g, gp_w, gp_b, out_glob);
}

// Round 8
// 287.812 us; speedup vs baseline: 3.4624x; 1.0335x over previous
//
#include <hip/hip_runtime.h>
#include <hip/hip_bf16.h>

#define NT 20000
#define NU 2000
#define HID 256
#define HEADS 8
#define FPH 32
#define E_TT 320000
#define E_UT 100000
#define CAP 80

typedef __attribute__((ext_vector_type(8))) short s16x8;
typedef __attribute__((ext_vector_type(4))) short s16x4;
typedef __attribute__((ext_vector_type(4))) float f32x4;
typedef __attribute__((ext_vector_type(2))) float f32x2;

__device__ inline short f2bf(float f) {
  union { float f; unsigned u; } v; v.f = f;
  unsigned r = v.u + 0x7fff + ((v.u >> 16) & 1);
  return (short)(r >> 16);
}
__device__ inline float bf2f(short s) {
  return __uint_as_float(((unsigned)(unsigned short)s) << 16);
}
__device__ inline unsigned char f2q(float f) {
  return (unsigned char)(__builtin_amdgcn_cvt_pk_fp8_f32(f, f, 0, false) & 0xff);
}

// ------ prep: 4x weight transpose (f32->bf16 [col][k]) + 3x w2 + zero init ----------
__global__ __launch_bounds__(256) void prep(const float* __restrict__ w0,
                                            const float* __restrict__ w1,
                                            const float* __restrict__ w2_,
                                            const float* __restrict__ w3,
                                            short* __restrict__ o0,
                                            short* __restrict__ o1,
                                            short* __restrict__ o2,
                                            short* __restrict__ o3,
                                            const float* __restrict__ wd0,
                                            const float* __restrict__ ar0,
                                            const float* __restrict__ wd1,
                                            const float* __restrict__ ar1,
                                            const float* __restrict__ wd2,
                                            const float* __restrict__ ar2,
                                            float* __restrict__ w2all,
                                            int* __restrict__ tt_deg,
                                            int* __restrict__ ut_deg,
                                            float* __restrict__ g) {
  int z = blockIdx.z;
  if (z < 4) {
    __shared__ float tile[32][33];
    const float* W = (z == 0) ? w0 : (z == 1) ? w1 : (z == 2) ? w2_ : w3;
    short* Wt = (z == 0) ? o0 : (z == 1) ? o1 : (z == 2) ? o2 : o3;
    int bx = blockIdx.x, by = blockIdx.y;
    int tx = threadIdx.x & 31, ty = threadIdx.x >> 5;
#pragma unroll
    for (int i = 0; i < 32; i += 8)
      tile[ty + i][tx] = W[(by * 32 + ty + i) * 256 + bx * 32 + tx];
    __syncthreads();
#pragma unroll
    for (int i = 0; i < 32; i += 8)
      Wt[(bx * 32 + ty + i) * 256 + by * 32 + tx] = f2bf(tile[tx][ty + i]);
  } else if (z == 4) {
    int flat = (blockIdx.y * 8 + blockIdx.x) * 256 + threadIdx.x;
    if (flat >= 3 * 2048) return;
    int e = flat >> 11, idx = flat & 2047;
    const float* wd = (e == 0) ? wd0 : (e == 1) ? wd1 : wd2;
    const float* ar = (e == 0) ? ar0 : (e == 1) ? ar1 : ar2;
    int k = idx >> 3, h = idx & 7;
    float s = 0.f;
#pragma unroll
    for (int f = 0; f < 32; ++f) s += wd[k * 256 + h * 32 + f] * ar[h * 32 + f];
    w2all[flat] = s;
  } else {
    int flat = (blockIdx.y * 8 + blockIdx.x) * 256 + threadIdx.x;  // 0..16383
    for (int i = flat; i < NT; i += 16384) { tt_deg[i] = 0; ut_deg[i] = 0; }
    if (flat < 512) g[flat] = 0.f;
  }
}

// ---- deg count (both graphs) + er-projection matrices M[3][32][8], c[3][8] ---------
__global__ void deg2M(const int* __restrict__ tt_dst, const int* __restrict__ ut_dst,
                      int* __restrict__ tt_deg, int* __restrict__ ut_deg,
                      const float* __restrict__ task_enc_w,
                      const float* __restrict__ task_enc_b,
                      const float* __restrict__ l0_post_w,
                      const float* __restrict__ l0_post_b,
                      const float* __restrict__ w2all,
                      float* __restrict__ M, float* __restrict__ c) {
  int e = blockIdx.x * 256 + threadIdx.x;
  if (e < E_TT) atomicAdd(&tt_deg[tt_dst[e]], 1);
  int e2 = e - E_TT;
  if (e2 >= 0 && e2 < E_UT) atomicAdd(&ut_deg[ut_dst[e2]], 1);
  if (e < 768) {
    int et = e >> 8, j = (e >> 3) & 31, h = e & 7;
    const float* W = (et == 2) ? l0_post_w : task_enc_w;
    const float* w2p = w2all + et * 2048;
    float s = 0.f;
    for (int k = 0; k < 256; ++k) s += W[j * 256 + k] * w2p[k * 8 + h];
    M[e] = s;
  } else if (e < 792) {
    int idx = e - 768, et = idx >> 3, h = idx & 7;
    const float* b = (et == 2) ? l0_post_b : task_enc_b;
    const float* w2p = w2all + et * 2048;
    float s = 0.f;
    for (int k = 0; k < 256; ++k) s += b[k] * w2p[k * 8 + h];
    c[idx] = s;
  }
}

// ---------------- K=32 GEMM body (+ optional colsum, + optional er epilogue) --------
__device__ inline void k32_body(const float* __restrict__ A, const float* __restrict__ W,
                                const float* __restrict__ bias, float* __restrict__ Cf,
                                short* __restrict__ Cb, int N, int blk,
                                float* __restrict__ gsum,
                                const float* __restrict__ M, const float* __restrict__ c,
                                float* __restrict__ er0, float* __restrict__ er1) {
  __shared__ float Ws[32][256];
  __shared__ float Ar[16][32];
  int tid = threadIdx.x;
  for (int i = tid; i < 32 * 256; i += 256) Ws[i >> 8][i & 255] = W[i];
  int n0 = blk * 16;
  int nrows = min(16, N - n0);
  for (int i = tid; i < 512; i += 256) {
    int r = i >> 5, k = i & 31;
    if (r < nrows) Ar[r][k] = A[(size_t)(n0 + r) * 32 + k];
  }
  __syncthreads();
  float b = bias[tid];
  float colacc = 0.f;
  for (int r = 0; r < nrows; ++r) {
    float acc = b;
#pragma unroll
    for (int k = 0; k < 32; ++k) acc += Ar[r][k] * Ws[k][tid];
    size_t o = (size_t)(n0 + r) * 256 + tid;
    if (Cf) Cf[o] = acc;
    if (Cb) Cb[o] = f2bf(acc);
    colacc += acc;
  }
  if (gsum) atomicAdd(&gsum[tid], colacc);
  if (er0) {
    int r = tid >> 4, e = (tid >> 3) & 1, h = tid & 7;
    int n = n0 + r;
    if (r < nrows) {
      const float* Mp = M + e * 256;
      float s = c[e * 8 + h];
#pragma unroll
      for (int j = 0; j < 32; ++j) s += Ar[r][j] * Mp[j * 8 + h];
      (e ? er1 : er0)[n * 8 + h] = s;
    }
  }
}

// merged encoders: usv blocks then task blocks (task part also emits er, er2)
__global__ __launch_bounds__(256) void enc_gemm(const float* __restrict__ uf,
                                                const float* __restrict__ uw,
                                                const float* __restrict__ ub,
                                                float* __restrict__ out_usv,
                                                short* __restrict__ usvh_b,
                                                const float* __restrict__ tf,
                                                const float* __restrict__ tw,
                                                const float* __restrict__ tb,
                                                short* __restrict__ taskh_b,
                                                float* __restrict__ g,
                                                const float* __restrict__ M,
                                                const float* __restrict__ c,
                                                float* __restrict__ er,
                                                float* __restrict__ er2, int nbU) {
  int b = blockIdx.x;
  if (b < nbU)
    k32_body(uf, uw, ub, out_usv, usvh_b, NU, b, g, nullptr, nullptr, nullptr, nullptr);
  else
    k32_body(tf, tw, tb, nullptr, taskh_b, NT, b - nbU, nullptr, M, c, er, er2);
}

// ---- fused head-mean + K=32 GEMM -> bf16 (bf16 obuf inputs, optional er for L1) ----
__global__ __launch_bounds__(256) void gemm_k32hm(const short* __restrict__ obuf,
                                                  const short* __restrict__ obuf2,
                                                  const float* __restrict__ W,
                                                  const float* __restrict__ bias,
                                                  short* __restrict__ Cb, int N,
                                                  const float* __restrict__ M1,
                                                  const float* __restrict__ c1,
                                                  float* __restrict__ erOut) {
  __shared__ float Ws[32][256];
  __shared__ float Ar[16][32];
  int tid = threadIdx.x;
  for (int i = tid; i < 32 * 256; i += 256) Ws[i >> 8][i & 255] = W[i];
  int n0 = blockIdx.x * 16;
  for (int i = tid; i < 512; i += 256) {
    int r = i >> 5, f = i & 31;
    int n = n0 + r;
    float s = 0.f;
    if (n < N) {
#pragma unroll
      for (int h = 0; h < 8; ++h) s += bf2f(obuf[(size_t)n * 256 + h * 32 + f]);
      if (obuf2) {
#pragma unroll
        for (int h = 0; h < 8; ++h) s += bf2f(obuf2[(size_t)n * 256 + h * 32 + f]);
      }
    }
    Ar[r][f] = s * 0.125f;
  }
  __syncthreads();
  float b = bias[tid];
  int nrows = min(16, N - n0);
  for (int r = 0; r < nrows; ++r) {
    float acc = b;
#pragma unroll
    for (int k = 0; k < 32; ++k) acc += Ar[r][k] * Ws[k][tid];
    Cb[(size_t)(n0 + r) * 256 + tid] = f2bf(acc);
  }
  if (erOut && tid < 128) {
    int r = tid >> 3, h = tid & 7;
    int n = n0 + r;
    if (r < nrows) {
      float s = c1[h];
#pragma unroll
      for (int j = 0; j < 32; ++j) s += Ar[r][j] * M1[j * 8 + h];
      erOut[n * 8 + h] = s;
    }
  }
}

// ---- direct-load MFMA GEMM: no LDS, wave = 32 rows x 64 cols; fp8/bf16/f32 outs ----
__device__ inline void gemm_dl_body(const short* __restrict__ A,
                                    const short* __restrict__ Wt,
                                    const float* __restrict__ bias,
                                    float* __restrict__ Cf, short* __restrict__ Cb,
                                    unsigned char* __restrict__ Cq,
                                    int N, int relu, float* __restrict__ gsum,
                                    const float* __restrict__ elW,
                                    float* __restrict__ elOut,
                                    int strip) {
  int lane = threadIdx.x & 63;
  int wv = threadIdx.x >> 6;
  int fr = lane & 15, fq = lane >> 4;
  int row0 = strip * 32;
  int col0 = wv * 64;

  f32x4 acc[2][4];
#pragma unroll
  for (int m = 0; m < 2; ++m)
#pragma unroll
    for (int n = 0; n < 4; ++n) acc[m][n] = (f32x4){0.f, 0.f, 0.f, 0.f};

  const int gr0 = row0 + fr, gr1 = row0 + 16 + fr;
  const bool v0 = gr0 < N, v1 = gr1 < N;
  const short* pa0 = A + (size_t)gr0 * 256 + fq * 8;
  const short* pa1 = A + (size_t)gr1 * 256 + fq * 8;
  const short* pb = Wt + (size_t)(col0 + fr) * 256 + fq * 8;

#pragma unroll
  for (int k0 = 0; k0 < 256; k0 += 32) {
    s16x8 a0 = v0 ? *(const s16x8*)(pa0 + k0) : (s16x8){0,0,0,0,0,0,0,0};
    s16x8 a1 = v1 ? *(const s16x8*)(pa1 + k0) : (s16x8){0,0,0,0,0,0,0,0};
    s16x8 b0 = *(const s16x8*)(pb + k0);
    s16x8 b1 = *(const s16x8*)(pb + 16 * 256 + k0);
    s16x8 b2 = *(const s16x8*)(pb + 32 * 256 + k0);
    s16x8 b3 = *(const s16x8*)(pb + 48 * 256 + k0);
    acc[0][0] = __builtin_amdgcn_mfma_f32_16x16x32_bf16(a0, b0, acc[0][0], 0, 0, 0);
    acc[0][1] = __builtin_amdgcn_mfma_f32_16x16x32_bf16(a0, b1, acc[0][1], 0, 0, 0);
    acc[0][2] = __builtin_amdgcn_mfma_f32_16x16x32_bf16(a0, b2, acc[0][2], 0, 0, 0);
    acc[0][3] = __builtin_amdgcn_mfma_f32_16x16x32_bf16(a0, b3, acc[0][3], 0, 0, 0);
    acc[1][0] = __builtin_amdgcn_mfma_f32_16x16x32_bf16(a1, b0, acc[1][0], 0, 0, 0);
    acc[1][1] = __builtin_amdgcn_mfma_f32_16x16x32_bf16(a1, b1, acc[1][1], 0, 0, 0);
    acc[1][2] = __builtin_amdgcn_mfma_f32_16x16x32_bf16(a1, b2, acc[1][2], 0, 0, 0);
    acc[1][3] = __builtin_amdgcn_mfma_f32_16x16x32_bf16(a1, b3, acc[1][3], 0, 0, 0);
  }

  // el epilogue: wave covers heads 2wv, 2wv+1; reduce acc*al over the 16 fr lanes
  if (elOut) {
    float al0 = elW[(2 * wv + 0) * 32 + fr];
    float al1 = elW[(2 * wv + 0) * 32 + 16 + fr];
    float al2 = elW[(2 * wv + 1) * 32 + fr];
    float al3 = elW[(2 * wv + 1) * 32 + 16 + fr];
#pragma unroll
    for (int m = 0; m < 2; ++m) {
#pragma unroll
      for (int r = 0; r < 4; ++r) {
        int row = row0 + m * 16 + fq * 4 + r;
        float p0 = acc[m][0][r] * al0 + acc[m][1][r] * al1;
        float p1 = acc[m][2][r] * al2 + acc[m][3][r] * al3;
        p0 += __shfl_xor(p0, 1); p0 += __shfl_xor(p0, 2);
        p0 += __shfl_xor(p0, 4); p0 += __shfl_xor(p0, 8);
        p1 += __shfl_xor(p1, 1); p1 += __shfl_xor(p1, 2);
        p1 += __shfl_xor(p1, 4); p1 += __shfl_xor(p1, 8);
        if (fr == 0 && row < N) {
          elOut[row * 8 + 2 * wv] = p0;
          elOut[row * 8 + 2 * wv + 1] = p1;
        }
      }
    }
  }

  float bv[4];
#pragma unroll
  for (int n = 0; n < 4; ++n) bv[n] = bias ? bias[col0 + n * 16 + fr] : 0.f;

  float csum[4] = {0.f, 0.f, 0.f, 0.f};
#pragma unroll
  for (int m = 0; m < 2; ++m) {
    int grb = row0 + m * 16 + fq * 4;
#pragma unroll
    for (int r = 0; r < 4; ++r) {
      if (grb + r >= N) continue;
#pragma unroll
      for (int n = 0; n < 4; ++n) {
        float v = acc[m][n][r] + bv[n];
        if (relu) v = fmaxf(v, 0.f);
        size_t o = (size_t)(grb + r) * 256 + col0 + n * 16 + fr;
        if (Cf) Cf[o] = v;
        if (Cb) Cb[o] = f2bf(v);
        if (Cq) Cq[o] = f2q(v);
        csum[n] += v;
      }
    }
  }
  if (gsum) {
#pragma unroll
    for (int n = 0; n < 4; ++n) {
      float s = csum[n];
      s += __shfl_xor(s, 16);
      s += __shfl_xor(s, 32);
      if (fq == 0) atomicAdd(&gsum[col0 + n * 16 + fr], s);
    }
  }
}

__global__ __launch_bounds__(256) void gemm_dl(const short* __restrict__ A,
                                               const short* __restrict__ Wt,
                                               const float* __restrict__ bias,
                                               float* __restrict__ Cf,
                                               short* __restrict__ Cb,
                                               unsigned char* __restrict__ Cq,
                                               int N, int relu, float* __restrict__ gsum,
                                               const float* __restrict__ elW,
                                               float* __restrict__ elOut) {
  gemm_dl_body(A, Wt, bias, Cf, Cb, Cq, N, relu, gsum, elW, elOut, blockIdx.x);
}

// layer-0 dual: tt strips then ut strips (both with el epilogues, fp8 fs outputs)
__global__ __launch_bounds__(256) void gemm_dl_dual(const short* __restrict__ A0,
                                                    const short* __restrict__ Wt0,
                                                    unsigned char* __restrict__ C0q,
                                                    const float* __restrict__ elW0,
                                                    float* __restrict__ el0,
                                                    const short* __restrict__ A1,
                                                    const short* __restrict__ Wt1,
                                                    unsigned char* __restrict__ C1q,
                                                    const float* __restrict__ elW1,
                                                    float* __restrict__ el1,
                                                    int nstr0) {
  if ((int)blockIdx.x < nstr0)
    gemm_dl_body(A0, Wt0, nullptr, nullptr, nullptr, C0q, NT, 0, nullptr, elW0, el0, blockIdx.x);
  else
    gemm_dl_body(A1, Wt1, nullptr, nullptr, nullptr, C1q, NU, 0, nullptr, elW1, el1, blockIdx.x - nstr0);
}

// ---------------- CSR scan + scatter ----------------
__global__ __launch_bounds__(1024) void scan2(const int* __restrict__ d0, int* __restrict__ o0,
                                              int* __restrict__ c0,
                                              const int* __restrict__ d1, int* __restrict__ o1,
                                              int* __restrict__ c1, int n) {
  const int* deg = blockIdx.x ? d1 : d0;
  int* off = blockIdx.x ? o1 : o0;
  int* cursor = blockIdx.x ? c1 : c0;
  int tid = threadIdx.x;
  const int C = 20;
  int base = tid * C;
  int local[C];
  int s = 0;
#pragma unroll
  for (int i = 0; i < C; ++i) {
    int idx = base + i;
    int v = (idx < n) ? deg[idx] : 0;
    local[i] = s;
    s += v;
  }
  int lane = tid & 63, wave = tid >> 6;
  int x = s;
#pragma unroll
  for (int d = 1; d < 64; d <<= 1) {
    int y = __shfl_up(x, d, 64);
    if (lane >= d) x += y;
  }
  __shared__ int wsum[16];
  if (lane == 63) wsum[wave] = x;
  __syncthreads();
  if (wave == 0) {
    int wv = (lane < 16) ? wsum[lane] : 0;
#pragma unroll
    for (int d = 1; d < 16; d <<= 1) {
      int y = __shfl_up(wv, d, 64);
      if (lane >= d) wv += y;
    }
    if (lane < 16) wsum[lane] = wv;
  }
  __syncthreads();
  int waveoff = (wave == 0) ? 0 : wsum[wave - 1];
  int excl = waveoff + x - s;
#pragma unroll
  for (int i = 0; i < C; ++i) {
    int idx = base + i;
    if (idx < n) {
      int o = excl + local[i];
      off[idx] = o;
      cursor[idx] = o;
    }
  }
  if (tid == 1023) off[n] = waveoff + x;
}

__global__ void scat2(const int* __restrict__ tt_src, const int* __restrict__ tt_dst,
                      int* __restrict__ tt_cur, int* __restrict__ tt_srcs,
                      const int* __restrict__ ut_src, const int* __restrict__ ut_dst,
                      int* __restrict__ ut_cur, int* __restrict__ ut_srcs) {
  int e = blockIdx.x * 256 + threadIdx.x;
  if (e < E_TT) {
    int p = atomicAdd(&tt_cur[tt_dst[e]], 1);
    tt_srcs[p] = tt_src[e];
  }
  int e2 = e - E_TT;
  if (e2 >= 0 && e2 < E_UT) {
    int p = atomicAdd(&ut_cur[ut_dst[e2]], 1);
    ut_srcs[p] = ut_src[e2];
  }
}

// -------- fused softmax + aggregation, wave/node, LDS weights, fp8 gather -----------
__device__ inline float gat_w(const float* __restrict__ el, int src, int h,
                              float ern, float mh) {
  float l = el[src * 8 + h] + ern;
  l = l >= 0.f ? l : 0.2f * l;
  return __expf(l - mh);
}

__device__ inline void gat_body(const int* __restrict__ offs, const int* __restrict__ srcs,
                                const float* __restrict__ el, const float* __restrict__ er,
                                const unsigned char* __restrict__ fsq,
                                const float* __restrict__ bias0,
                                const float* __restrict__ bias1,
                                short* __restrict__ out, int n, float (*wl)[8]) {
  int lane = threadIdx.x & 63;
  int e0 = offs[n], e1 = offs[n + 1];
  s16x4* po = (s16x4*)(out + (size_t)n * 256 + lane * 4);
  if (e0 == e1) {
    float4 o = {0.f, 0.f, 0.f, 0.f};
    if (bias0) {
      o = *(const float4*)(bias0 + lane * 4);
      if (bias1) {
        float4 b1 = *(const float4*)(bias1 + lane * 4);
        o.x += b1.x; o.y += b1.y; o.z += b1.z; o.w += b1.w;
      }
    }
    *po = (s16x4){f2bf(o.x), f2bf(o.y), f2bf(o.z), f2bf(o.w)};
    return;
  }
  int h1 = lane & 7, slot = lane >> 3;
  float ern1 = er[n * 8 + h1];
  float m = -3.4e38f;
  for (int i = e0 + slot; i < e1; i += 8) {
    float l = el[srcs[i] * 8 + h1] + ern1;
    l = l >= 0.f ? l : 0.2f * l;
    int idx = i - e0;
    if (idx < CAP) wl[idx][h1] = l;
    m = fmaxf(m, l);
  }
  m = fmaxf(m, __shfl_xor(m, 8));
  m = fmaxf(m, __shfl_xor(m, 16));
  m = fmaxf(m, __shfl_xor(m, 32));
  float s = 0.f;
  for (int i = e0 + slot; i < e1; i += 8) {
    int idx = i - e0;
    float l;
    if (idx < CAP) l = wl[idx][h1];
    else {
      l = el[srcs[i] * 8 + h1] + ern1;
      l = l >= 0.f ? l : 0.2f * l;
    }
    float w = __expf(l - m);
    if (idx < CAP) wl[idx][h1] = w;
    s += w;
  }
  s += __shfl_xor(s, 8);
  s += __shfl_xor(s, 16);
  s += __shfl_xor(s, 32);
  int h2 = lane >> 3;
  float mh = __shfl(m, h2);
  float sh = __shfl(s, h2);
  float ern2 = __shfl(ern1, h2);
  float ax = 0.f, ay = 0.f, az = 0.f, aw = 0.f;
  int i = e0;
  for (; i + 4 <= e1; i += 4) {
    int s0 = srcs[i], s1 = srcs[i + 1], s2 = srcs[i + 2], s3 = srcs[i + 3];
    unsigned q0 = *(const unsigned*)(fsq + (size_t)s0 * 256 + lane * 4);
    unsigned q1 = *(const unsigned*)(fsq + (size_t)s1 * 256 + lane * 4);
    unsigned q2 = *(const unsigned*)(fsq + (size_t)s2 * 256 + lane * 4);
    unsigned q3 = *(const unsigned*)(fsq + (size_t)s3 * 256 + lane * 4);
    int idx = i - e0;
    float w0, w1, w2, w3;
    if (idx + 3 < CAP) {
      w0 = wl[idx][h2]; w1 = wl[idx + 1][h2];
      w2 = wl[idx + 2][h2]; w3 = wl[idx + 3][h2];
    } else {
      w0 = (idx < CAP) ? wl[idx][h2] : gat_w(el, s0, h2, ern2, mh);
      w1 = (idx + 1 < CAP) ? wl[idx + 1][h2] : gat_w(el, s1, h2, ern2, mh);
      w2 = (idx + 2 < CAP) ? wl[idx + 2][h2] : gat_w(el, s2, h2, ern2, mh);
      w3 = gat_w(el, s3, h2, ern2, mh);
    }
    f32x2 l0 = __builtin_amdgcn_cvt_pk_f32_fp8(q0, false);
    f32x2 u0 = __builtin_amdgcn_cvt_pk_f32_fp8(q0, true);
    f32x2 l1 = __builtin_amdgcn_cvt_pk_f32_fp8(q1, false);
    f32x2 u1 = __builtin_amdgcn_cvt_pk_f32_fp8(q1, true);
    f32x2 l2 = __builtin_amdgcn_cvt_pk_f32_fp8(q2, false);
    f32x2 u2 = __builtin_amdgcn_cvt_pk_f32_fp8(q2, true);
    f32x2 l3 = __builtin_amdgcn_cvt_pk_f32_fp8(q3, false);
    f32x2 u3 = __builtin_amdgcn_cvt_pk_f32_fp8(q3, true);
    ax += w0 * l0[0] + w1 * l1[0] + w2 * l2[0] + w3 * l3[0];
    ay += w0 * l0[1] + w1 * l1[1] + w2 * l2[1] + w3 * l3[1];
    az += w0 * u0[0] + w1 * u1[0] + w2 * u2[0] + w3 * u3[0];
    aw += w0 * u0[1] + w1 * u1[1] + w2 * u2[1] + w3 * u3[1];
  }
  for (; i < e1; ++i) {
    int src = srcs[i];
    int idx = i - e0;
    float w = (idx < CAP) ? wl[idx][h2] : gat_w(el, src, h2, ern2, mh);
    unsigned q = *(const unsigned*)(fsq + (size_t)src * 256 + lane * 4);
    f32x2 lo = __builtin_amdgcn_cvt_pk_f32_fp8(q, false);
    f32x2 up = __builtin_amdgcn_cvt_pk_f32_fp8(q, true);
    ax += w * lo[0];
    ay += w * lo[1];
    az += w * up[0];
    aw += w * up[1];
  }
  float sinv = 1.f / sh;
  float4 o = {ax * sinv, ay * sinv, az * sinv, aw * sinv};
  if (bias0) {
    float4 b = *(const float4*)(bias0 + lane * 4);
    o.x += b.x; o.y += b.y; o.z += b.z; o.w += b.w;
    if (bias1) {
      float4 b1 = *(const float4*)(bias1 + lane * 4);
      o.x += b1.x; o.y += b1.y; o.z += b1.z; o.w += b1.w;
    }
  }
  *po = (s16x4){f2bf(o.x), f2bf(o.y), f2bf(o.z), f2bf(o.w)};
}

__global__ __launch_bounds__(256) void gat_fused2(
    const int* __restrict__ oA, const int* __restrict__ sA,
    const float* __restrict__ elA, const float* __restrict__ erA,
    const unsigned char* __restrict__ fA,
    const float* __restrict__ b0A, const float* __restrict__ b1A,
    short* __restrict__ outA, int ndstA, int nA,
    const int* __restrict__ oB, const int* __restrict__ sB,
    const float* __restrict__ elB, const float* __restrict__ erB,
    const unsigned char* __restrict__ fB, short* __restrict__ outB, int ndstB) {
  __shared__ float wlds[4][CAP][8];
  int wv = threadIdx.x >> 6;
  int b = blockIdx.x;
  if (b < nA) {
    int n = b * 4 + wv;
    if (n >= ndstA) return;
    gat_body(oA, sA, elA, erA, fA, b0A, b1A, outA, n, wlds[wv]);
  } else {
    int n = (b - nA) * 4 + wv;
    if (n >= ndstB) return;
    gat_body(oB, sB, elB, erB, fB, nullptr, nullptr, outB, n, wlds[wv]);
  }
}

// ---------------- global projection (with mean scaling) ----------------
__global__ __launch_bounds__(512) void global_proj(const float* __restrict__ g,
                                                   const float* __restrict__ W,
                                                   const float* __restrict__ b,
                                                   float* __restrict__ out) {
  __shared__ float gl[512];
  int tid = threadIdx.x;
  gl[tid] = g[tid] * (tid < 256 ? (1.f / NU) : (1.f / NT));
  __syncthreads();
  float s = b[tid];
  for (int k = 0; k < 512; ++k) s += gl[k] * W[k * 512 + tid];
  out[tid] = s;
}

extern "C" void kernel_launch(void* const* d_in, const int* in_sizes, int n_in,
                              void* d_out, int out_size, void* d_ws, size_t ws_size,
                              hipStream_t stream) {
  const float* usv_feat   = (const float*)d_in[0];
  const float* task_feat  = (const float*)d_in[1];
  const float* usv_enc_w  = (const float*)d_in[2];
  const float* usv_enc_b  = (const float*)d_in[3];
  const float* task_enc_w = (const float*)d_in[4];
  const float* task_enc_b = (const float*)d_in[5];
  const float* l0_tt_wsrc = (const float*)d_in[6];
  const float* l0_tt_wdst = (const float*)d_in[7];
  const float* l0_tt_al   = (const float*)d_in[8];
  const float* l0_tt_ar   = (const float*)d_in[9];
  const float* l0_tt_bias = (const float*)d_in[10];
  const float* l0_ut_wsrc = (const float*)d_in[11];
  const float* l0_ut_wdst = (const float*)d_in[12];
  const float* l0_ut_al   = (const float*)d_in[13];
  const float* l0_ut_ar   = (const float*)d_in[14];
  const float* l0_ut_bias = (const float*)d_in[15];
  const float* l0_post_w  = (const float*)d_in[16];
  const float* l0_post_b  = (const float*)d_in[17];
  const float* l1_tt_wsrc = (const float*)d_in[18];
  const float* l1_tt_wdst = (const float*)d_in[19];
  const float* l1_tt_al   = (const float*)d_in[20];
  const float* l1_tt_ar   = (const float*)d_in[21];
  const float* l1_tt_bias = (const float*)d_in[22];
  const float* l1_post_w  = (const float*)d_in[23];
  const float* l1_post_b  = (const float*)d_in[24];
  const float* task_dec_w = (const float*)d_in[25];
  const float* task_dec_b = (const float*)d_in[26];
  const float* gp_w       = (const float*)d_in[27];
  const float* gp_b       = (const float*)d_in[28];
  const int* tt_src = (const int*)d_in[29];
  const int* tt_dst = (const int*)d_in[30];
  const int* ut_src = (const int*)d_in[31];
  const int* ut_dst = (const int*)d_in[32];

  float* out = (float*)d_out;
  float* out_usv  = out;
  float* out_task = out + NU * HID;
  float* out_glob = out + NU * HID + NT * HID;

  char* ws = (char*)d_ws;
  size_t off = 0;
  auto alloc_f = [&](size_t n) {
    float* p = (float*)(ws + off);
    off += ((n * 4 + 1023) / 1024) * 1024;
    return p;
  };
  auto alloc_i = [&](size_t n) {
    int* p = (int*)(ws + off);
    off += ((n * 4 + 1023) / 1024) * 1024;
    return p;
  };
  auto alloc_s = [&](size_t n) {
    short* p = (short*)(ws + off);
    off += ((n * 2 + 1023) / 1024) * 1024;
    return p;
  };
  auto alloc_b = [&](size_t n) {
    unsigned char* p = (unsigned char*)(ws + off);
    off += ((n + 1023) / 1024) * 1024;
    return p;
  };
  short* taskh_b = alloc_s((size_t)NT * HID);
  short* usvh_b  = alloc_s((size_t)NU * HID);
  unsigned char* fs_q  = alloc_b((size_t)NT * HID);
  unsigned char* fsu_q = alloc_b((size_t)NU * HID);
  short* obuf_b  = alloc_s((size_t)NT * HID);
  short* obuf2_b = alloc_s((size_t)NT * HID);
  float* el    = alloc_f((size_t)NT * HEADS);
  float* er    = alloc_f((size_t)NT * HEADS);
  float* el2   = alloc_f((size_t)NU * HEADS);
  float* er2   = alloc_f((size_t)NT * HEADS);
  float* w2all = alloc_f(3 * 2048);
  float* g     = alloc_f(512);
  float* Mbuf  = alloc_f(768);
  float* cbuf  = alloc_f(24);
  short* wt0 = alloc_s(256 * 256);
  short* wt1 = alloc_s(256 * 256);
  short* wt2 = alloc_s(256 * 256);
  short* wt3 = alloc_s(256 * 256);
  int* tt_deg  = alloc_i(NT);
  int* tt_offs = alloc_i(NT + 1);
  int* tt_cur  = alloc_i(NT);
  int* tt_srcs = alloc_i(E_TT);
  int* ut_deg  = alloc_i(NT);
  int* ut_offs = alloc_i(NT + 1);
  int* ut_cur  = alloc_i(NT);
  int* ut_srcs = alloc_i(E_UT);

  // 1) transposes + w2 + zero init
  prep<<<dim3(8, 8, 6), 256, 0, stream>>>(l0_tt_wsrc, l0_ut_wsrc, l1_tt_wsrc, task_dec_w,
                                          wt0, wt1, wt2, wt3,
                                          l0_tt_wdst, l0_tt_ar, l0_ut_wdst, l0_ut_ar,
                                          l1_tt_wdst, l1_tt_ar, w2all,
                                          tt_deg, ut_deg, g);

  // 2) degree count + er-projection matrices
  int nbE = (E_TT + E_UT + 255) / 256;
  deg2M<<<nbE, 256, 0, stream>>>(tt_dst, ut_dst, tt_deg, ut_deg,
                                 task_enc_w, task_enc_b, l0_post_w, l0_post_b,
                                 w2all, Mbuf, cbuf);

  // 3-4) CSR scan + scatter
  scan2<<<2, 1024, 0, stream>>>(tt_deg, tt_offs, tt_cur, ut_deg, ut_offs, ut_cur, NT);
  scat2<<<nbE, 256, 0, stream>>>(tt_src, tt_dst, tt_cur, tt_srcs, ut_src, ut_dst, ut_cur, ut_srcs);

  // 5) encoders (usv: colsum into g; task: er, er2 epilogue)
  int nbU16 = (NU + 15) / 16, nbT16 = (NT + 15) / 16;
  enc_gemm<<<nbU16 + nbT16, 256, 0, stream>>>(usv_feat, usv_enc_w, usv_enc_b, out_usv, usvh_b,
                                              task_feat, task_enc_w, task_enc_b, taskh_b,
                                              g, Mbuf, cbuf, er, er2, nbU16);

  int nstrT = (NT + 31) / 32, nstrU = (NU + 31) / 32;
  int nbAgg = (NT + 3) / 4;

  // 6) layer 0: both GEMMs + el/el2 epilogues, fp8 fs outputs
  gemm_dl_dual<<<nstrT + nstrU, 256, 0, stream>>>(taskh_b, wt0, fs_q, l0_tt_al, el,
                                                  usvh_b, wt1, fsu_q, l0_ut_al, el2, nstrT);

  // 7) layer 0: both aggregations (tt -> obuf_b, ut -> obuf2_b)
  gat_fused2<<<nbAgg + nbAgg, 256, 0, stream>>>(
      tt_offs, tt_srcs, el, er, fs_q, l0_tt_bias, l0_ut_bias, obuf_b, NT, nbAgg,
      ut_offs, ut_srcs, el2, er2, fsu_q, obuf2_b, NT);

  // 8) post 0 (head-mean fused) + er for layer 1
  gemm_k32hm<<<nbT16, 256, 0, stream>>>(obuf_b, obuf2_b, l0_post_w, l0_post_b, taskh_b, NT,
                                        Mbuf + 512, cbuf + 16, er);

  // 9) layer 1 GEMM + el epilogue, fp8 fs output
  gemm_dl<<<nstrT, 256, 0, stream>>>(taskh_b, wt2, nullptr, nullptr, nullptr, fs_q, NT, 0, nullptr,
                                     l1_tt_al, el);

  // 10) layer 1 aggregation
  gat_fused2<<<nbAgg, 256, 0, stream>>>(
      tt_offs, tt_srcs, el, er, fs_q, l1_tt_bias, nullptr, obuf_b, NT, nbAgg,
      tt_offs, tt_srcs, el, er, fs_q, obuf2_b, 0);

  // 11) post 1
  gemm_k32hm<<<nbT16, 256, 0, stream>>>(obuf_b, nullptr, l1_post_w, l1_post_b, taskh_b, NT,
                                        nullptr, nullptr, nullptr);

  // 12) decoder (relu, f32 out, fused task column sums)
  gemm_dl<<<nstrT, 256, 0, stream>>>(taskh_b, wt3, task_dec_b, out_task, nullptr, nullptr, NT, 1,
                                     g + 256, nullptr, nullptr);

  // 13) global projection
  global_proj<<<1, 512, 0, stream>>>(g, gp_w, gp_b, out_glob);
}